// Round 1
// baseline (7437.538 us; speedup 1.0000x reference)
//
#include <hip/hip_runtime.h>
#include <cstddef>

#define B_   16
#define N_   8192
#define G_   512
#define K_   32
#define GT   8192          // B_*G_
#define NROW 262144        // GT*K_
#define EPS  1e-5f

// ---------------- workspace layout (float offsets) ----------------
constexpr size_t OFF_CENTERS = 0;                          // B*G*3
constexpr size_t OFF_NB      = OFF_CENTERS + 24576;        // GT*K*3
constexpr size_t OFF_FG      = OFF_NB      + 786432;       // GT*256
constexpr size_t OFF_C1      = OFF_FG      + 2097152;      // GT*128
constexpr size_t OFF_MOM     = OFF_C1      + 1048576;      // 16
constexpr size_t OFF_A       = OFF_MOM     + 16;           // 128*128
constexpr size_t OFF_S1      = OFF_A       + 16384;        // 128
constexpr size_t OFF_SF      = OFF_S1      + 128;          // 256
constexpr size_t OFF_MU      = OFF_SF      + 256;          // 512
constexpr size_t OFF_W2S1    = OFF_MU      + 512;          // 256
constexpr size_t OFF_BN1A    = OFF_W2S1    + 256;          // 128
constexpr size_t OFF_BN1D    = OFF_BN1A    + 128;          // 128
constexpr size_t OFF_BN3A    = OFF_BN1D    + 128;          // 512
constexpr size_t OFF_BN3D    = OFF_BN3A    + 512;          // 512
constexpr size_t OFF_SFF     = OFF_BN3D    + 512;          // 256*256
constexpr size_t OFF_PFCT    = OFF_SFF     + 65536;        // 128*256
constexpr size_t OFF_T1      = OFF_PFCT    + 32768;        // 128*256
constexpr size_t OFF_SCCW    = OFF_T1      + 32768;        // 256*256
constexpr size_t OFF_SFC     = OFF_SCCW    + 65536;        // 256*256
constexpr size_t OFF_W2T     = OFF_SFC     + 65536;        // 128*256
constexpr size_t OFF_W3T     = OFF_W2T     + 32768;        // 512*512
constexpr size_t OFF_W4T     = OFF_W3T     + 262144;       // 512*384
constexpr size_t OFF_APART   = OFF_W4T     + 196608;       // 512 blocks * 16384
constexpr size_t WS_FLOATS   = OFF_APART   + 8388608;      // ~52.5 MB

// =================== FPS ===================
// One block per batch. Points + dists in registers (8/thread, strided).
// Tie-break = lowest index, matching jnp.argmax. Distance arithmetic pinned
// (no fma contraction) to mimic XLA's sub/square/sum.
__global__ __launch_bounds__(1024) void fps_kernel(const float* __restrict__ xyz,
                                                   float* __restrict__ centers) {
    int b = blockIdx.x, t = threadIdx.x;
    const float* xb = xyz + (size_t)b * N_ * 3;
    float px[8], py[8], pz[8], dist[8];
#pragma unroll
    for (int i = 0; i < 8; ++i) {
        int p = t + (i << 10);
        px[i] = xb[p*3]; py[i] = xb[p*3+1]; pz[i] = xb[p*3+2];
        dist[i] = 1e10f;
    }
    __shared__ float cx, cy, cz;
    __shared__ int farS;
    __shared__ float redV[16];
    __shared__ int   redI[16];
    if (t == 0) farS = 0;
    __syncthreads();
    for (int it = 0; it < G_; ++it) {
        int far = farS;
        if ((far & 1023) == t) {
            int i = far >> 10;
            cx = px[i]; cy = py[i]; cz = pz[i];
            float* cd = centers + ((size_t)b * G_ + it) * 3;
            cd[0] = px[i]; cd[1] = py[i]; cd[2] = pz[i];
        }
        __syncthreads();
        float lcx = cx, lcy = cy, lcz = cz;
        float bv = -1.0f; int bp = 0;
#pragma unroll
        for (int i = 0; i < 8; ++i) {
            float dx = __fsub_rn(px[i], lcx);
            float dy = __fsub_rn(py[i], lcy);
            float dz = __fsub_rn(pz[i], lcz);
            float d  = __fadd_rn(__fadd_rn(__fmul_rn(dx,dx), __fmul_rn(dy,dy)), __fmul_rn(dz,dz));
            float nd = fminf(dist[i], d);
            dist[i] = nd;
            if (nd > bv) { bv = nd; bp = t + (i << 10); }
        }
#pragma unroll
        for (int off = 1; off < 64; off <<= 1) {
            float ov = __shfl_xor(bv, off);
            int   op = __shfl_xor(bp, off);
            if (ov > bv || (ov == bv && op < bp)) { bv = ov; bp = op; }
        }
        if ((t & 63) == 0) { redV[t >> 6] = bv; redI[t >> 6] = bp; }
        __syncthreads();
        if (t < 16) {
            float v = redV[t]; int p = redI[t];
#pragma unroll
            for (int off = 1; off < 16; off <<= 1) {
                float ov = __shfl_xor(v, off, 16);
                int   op = __shfl_xor(p, off, 16);
                if (ov > v || (ov == v && op < p)) { v = ov; p = op; }
            }
            if (t == 0) farS = p;
        }
        __syncthreads();
    }
}

// =================== kNN + gather(centered) ===================
// One block per (b,g) query. Reference distance formula: -2*dot + |c|^2 + |p|^2.
// 32 iterative argmins over LDS dist array; tie -> lowest index (= top_k order).
__global__ __launch_bounds__(256) void knn_kernel(const float* __restrict__ xyz,
                                                  const float* __restrict__ centers,
                                                  float* __restrict__ nb) {
    int g = blockIdx.x, t = threadIdx.x;
    int b = g >> 9;
    const float* xb = xyz + (size_t)b * N_ * 3;
    const float* c  = centers + (size_t)g * 3;
    float lcx = c[0], lcy = c[1], lcz = c[2];
    float cn2 = __fadd_rn(__fadd_rn(__fmul_rn(lcx,lcx), __fmul_rn(lcy,lcy)), __fmul_rn(lcz,lcz));
    __shared__ float distL[N_];
    __shared__ int   sel[K_];
    __shared__ float redV[4];
    __shared__ int   redI[4];
#pragma unroll 4
    for (int i = 0; i < 32; ++i) {
        int p = t + (i << 8);
        float x = xb[p*3], y = xb[p*3+1], z = xb[p*3+2];
        float pn2 = __fadd_rn(__fadd_rn(__fmul_rn(x,x), __fmul_rn(y,y)), __fmul_rn(z,z));
        float dot = __fadd_rn(__fadd_rn(__fmul_rn(lcx,x), __fmul_rn(lcy,y)), __fmul_rn(lcz,z));
        float d   = __fadd_rn(__fadd_rn(__fmul_rn(-2.0f,dot), cn2), pn2);
        distL[p] = d;
    }
    __syncthreads();
    for (int s = 0; s < K_; ++s) {
        float bv = 1e30f; int bp = 0;
#pragma unroll 4
        for (int i = 0; i < 32; ++i) {
            int p = t + (i << 8);
            float v = distL[p];
            if (v < bv) { bv = v; bp = p; }
        }
#pragma unroll
        for (int off = 1; off < 64; off <<= 1) {
            float ov = __shfl_xor(bv, off);
            int   op = __shfl_xor(bp, off);
            if (ov < bv || (ov == bv && op < bp)) { bv = ov; bp = op; }
        }
        if ((t & 63) == 0) { redV[t >> 6] = bv; redI[t >> 6] = bp; }
        __syncthreads();
        if (t == 0) {
            float v = redV[0]; int p = redI[0];
            for (int w = 1; w < 4; ++w) {
                float ov = redV[w]; int op = redI[w];
                if (ov < v || (ov == v && op < p)) { v = ov; p = op; }
            }
            sel[s] = p; distL[p] = 1e30f;
        }
        __syncthreads();
    }
    if (t < K_) {
        int p = sel[t];
        float* dst = nb + ((size_t)g * K_ + t) * 3;
        dst[0] = xb[p*3]   - lcx;
        dst[1] = xb[p*3+1] - lcy;
        dst[2] = xb[p*3+2] - lcz;
    }
}

// =================== small utility kernels ===================
__global__ void zero_mom_kernel(float* __restrict__ mom) {
    if (threadIdx.x < 16) mom[threadIdx.x] = 0.0f;
}

// first/second xyz moments of nb (for analytic bn1 stats)
__global__ void moments_kernel(const float* __restrict__ nb, float* __restrict__ mom) {
    int idx = blockIdx.x * blockDim.x + threadIdx.x;
    float x = 0.f, y = 0.f, z = 0.f;
    if (idx < NROW) { x = nb[idx*3]; y = nb[idx*3+1]; z = nb[idx*3+2]; }
    float v[9] = {x, y, z, x*x, y*y, z*z, x*y, x*z, y*z};
#pragma unroll
    for (int q = 0; q < 9; ++q) {
        float s = v[q];
#pragma unroll
        for (int off = 32; off; off >>= 1) s += __shfl_xor(s, off);
        if ((threadIdx.x & 63) == 0) atomicAdd(&mom[q], s);
    }
}

__global__ void bn1_params_kernel(const float* __restrict__ mom,
                                  const float* __restrict__ w1, const float* __restrict__ b1,
                                  const float* __restrict__ g1, const float* __restrict__ bt1,
                                  float* __restrict__ bn1a, float* __restrict__ bn1d) {
    int c = threadIdx.x;  // 128
    const float inv_n = 1.0f / (float)NROW;
    float mx = mom[0]*inv_n, my = mom[1]*inv_n, mz = mom[2]*inv_n;
    float cxx = mom[3]*inv_n - mx*mx, cyy = mom[4]*inv_n - my*my, czz = mom[5]*inv_n - mz*mz;
    float cxy = mom[6]*inv_n - mx*my, cxz = mom[7]*inv_n - mx*mz, cyz = mom[8]*inv_n - my*mz;
    float wx = w1[c*3], wy = w1[c*3+1], wz = w1[c*3+2];
    float mean = wx*mx + wy*my + wz*mz + b1[c];
    float var  = wx*wx*cxx + wy*wy*cyy + wz*wz*czz
               + 2.0f*(wx*wy*cxy + wx*wz*cxz + wy*wz*cyz);
    float a = rsqrtf(var + EPS) * g1[c];
    bn1a[c] = a;
    bn1d[c] = (b1[c] - mean) * a + bt1[c];
}

__global__ void transpose_kernel(float* __restrict__ out, const float* __restrict__ in, int R, int C) {
    int t = blockIdx.x * blockDim.x + threadIdx.x;
    if (t < R * C) {
        int i = t / C, j = t % C;
        out[(size_t)j * R + i] = in[t];
    }
}

// =================== shared f1/f2 computation (exact arithmetic, fmaf-pinned) ===================
__device__ __forceinline__ void compute_f1(const float* __restrict__ nbs, const float* __restrict__ w1,
                                           const float* __restrict__ bn1a, const float* __restrict__ bn1d,
                                           float* __restrict__ f1s, int t) {
    if (t < 128) {
        float a = bn1a[t], d = bn1d[t];
        float w0 = w1[t*3], wa = w1[t*3+1], wb = w1[t*3+2];
#pragma unroll 4
        for (int r = 0; r < 32; ++r) {
            float m = __fmul_rn(nbs[r*3], w0);
            m = __fmaf_rn(nbs[r*3+1], wa, m);
            m = __fmaf_rn(nbs[r*3+2], wb, m);
            m = __fmaf_rn(m, a, d);
            f1s[r*129 + t] = fmaxf(m, 0.0f);
        }
    }
}

__device__ __forceinline__ void compute_f2(const float* __restrict__ f1s, const float* __restrict__ w2t,
                                           const float* __restrict__ b2, float* __restrict__ f2s, int t) {
    int rb = t >> 6, cb = t & 63;     // 8-row x 4-col micro tile
    float4 bv = *reinterpret_cast<const float4*>(&b2[cb*4]);
    float acc[8][4];
#pragma unroll
    for (int m = 0; m < 8; ++m) { acc[m][0]=bv.x; acc[m][1]=bv.y; acc[m][2]=bv.z; acc[m][3]=bv.w; }
    for (int k = 0; k < 128; ++k) {
        float4 wv = *reinterpret_cast<const float4*>(&w2t[k*256 + cb*4]);
#pragma unroll
        for (int m = 0; m < 8; ++m) {
            float fv = f1s[(rb*8 + m)*129 + k];
            acc[m][0] = __fmaf_rn(fv, wv.x, acc[m][0]);
            acc[m][1] = __fmaf_rn(fv, wv.y, acc[m][1]);
            acc[m][2] = __fmaf_rn(fv, wv.z, acc[m][2]);
            acc[m][3] = __fmaf_rn(fv, wv.w, acc[m][3]);
        }
    }
#pragma unroll
    for (int m = 0; m < 8; ++m) {
        float4 o; o.x=acc[m][0]; o.y=acc[m][1]; o.z=acc[m][2]; o.w=acc[m][3];
        *reinterpret_cast<float4*>(&f2s[(rb*8 + m)*256 + cb*4]) = o;
    }
}

// =================== P1: per-group f1/f2 -> fg, c1, A-partials ===================
__global__ __launch_bounds__(256) void p1_kernel(const float* __restrict__ nbg, const float* __restrict__ w1,
                                                 const float* __restrict__ bn1a, const float* __restrict__ bn1d,
                                                 const float* __restrict__ w2t, const float* __restrict__ b2,
                                                 float* __restrict__ fg, float* __restrict__ c1,
                                                 float* __restrict__ apart) {
    __shared__ float f1s[32*129];
    __shared__ float f2s[32*256];
    __shared__ float nbs[96];
    int t = threadIdx.x;
    int i0 = (t >> 4) * 8, j0 = (t & 15) * 8;
    float accA[8][8];
#pragma unroll
    for (int m = 0; m < 8; ++m)
#pragma unroll
        for (int n = 0; n < 8; ++n) accA[m][n] = 0.f;

    for (int gi = 0; gi < 16; ++gi) {
        int g = blockIdx.x * 16 + gi;
        if (t < 96) nbs[t] = nbg[(size_t)g * 96 + t];
        __syncthreads();
        compute_f1(nbs, w1, bn1a, bn1d, f1s, t);
        __syncthreads();
        compute_f2(f1s, w2t, b2, f2s, t);
        __syncthreads();
        // fg = colmax(f2), c1 = colsum(f1)
        {
            float mx = f2s[t];
#pragma unroll 4
            for (int r = 1; r < 32; ++r) mx = fmaxf(mx, f2s[r*256 + t]);
            fg[(size_t)g * 256 + t] = mx;
            if (t < 128) {
                float s = 0.f;
#pragma unroll 4
                for (int r = 0; r < 32; ++r) s = __fadd_rn(s, f1s[r*129 + t]);
                c1[(size_t)g * 128 + t] = s;
            }
        }
        // A += f1^T f1 (8x8 register tile per thread)
#pragma unroll 2
        for (int r = 0; r < 32; ++r) {
            float am[8], bn_[8];
#pragma unroll
            for (int m = 0; m < 8; ++m) am[m]  = f1s[r*129 + i0 + m];
#pragma unroll
            for (int n = 0; n < 8; ++n) bn_[n] = f1s[r*129 + j0 + n];
#pragma unroll
            for (int m = 0; m < 8; ++m)
#pragma unroll
                for (int n = 0; n < 8; ++n)
                    accA[m][n] = __fmaf_rn(am[m], bn_[n], accA[m][n]);
        }
        __syncthreads();
    }
    float* ap = apart + (size_t)blockIdx.x * 16384;
#pragma unroll
    for (int m = 0; m < 8; ++m)
#pragma unroll
        for (int n = 0; n < 8; ++n)
            ap[(i0 + m)*128 + j0 + n] = accA[m][n];
}

__global__ void reduce_a_kernel(const float* __restrict__ apart, float* __restrict__ A) {
    int e = blockIdx.x * 256 + threadIdx.x;  // < 16384
    float s = 0.f;
    for (int b = 0; b < 512; ++b) s = __fadd_rn(s, apart[(size_t)b * 16384 + e]);
    A[e] = s;
}

__global__ void reduce_cf_kernel(const float* __restrict__ c1, const float* __restrict__ fgb,
                                 float* __restrict__ s1, float* __restrict__ sf) {
    int c = blockIdx.x, t = threadIdx.x;  // 384 blocks
    __shared__ float red[256];
    float s = 0.f;
    if (c < 128) { for (int g = t; g < GT; g += 256) s += c1[(size_t)g*128 + c]; }
    else { int cc = c - 128; for (int g = t; g < GT; g += 256) s += fgb[(size_t)g*256 + cc]; }
    red[t] = s; __syncthreads();
    for (int w = 128; w; w >>= 1) { if (t < w) red[t] += red[t + w]; __syncthreads(); }
    if (t == 0) { if (c < 128) s1[c] = red[0]; else sf[c - 128] = red[0]; }
}

__global__ void assemble_mu_kernel(const float* __restrict__ s1, const float* __restrict__ sf,
                                   const float* __restrict__ w2t, const float* __restrict__ b2,
                                   float* __restrict__ mu, float* __restrict__ w2s1) {
    int t = blockIdx.x * 256 + threadIdx.x;  // < 512
    const float inv_n = 1.0f / (float)NROW;
    if (t < 256) {
        mu[t] = sf[t] * (1.0f / (float)GT);
    } else {
        int c = t - 256;
        float s = 0.f;
        for (int k = 0; k < 128; ++k) s = __fmaf_rn(w2t[k*256 + c], s1[k], s);
        w2s1[c] = s;
        mu[t] = (s + (float)NROW * b2[c]) * inv_n;
    }
}

// C[i,j] = sum_k A[k*lda+i] * B[k*ldb+j]   (TN gemm, all dims % 16 == 0)
__global__ __launch_bounds__(256) void gemm_tn_kernel(float* __restrict__ Cm,
                                                      const float* __restrict__ Am, const float* __restrict__ Bm,
                                                      int M, int N, int Kd, int lda, int ldb) {
    __shared__ float As[16][17], Bs[16][17];
    int tx = threadIdx.x & 15, ty = threadIdx.x >> 4;
    int j = blockIdx.x * 16 + tx;
    int i = blockIdx.y * 16 + ty;
    float acc = 0.f;
    for (int k0 = 0; k0 < Kd; k0 += 16) {
        As[ty][tx] = Am[(size_t)(k0 + ty) * lda + blockIdx.y*16 + tx];
        Bs[ty][tx] = Bm[(size_t)(k0 + ty) * ldb + blockIdx.x*16 + tx];
        __syncthreads();
#pragma unroll
        for (int kk = 0; kk < 16; ++kk) acc = __fmaf_rn(As[kk][ty], Bs[kk][tx], acc);
        __syncthreads();
    }
    Cm[(size_t)i * N + j] = acc;
}

// bn3 stats from quadratic forms: var_c = w3_c S w3_c^T / n - mean^2
__global__ __launch_bounds__(256) void bn3_params_kernel(const float* __restrict__ w3, const float* __restrict__ b3,
        const float* __restrict__ g3, const float* __restrict__ bt3,
        const float* __restrict__ sff, const float* __restrict__ sfc, const float* __restrict__ sccw,
        const float* __restrict__ sf, const float* __restrict__ w2s1, const float* __restrict__ b2,
        const float* __restrict__ mu, float* __restrict__ bn3a, float* __restrict__ bn3d) {
    int c = blockIdx.x, t = threadIdx.x;
    __shared__ float wL[512];
    __shared__ float red[256];
    wL[t]       = w3[(size_t)c*512 + t];
    wL[256 + t] = w3[(size_t)c*512 + 256 + t];
    __syncthreads();
    float v1 = 0.f, v2 = 0.f, v3 = 0.f;
    for (int i = 0; i < 256; ++i) {
        float wfi = wL[i], wci = wL[256 + i];
        v1 = __fmaf_rn(wfi, sff[(size_t)i*256 + t], v1);
        v2 = __fmaf_rn(wfi, sfc[(size_t)i*256 + t], v2);
        v3 = __fmaf_rn(wci, sccw[(size_t)i*256 + t], v3);
    }
    float wf_t = wL[t], wc_t = wL[256 + t];
    float vals[7];
    vals[0] = v1 * wf_t;           // wf Sff_raw wf (col partial)
    vals[1] = v2 * wc_t;           // wf Sfc_mat wc
    vals[2] = v3 * wc_t;           // wc Sccw wc
    vals[3] = wf_t * sf[t];        // wf . sf
    vals[4] = wc_t * b2[t];        // wc . b2
    vals[5] = wc_t * w2s1[t];      // wc . W2s1
    vals[6] = wf_t * mu[t] + wc_t * mu[256 + t];  // w . mu
    float sums[7];
    for (int q = 0; q < 7; ++q) {
        red[t] = vals[q]; __syncthreads();
        for (int w = 128; w; w >>= 1) { if (t < w) red[t] += red[t + w]; __syncthreads(); }
        sums[q] = red[0]; __syncthreads();
    }
    if (t == 0) {
        float n = (float)NROW;
        float Q = 32.f*sums[0] + 2.f*(sums[1] + 32.f*sums[3]*sums[4])
                + sums[2] + 2.f*sums[5]*sums[4] + n*sums[4]*sums[4];
        float m3 = sums[6] + b3[c];
        float E2 = Q / n + 2.f*b3[c]*sums[6] + b3[c]*b3[c];
        float var = E2 - m3*m3;
        float a = rsqrtf(var + EPS) * g3[c];
        bn3a[c] = a;
        bn3d[c] = (b3[c] - m3) * a + bt3[c];
    }
}

// =================== P3: fused f1/f2 -> mm3 -> bn3+relu -> mm4 -> maxpool ===================
// One block per group. LDS pool with region reuse (50.7 KB -> 3 blocks/CU).
__global__ __launch_bounds__(256) void p3_kernel(const float* __restrict__ nbg, const float* __restrict__ w1,
        const float* __restrict__ bn1a, const float* __restrict__ bn1d,
        const float* __restrict__ w2t, const float* __restrict__ b2,
        const float* __restrict__ fgb,
        const float* __restrict__ w3t, const float* __restrict__ bn3a, const float* __restrict__ bn3d,
        const float* __restrict__ w4t, const float* __restrict__ b4,
        float* __restrict__ out) {
    __shared__ float pool[12672];
    float* f2s = pool;             // [32][256], dead after mm3
    float* f1s = pool + 8192;      // [32][129], dead after f2
    float* fgs = pool + 12320;     // [256]
    float* nbs = pool + 12576;     // [96]
    float* f3s = pool;             // [32][256] half of f3n, overlaps f2s (post-mm3)
    float* redb = pool + 8192;     // [8][384] epilogue, overlaps f1s (dead)
    int t = threadIdx.x;
    int g = blockIdx.x;
    int tx = t & 31, ty = t >> 5;

    if (t < 96) nbs[t] = nbg[(size_t)g * 96 + t];
    fgs[t] = fgb[(size_t)g * 256 + t];
    __syncthreads();
    compute_f1(nbs, w1, bn1a, bn1d, f1s, t);
    __syncthreads();
    compute_f2(f1s, w2t, b2, f2s, t);
    __syncthreads();

    // ---- mm3: f3[r][c] = sum_k in[r][k] * W3T[k][c], rows=ty*4.., cols=tx+32j ----
    float acc3[4][16];
#pragma unroll
    for (int rr = 0; rr < 4; ++rr)
#pragma unroll
        for (int j = 0; j < 16; ++j) acc3[rr][j] = 0.f;
    // k < 256: broadcast fg (row-independent)
    for (int k = 0; k < 256; ++k) {
        float av = fgs[k];
        const float* wr = w3t + (size_t)k * 512 + tx;
#pragma unroll
        for (int j = 0; j < 16; ++j) {
            float bw = wr[32*j];
            acc3[0][j] = __fmaf_rn(av, bw, acc3[0][j]);
            acc3[1][j] = __fmaf_rn(av, bw, acc3[1][j]);
            acc3[2][j] = __fmaf_rn(av, bw, acc3[2][j]);
            acc3[3][j] = __fmaf_rn(av, bw, acc3[3][j]);
        }
    }
    // k >= 256: f2 part
    for (int k = 0; k < 256; ++k) {
        float a0 = f2s[(ty*4+0)*256 + k];
        float a1 = f2s[(ty*4+1)*256 + k];
        float a2 = f2s[(ty*4+2)*256 + k];
        float a3 = f2s[(ty*4+3)*256 + k];
        const float* wr = w3t + (size_t)(k + 256) * 512 + tx;
#pragma unroll
        for (int j = 0; j < 16; ++j) {
            float bw = wr[32*j];
            acc3[0][j] = __fmaf_rn(a0, bw, acc3[0][j]);
            acc3[1][j] = __fmaf_rn(a1, bw, acc3[1][j]);
            acc3[2][j] = __fmaf_rn(a2, bw, acc3[2][j]);
            acc3[3][j] = __fmaf_rn(a3, bw, acc3[3][j]);
        }
    }
    __syncthreads();  // all f2s reads done -> safe to overwrite with f3s

    // bn3+relu, write first half (c < 256)
#pragma unroll
    for (int j = 0; j < 8; ++j) {
        int cc = tx + 32*j;
        float a = bn3a[cc], d = bn3d[cc];
#pragma unroll
        for (int rr = 0; rr < 4; ++rr) {
            float v = __fmaf_rn(acc3[rr][j], a, d);
            f3s[(ty*4+rr)*256 + cc] = fmaxf(v, 0.f);
        }
    }
    __syncthreads();

    // ---- mm4 over c in two halves; outputs o = tx + 32j, j<12 ----
    float acc4[4][12];
#pragma unroll
    for (int rr = 0; rr < 4; ++rr)
#pragma unroll
        for (int j = 0; j < 12; ++j) acc4[rr][j] = 0.f;
    for (int cph = 0; cph < 2; ++cph) {
        int cbase = cph * 256;
        for (int cc = 0; cc < 256; ++cc) {
            float a0 = f3s[(ty*4+0)*256 + cc];
            float a1 = f3s[(ty*4+1)*256 + cc];
            float a2 = f3s[(ty*4+2)*256 + cc];
            float a3 = f3s[(ty*4+3)*256 + cc];
            const float* wr = w4t + (size_t)(cbase + cc) * 384 + tx;
#pragma unroll
            for (int j = 0; j < 12; ++j) {
                float bw = wr[32*j];
                acc4[0][j] = __fmaf_rn(a0, bw, acc4[0][j]);
                acc4[1][j] = __fmaf_rn(a1, bw, acc4[1][j]);
                acc4[2][j] = __fmaf_rn(a2, bw, acc4[2][j]);
                acc4[3][j] = __fmaf_rn(a3, bw, acc4[3][j]);
            }
        }
        if (cph == 0) {
            __syncthreads();  // all reads of half1 done
#pragma unroll
            for (int j = 8; j < 16; ++j) {
                int cc = tx + 32*j;          // in [256,512)
                float a = bn3a[cc], d = bn3d[cc];
#pragma unroll
                for (int rr = 0; rr < 4; ++rr) {
                    float v = __fmaf_rn(acc3[rr][j], a, d);
                    f3s[(ty*4+rr)*256 + (cc - 256)] = fmaxf(v, 0.f);
                }
            }
            __syncthreads();
        }
    }

    // ---- epilogue: max over 32 rows, + b4 ----
#pragma unroll
    for (int j = 0; j < 12; ++j) {
        float m = fmaxf(fmaxf(acc4[0][j], acc4[1][j]), fmaxf(acc4[2][j], acc4[3][j]));
        redb[ty*384 + tx + 32*j] = m;
    }
    __syncthreads();
    if (t < 192) {
#pragma unroll
        for (int rep = 0; rep < 2; ++rep) {
            int o = t + 192*rep;
            float m = redb[o];
#pragma unroll
            for (int w = 1; w < 8; ++w) m = fmaxf(m, redb[w*384 + o]);
            out[(size_t)g * 384 + o] = m + b4[o];
        }
    }
}

// =================== launch ===================
extern "C" void kernel_launch(void* const* d_in, const int* in_sizes, int n_in,
                              void* d_out, int out_size, void* d_ws, size_t ws_size,
                              hipStream_t stream) {
    const float* xyz = (const float*)d_in[0];
    const float* w1  = (const float*)d_in[1];
    const float* b1  = (const float*)d_in[2];
    const float* g1  = (const float*)d_in[3];
    const float* bt1 = (const float*)d_in[4];
    const float* w2  = (const float*)d_in[5];
    const float* b2  = (const float*)d_in[6];
    const float* w3  = (const float*)d_in[7];
    const float* b3  = (const float*)d_in[8];
    const float* g3  = (const float*)d_in[9];
    const float* bt3 = (const float*)d_in[10];
    const float* w4  = (const float*)d_in[11];
    const float* b4  = (const float*)d_in[12];
    float* out = (float*)d_out;
    float* ws  = (float*)d_ws;

    if (ws_size < WS_FLOATS * sizeof(float)) return;  // leaves poison -> clean mismatch signal

    float* centers = ws + OFF_CENTERS;
    float* nb      = ws + OFF_NB;
    float* fgB     = ws + OFF_FG;
    float* c1B     = ws + OFF_C1;
    float* mom     = ws + OFF_MOM;
    float* A       = ws + OFF_A;
    float* s1      = ws + OFF_S1;
    float* sf      = ws + OFF_SF;
    float* mu      = ws + OFF_MU;
    float* w2s1    = ws + OFF_W2S1;
    float* bn1a    = ws + OFF_BN1A;
    float* bn1d    = ws + OFF_BN1D;
    float* bn3a    = ws + OFF_BN3A;
    float* bn3d    = ws + OFF_BN3D;
    float* sff     = ws + OFF_SFF;
    float* pfct    = ws + OFF_PFCT;
    float* t1m     = ws + OFF_T1;
    float* sccw    = ws + OFF_SCCW;
    float* sfcm    = ws + OFF_SFC;
    float* w2t     = ws + OFF_W2T;
    float* w3t     = ws + OFF_W3T;
    float* w4t     = ws + OFF_W4T;
    float* apart   = ws + OFF_APART;

    zero_mom_kernel<<<1, 64, 0, stream>>>(mom);
    fps_kernel<<<B_, 1024, 0, stream>>>(xyz, centers);
    knn_kernel<<<GT, 256, 0, stream>>>(xyz, centers, nb);
    moments_kernel<<<NROW/256, 256, 0, stream>>>(nb, mom);
    bn1_params_kernel<<<1, 128, 0, stream>>>(mom, w1, b1, g1, bt1, bn1a, bn1d);
    transpose_kernel<<<(256*128 + 255)/256, 256, 0, stream>>>(w2t, w2, 256, 128);
    transpose_kernel<<<(512*512 + 255)/256, 256, 0, stream>>>(w3t, w3, 512, 512);
    transpose_kernel<<<(384*512 + 255)/256, 256, 0, stream>>>(w4t, w4, 384, 512);
    p1_kernel<<<512, 256, 0, stream>>>(nb, w1, bn1a, bn1d, w2t, b2, fgB, c1B, apart);
    reduce_a_kernel<<<64, 256, 0, stream>>>(apart, A);
    reduce_cf_kernel<<<384, 256, 0, stream>>>(c1B, fgB, s1, sf);
    assemble_mu_kernel<<<2, 256, 0, stream>>>(s1, sf, w2t, b2, mu, w2s1);
    // S assembly gemms (all TN: C[i,j] = sum_k A[k][i] B[k][j])
    gemm_tn_kernel<<<dim3(16,16), 256, 0, stream>>>(sff,  fgB,  fgB, 256, 256, GT,  256, 256);
    gemm_tn_kernel<<<dim3(16, 8), 256, 0, stream>>>(pfct, c1B,  fgB, 128, 256, GT,  128, 256);
    gemm_tn_kernel<<<dim3(16, 8), 256, 0, stream>>>(t1m,  A,    w2t, 128, 256, 128, 128, 256);
    gemm_tn_kernel<<<dim3(16,16), 256, 0, stream>>>(sccw, w2t,  t1m, 256, 256, 128, 256, 256);
    gemm_tn_kernel<<<dim3(16,16), 256, 0, stream>>>(sfcm, pfct, w2t, 256, 256, 128, 256, 256);
    bn3_params_kernel<<<512, 256, 0, stream>>>(w3, b3, g3, bt3, sff, sfcm, sccw, sf, w2s1, b2, mu, bn3a, bn3d);
    p3_kernel<<<GT, 256, 0, stream>>>(nb, w1, bn1a, bn1d, w2t, b2, fgB, w3t, bn3a, bn3d, w4t, b4, out);
}

// Round 2
// 4299.796 us; speedup vs baseline: 1.7297x; 1.7297x over previous
//
#include <hip/hip_runtime.h>
#include <cstddef>

#define B_   16
#define N_   8192
#define G_   512
#define K_   32
#define GT   8192          // B_*G_
#define NROW 262144        // GT*K_
#define EPS  1e-5f

typedef unsigned short ushort_t;
typedef short bf16x8 __attribute__((ext_vector_type(8)));
typedef float f32x4  __attribute__((ext_vector_type(4)));

// ---------------- workspace layout (float offsets) ----------------
constexpr size_t OFF_CENTERS = 0;                          // B*G*3
constexpr size_t OFF_NB      = OFF_CENTERS + 24576;        // GT*K*3
constexpr size_t OFF_FG      = OFF_NB      + 786432;       // GT*256
constexpr size_t OFF_C1      = OFF_FG      + 2097152;      // GT*128
constexpr size_t OFF_MOM     = OFF_C1      + 1048576;      // 16
constexpr size_t OFF_A       = OFF_MOM     + 16;           // 128*128
constexpr size_t OFF_S1      = OFF_A       + 16384;        // 128
constexpr size_t OFF_SF      = OFF_S1      + 128;          // 256
constexpr size_t OFF_MU      = OFF_SF      + 256;          // 512
constexpr size_t OFF_W2S1    = OFF_MU      + 512;          // 256
constexpr size_t OFF_BN1A    = OFF_W2S1    + 256;          // 128
constexpr size_t OFF_BN1D    = OFF_BN1A    + 128;          // 128
constexpr size_t OFF_BN3A    = OFF_BN1D    + 128;          // 512
constexpr size_t OFF_BN3D    = OFF_BN3A    + 512;          // 512
constexpr size_t OFF_SFF     = OFF_BN3D    + 512;          // 256*256
constexpr size_t OFF_PFCT    = OFF_SFF     + 65536;        // 128*256
constexpr size_t OFF_T1      = OFF_PFCT    + 32768;        // 128*256
constexpr size_t OFF_SCCW    = OFF_T1      + 32768;        // 256*256
constexpr size_t OFF_SFC     = OFF_SCCW    + 65536;        // 256*256
constexpr size_t OFF_W2T     = OFF_SFC     + 65536;        // 128*256
constexpr size_t OFF_W3T     = OFF_W2T     + 32768;        // 512*512
constexpr size_t OFF_W4H     = OFF_W3T     + 262144;       // 196608 ushorts (bf16 hi of w4)
constexpr size_t OFF_W4L     = OFF_W4H     + 98304;        // 196608 ushorts
constexpr size_t OFF_APART   = OFF_W4L     + 98304;        // 512 blocks * 16384
constexpr size_t OFF_W23     = OFF_APART   + 8388608;      // 512*128 f32
constexpr size_t OFF_W23H    = OFF_W23     + 65536;        // 65536 ushorts
constexpr size_t OFF_W23L    = OFF_W23H    + 32768;        // 65536 ushorts
constexpr size_t WS_FLOATS   = OFF_W23L    + 32768;        // ~53.0 MB
constexpr size_t OFF_BASE3   = OFF_APART;                  // alias: base3 [8192][512] after reduce_a

// =================== FPS ===================
__global__ __launch_bounds__(1024) void fps_kernel(const float* __restrict__ xyz,
                                                   float* __restrict__ centers) {
    int b = blockIdx.x, t = threadIdx.x;
    const float* xb = xyz + (size_t)b * N_ * 3;
    float px[8], py[8], pz[8], dist[8];
#pragma unroll
    for (int i = 0; i < 8; ++i) {
        int p = t + (i << 10);
        px[i] = xb[p*3]; py[i] = xb[p*3+1]; pz[i] = xb[p*3+2];
        dist[i] = 1e10f;
    }
    __shared__ float cx, cy, cz;
    __shared__ int farS;
    __shared__ float redV[16];
    __shared__ int   redI[16];
    if (t == 0) farS = 0;
    __syncthreads();
    for (int it = 0; it < G_; ++it) {
        int far = farS;
        if ((far & 1023) == t) {
            int i = far >> 10;
            cx = px[i]; cy = py[i]; cz = pz[i];
            float* cd = centers + ((size_t)b * G_ + it) * 3;
            cd[0] = px[i]; cd[1] = py[i]; cd[2] = pz[i];
        }
        __syncthreads();
        float lcx = cx, lcy = cy, lcz = cz;
        float bv = -1.0f; int bp = 0;
#pragma unroll
        for (int i = 0; i < 8; ++i) {
            float dx = __fsub_rn(px[i], lcx);
            float dy = __fsub_rn(py[i], lcy);
            float dz = __fsub_rn(pz[i], lcz);
            float d  = __fadd_rn(__fadd_rn(__fmul_rn(dx,dx), __fmul_rn(dy,dy)), __fmul_rn(dz,dz));
            float nd = fminf(dist[i], d);
            dist[i] = nd;
            if (nd > bv) { bv = nd; bp = t + (i << 10); }
        }
#pragma unroll
        for (int off = 1; off < 64; off <<= 1) {
            float ov = __shfl_xor(bv, off);
            int   op = __shfl_xor(bp, off);
            if (ov > bv || (ov == bv && op < bp)) { bv = ov; bp = op; }
        }
        if ((t & 63) == 0) { redV[t >> 6] = bv; redI[t >> 6] = bp; }
        __syncthreads();
        if (t < 16) {
            float v = redV[t]; int p = redI[t];
#pragma unroll
            for (int off = 1; off < 16; off <<= 1) {
                float ov = __shfl_xor(v, off, 16);
                int   op = __shfl_xor(p, off, 16);
                if (ov > v || (ov == v && op < p)) { v = ov; p = op; }
            }
            if (t == 0) farS = p;
        }
        __syncthreads();
    }
}

// =================== kNN + gather(centered) ===================
__global__ __launch_bounds__(256) void knn_kernel(const float* __restrict__ xyz,
                                                  const float* __restrict__ centers,
                                                  float* __restrict__ nb) {
    int g = blockIdx.x, t = threadIdx.x;
    int b = g >> 9;
    const float* xb = xyz + (size_t)b * N_ * 3;
    const float* c  = centers + (size_t)g * 3;
    float lcx = c[0], lcy = c[1], lcz = c[2];
    float cn2 = __fadd_rn(__fadd_rn(__fmul_rn(lcx,lcx), __fmul_rn(lcy,lcy)), __fmul_rn(lcz,lcz));
    __shared__ float distL[N_];
    __shared__ int   sel[K_];
    __shared__ float redV[4];
    __shared__ int   redI[4];
#pragma unroll 4
    for (int i = 0; i < 32; ++i) {
        int p = t + (i << 8);
        float x = xb[p*3], y = xb[p*3+1], z = xb[p*3+2];
        float pn2 = __fadd_rn(__fadd_rn(__fmul_rn(x,x), __fmul_rn(y,y)), __fmul_rn(z,z));
        float dot = __fadd_rn(__fadd_rn(__fmul_rn(lcx,x), __fmul_rn(lcy,y)), __fmul_rn(lcz,z));
        float d   = __fadd_rn(__fadd_rn(__fmul_rn(-2.0f,dot), cn2), pn2);
        distL[p] = d;
    }
    __syncthreads();
    for (int s = 0; s < K_; ++s) {
        float bv = 1e30f; int bp = 0;
#pragma unroll 4
        for (int i = 0; i < 32; ++i) {
            int p = t + (i << 8);
            float v = distL[p];
            if (v < bv) { bv = v; bp = p; }
        }
#pragma unroll
        for (int off = 1; off < 64; off <<= 1) {
            float ov = __shfl_xor(bv, off);
            int   op = __shfl_xor(bp, off);
            if (ov < bv || (ov == bv && op < bp)) { bv = ov; bp = op; }
        }
        if ((t & 63) == 0) { redV[t >> 6] = bv; redI[t >> 6] = bp; }
        __syncthreads();
        if (t == 0) {
            float v = redV[0]; int p = redI[0];
            for (int w = 1; w < 4; ++w) {
                float ov = redV[w]; int op = redI[w];
                if (ov < v || (ov == v && op < p)) { v = ov; p = op; }
            }
            sel[s] = p; distL[p] = 1e30f;
        }
        __syncthreads();
    }
    if (t < K_) {
        int p = sel[t];
        float* dst = nb + ((size_t)g * K_ + t) * 3;
        dst[0] = xb[p*3]   - lcx;
        dst[1] = xb[p*3+1] - lcy;
        dst[2] = xb[p*3+2] - lcz;
    }
}

// =================== small utility kernels ===================
__global__ void zero_mom_kernel(float* __restrict__ mom) {
    if (threadIdx.x < 16) mom[threadIdx.x] = 0.0f;
}

__global__ void moments_kernel(const float* __restrict__ nb, float* __restrict__ mom) {
    int idx = blockIdx.x * blockDim.x + threadIdx.x;
    float x = 0.f, y = 0.f, z = 0.f;
    if (idx < NROW) { x = nb[idx*3]; y = nb[idx*3+1]; z = nb[idx*3+2]; }
    float v[9] = {x, y, z, x*x, y*y, z*z, x*y, x*z, y*z};
#pragma unroll
    for (int q = 0; q < 9; ++q) {
        float s = v[q];
#pragma unroll
        for (int off = 32; off; off >>= 1) s += __shfl_xor(s, off);
        if ((threadIdx.x & 63) == 0) atomicAdd(&mom[q], s);
    }
}

__global__ void bn1_params_kernel(const float* __restrict__ mom,
                                  const float* __restrict__ w1, const float* __restrict__ b1,
                                  const float* __restrict__ g1, const float* __restrict__ bt1,
                                  float* __restrict__ bn1a, float* __restrict__ bn1d) {
    int c = threadIdx.x;  // 128
    const float inv_n = 1.0f / (float)NROW;
    float mx = mom[0]*inv_n, my = mom[1]*inv_n, mz = mom[2]*inv_n;
    float cxx = mom[3]*inv_n - mx*mx, cyy = mom[4]*inv_n - my*my, czz = mom[5]*inv_n - mz*mz;
    float cxy = mom[6]*inv_n - mx*my, cxz = mom[7]*inv_n - mx*mz, cyz = mom[8]*inv_n - my*mz;
    float wx = w1[c*3], wy = w1[c*3+1], wz = w1[c*3+2];
    float mean = wx*mx + wy*my + wz*mz + b1[c];
    float var  = wx*wx*cxx + wy*wy*cyy + wz*wz*czz
               + 2.0f*(wx*wy*cxy + wx*wz*cxz + wy*wz*cyz);
    float a = rsqrtf(var + EPS) * g1[c];
    bn1a[c] = a;
    bn1d[c] = (b1[c] - mean) * a + bt1[c];
}

__global__ void transpose_kernel(float* __restrict__ out, const float* __restrict__ in, int R, int C) {
    int t = blockIdx.x * blockDim.x + threadIdx.x;
    if (t < R * C) {
        int i = t / C, j = t % C;
        out[(size_t)j * R + i] = in[t];
    }
}

// split f32 -> bf16 hi (RNE) + bf16 lo (RNE of residual)
__global__ void split_kernel(const float* __restrict__ src, ushort_t* __restrict__ hi,
                             ushort_t* __restrict__ lo, int n) {
    int i = blockIdx.x * 256 + threadIdx.x;
    if (i < n) {
        float v = src[i];
        unsigned u = __float_as_uint(v);
        unsigned h = (u + 0x7fffu + ((u >> 16) & 1u)) >> 16;
        hi[i] = (ushort_t)h;
        float r = v - __uint_as_float(h << 16);
        unsigned u2 = __float_as_uint(r);
        lo[i] = (ushort_t)((u2 + 0x7fffu + ((u2 >> 16) & 1u)) >> 16);
    }
}

// =================== shared f1/f2 computation (exact arithmetic, fmaf-pinned) ===================
__device__ __forceinline__ void compute_f1(const float* __restrict__ nbs, const float* __restrict__ w1,
                                           const float* __restrict__ bn1a, const float* __restrict__ bn1d,
                                           float* __restrict__ f1s, int t) {
    if (t < 128) {
        float a = bn1a[t], d = bn1d[t];
        float w0 = w1[t*3], wa = w1[t*3+1], wb = w1[t*3+2];
#pragma unroll 4
        for (int r = 0; r < 32; ++r) {
            float m = __fmul_rn(nbs[r*3], w0);
            m = __fmaf_rn(nbs[r*3+1], wa, m);
            m = __fmaf_rn(nbs[r*3+2], wb, m);
            m = __fmaf_rn(m, a, d);
            f1s[r*129 + t] = fmaxf(m, 0.0f);
        }
    }
}

__device__ __forceinline__ void compute_f2(const float* __restrict__ f1s, const float* __restrict__ w2t,
                                           const float* __restrict__ b2, float* __restrict__ f2s, int t) {
    int rb = t >> 6, cb = t & 63;     // 8-row x 4-col micro tile
    float4 bv = *reinterpret_cast<const float4*>(&b2[cb*4]);
    float acc[8][4];
#pragma unroll
    for (int m = 0; m < 8; ++m) { acc[m][0]=bv.x; acc[m][1]=bv.y; acc[m][2]=bv.z; acc[m][3]=bv.w; }
    for (int k = 0; k < 128; ++k) {
        float4 wv = *reinterpret_cast<const float4*>(&w2t[k*256 + cb*4]);
#pragma unroll
        for (int m = 0; m < 8; ++m) {
            float fv = f1s[(rb*8 + m)*129 + k];
            acc[m][0] = __fmaf_rn(fv, wv.x, acc[m][0]);
            acc[m][1] = __fmaf_rn(fv, wv.y, acc[m][1]);
            acc[m][2] = __fmaf_rn(fv, wv.z, acc[m][2]);
            acc[m][3] = __fmaf_rn(fv, wv.w, acc[m][3]);
        }
    }
#pragma unroll
    for (int m = 0; m < 8; ++m) {
        float4 o; o.x=acc[m][0]; o.y=acc[m][1]; o.z=acc[m][2]; o.w=acc[m][3];
        *reinterpret_cast<float4*>(&f2s[(rb*8 + m)*256 + cb*4]) = o;
    }
}

// =================== P1: per-group f1/f2 -> fg, c1, A-partials ===================
__global__ __launch_bounds__(256) void p1_kernel(const float* __restrict__ nbg, const float* __restrict__ w1,
                                                 const float* __restrict__ bn1a, const float* __restrict__ bn1d,
                                                 const float* __restrict__ w2t, const float* __restrict__ b2,
                                                 float* __restrict__ fg, float* __restrict__ c1,
                                                 float* __restrict__ apart) {
    __shared__ float f1s[32*129];
    __shared__ float f2s[32*256];
    __shared__ float nbs[96];
    int t = threadIdx.x;
    int i0 = (t >> 4) * 8, j0 = (t & 15) * 8;
    float accA[8][8];
#pragma unroll
    for (int m = 0; m < 8; ++m)
#pragma unroll
        for (int n = 0; n < 8; ++n) accA[m][n] = 0.f;

    for (int gi = 0; gi < 16; ++gi) {
        int g = blockIdx.x * 16 + gi;
        if (t < 96) nbs[t] = nbg[(size_t)g * 96 + t];
        __syncthreads();
        compute_f1(nbs, w1, bn1a, bn1d, f1s, t);
        __syncthreads();
        compute_f2(f1s, w2t, b2, f2s, t);
        __syncthreads();
        {
            float mx = f2s[t];
#pragma unroll 4
            for (int r = 1; r < 32; ++r) mx = fmaxf(mx, f2s[r*256 + t]);
            fg[(size_t)g * 256 + t] = mx;
            if (t < 128) {
                float s = 0.f;
#pragma unroll 4
                for (int r = 0; r < 32; ++r) s = __fadd_rn(s, f1s[r*129 + t]);
                c1[(size_t)g * 128 + t] = s;
            }
        }
#pragma unroll 2
        for (int r = 0; r < 32; ++r) {
            float am[8], bn_[8];
#pragma unroll
            for (int m = 0; m < 8; ++m) am[m]  = f1s[r*129 + i0 + m];
#pragma unroll
            for (int n = 0; n < 8; ++n) bn_[n] = f1s[r*129 + j0 + n];
#pragma unroll
            for (int m = 0; m < 8; ++m)
#pragma unroll
                for (int n = 0; n < 8; ++n)
                    accA[m][n] = __fmaf_rn(am[m], bn_[n], accA[m][n]);
        }
        __syncthreads();
    }
    float* ap = apart + (size_t)blockIdx.x * 16384;
#pragma unroll
    for (int m = 0; m < 8; ++m)
#pragma unroll
        for (int n = 0; n < 8; ++n)
            ap[(i0 + m)*128 + j0 + n] = accA[m][n];
}

__global__ void reduce_a_kernel(const float* __restrict__ apart, float* __restrict__ A) {
    int e = blockIdx.x * 256 + threadIdx.x;  // < 16384
    float s = 0.f;
    for (int b = 0; b < 512; ++b) s = __fadd_rn(s, apart[(size_t)b * 16384 + e]);
    A[e] = s;
}

__global__ void reduce_cf_kernel(const float* __restrict__ c1, const float* __restrict__ fgb,
                                 float* __restrict__ s1, float* __restrict__ sf) {
    int c = blockIdx.x, t = threadIdx.x;  // 384 blocks
    __shared__ float red[256];
    float s = 0.f;
    if (c < 128) { for (int g = t; g < GT; g += 256) s += c1[(size_t)g*128 + c]; }
    else { int cc = c - 128; for (int g = t; g < GT; g += 256) s += fgb[(size_t)g*256 + cc]; }
    red[t] = s; __syncthreads();
    for (int w = 128; w; w >>= 1) { if (t < w) red[t] += red[t + w]; __syncthreads(); }
    if (t == 0) { if (c < 128) s1[c] = red[0]; else sf[c - 128] = red[0]; }
}

__global__ void assemble_mu_kernel(const float* __restrict__ s1, const float* __restrict__ sf,
                                   const float* __restrict__ w2t, const float* __restrict__ b2,
                                   float* __restrict__ mu, float* __restrict__ w2s1) {
    int t = blockIdx.x * 256 + threadIdx.x;  // < 512
    const float inv_n = 1.0f / (float)NROW;
    if (t < 256) {
        mu[t] = sf[t] * (1.0f / (float)GT);
    } else {
        int c = t - 256;
        float s = 0.f;
        for (int k = 0; k < 128; ++k) s = __fmaf_rn(w2t[k*256 + c], s1[k], s);
        w2s1[c] = s;
        mu[t] = (s + (float)NROW * b2[c]) * inv_n;
    }
}

// C[i,j] = sum_k A[k*lda+i] * B[k*ldb+j]   (TN gemm, all dims % 16 == 0)
__global__ __launch_bounds__(256) void gemm_tn_kernel(float* __restrict__ Cm,
                                                      const float* __restrict__ Am, const float* __restrict__ Bm,
                                                      int M, int N, int Kd, int lda, int ldb) {
    __shared__ float As[16][17], Bs[16][17];
    int tx = threadIdx.x & 15, ty = threadIdx.x >> 4;
    int j = blockIdx.x * 16 + tx;
    int i = blockIdx.y * 16 + ty;
    float acc = 0.f;
    for (int k0 = 0; k0 < Kd; k0 += 16) {
        As[ty][tx] = Am[(size_t)(k0 + ty) * lda + blockIdx.y*16 + tx];
        Bs[ty][tx] = Bm[(size_t)(k0 + ty) * ldb + blockIdx.x*16 + tx];
        __syncthreads();
#pragma unroll
        for (int kk = 0; kk < 16; ++kk) acc = __fmaf_rn(As[kk][ty], Bs[kk][tx], acc);
        __syncthreads();
    }
    Cm[(size_t)i * N + j] = acc;
}

// C[i,j] = sum_k A[i*lda+k] * B[k*ldb+j]   (NN gemm, M%64==0, N%64==0, K%16==0)
__global__ __launch_bounds__(256) void gemm_nn_kernel(float* __restrict__ Cm,
                                                      const float* __restrict__ Am, const float* __restrict__ Bm,
                                                      int M, int N, int Kd, int lda, int ldb) {
    __shared__ float As[16][65], Bs[16][65];
    int t = threadIdx.x;
    int i0 = blockIdx.y * 64, j0 = blockIdx.x * 64;
    int tx = t & 15, ty = t >> 4;
    int lr = t & 63, lk = t >> 6;
    float acc[4][4];
#pragma unroll
    for (int a = 0; a < 4; ++a)
#pragma unroll
        for (int b = 0; b < 4; ++b) acc[a][b] = 0.f;
    for (int k0 = 0; k0 < Kd; k0 += 16) {
#pragma unroll
        for (int u = 0; u < 4; ++u) {
            int k = lk*4 + u;
            As[k][lr] = Am[(size_t)(i0 + lr) * lda + k0 + k];
            Bs[k][lr] = Bm[(size_t)(k0 + k) * ldb + j0 + lr];
        }
        __syncthreads();
#pragma unroll
        for (int kk = 0; kk < 16; ++kk) {
            float av[4], bv[4];
#pragma unroll
            for (int u = 0; u < 4; ++u) av[u] = As[kk][ty*4+u];
#pragma unroll
            for (int u = 0; u < 4; ++u) bv[u] = Bs[kk][tx*4+u];
#pragma unroll
            for (int a = 0; a < 4; ++a)
#pragma unroll
                for (int b = 0; b < 4; ++b) acc[a][b] = __fmaf_rn(av[a], bv[b], acc[a][b]);
        }
        __syncthreads();
    }
#pragma unroll
    for (int a = 0; a < 4; ++a)
#pragma unroll
        for (int b = 0; b < 4; ++b)
            Cm[(size_t)(i0 + ty*4 + a) * N + j0 + tx*4 + b] = acc[a][b];
}

// bn3 stats from quadratic forms: var_c = w3_c S w3_c^T / n - mean^2
// bn3d now also folds in b23 = w3c . b2 (sums[4]) since p3 computes f1*W23 (bias-free).
__global__ __launch_bounds__(256) void bn3_params_kernel(const float* __restrict__ w3, const float* __restrict__ b3,
        const float* __restrict__ g3, const float* __restrict__ bt3,
        const float* __restrict__ sff, const float* __restrict__ sfc, const float* __restrict__ sccw,
        const float* __restrict__ sf, const float* __restrict__ w2s1, const float* __restrict__ b2,
        const float* __restrict__ mu, float* __restrict__ bn3a, float* __restrict__ bn3d) {
    int c = blockIdx.x, t = threadIdx.x;
    __shared__ float wL[512];
    __shared__ float red[256];
    wL[t]       = w3[(size_t)c*512 + t];
    wL[256 + t] = w3[(size_t)c*512 + 256 + t];
    __syncthreads();
    float v1 = 0.f, v2 = 0.f, v3 = 0.f;
    for (int i = 0; i < 256; ++i) {
        float wfi = wL[i], wci = wL[256 + i];
        v1 = __fmaf_rn(wfi, sff[(size_t)i*256 + t], v1);
        v2 = __fmaf_rn(wfi, sfc[(size_t)i*256 + t], v2);
        v3 = __fmaf_rn(wci, sccw[(size_t)i*256 + t], v3);
    }
    float wf_t = wL[t], wc_t = wL[256 + t];
    float vals[7];
    vals[0] = v1 * wf_t;
    vals[1] = v2 * wc_t;
    vals[2] = v3 * wc_t;
    vals[3] = wf_t * sf[t];
    vals[4] = wc_t * b2[t];
    vals[5] = wc_t * w2s1[t];
    vals[6] = wf_t * mu[t] + wc_t * mu[256 + t];
    float sums[7];
    for (int q = 0; q < 7; ++q) {
        red[t] = vals[q]; __syncthreads();
        for (int w = 128; w; w >>= 1) { if (t < w) red[t] += red[t + w]; __syncthreads(); }
        sums[q] = red[0]; __syncthreads();
    }
    if (t == 0) {
        float n = (float)NROW;
        float Q = 32.f*sums[0] + 2.f*(sums[1] + 32.f*sums[3]*sums[4])
                + sums[2] + 2.f*sums[5]*sums[4] + n*sums[4]*sums[4];
        float m3 = sums[6] + b3[c];
        float E2 = Q / n + 2.f*b3[c]*sums[6] + b3[c]*b3[c];
        float var = E2 - m3*m3;
        float a = rsqrtf(var + EPS) * g3[c];
        bn3a[c] = a;
        // d folds in b23 (= sums[4]) since mm3 acc = base3 + f1*W23 (no biases)
        bn3d[c] = (b3[c] + sums[4] - m3) * a + bt3[c];
    }
}

// =================== P3 (MFMA): f1 -> [base3 + f1*W23] -> bn3+relu -> *w4 -> maxpool ===================
// 2 groups (64 rows) per block, 4 waves in 2x2 tile grid, split-bf16 3-pass mfma_f32_16x16x32_bf16.
// f1 / f3-chunk staged hi+lo in LDS with XOR swizzle (byte ^= (row&7)<<4) for conflict-free ds_read_b128.
__global__ __launch_bounds__(256) void p3_mfma_kernel(
        const float* __restrict__ nbg, const float* __restrict__ w1,
        const float* __restrict__ bn1a, const float* __restrict__ bn1d,
        const ushort_t* __restrict__ w23h, const ushort_t* __restrict__ w23l,
        const ushort_t* __restrict__ w4h, const ushort_t* __restrict__ w4l,
        const float* __restrict__ base3, const float* __restrict__ bn3a, const float* __restrict__ bn3d,
        const float* __restrict__ b4, float* __restrict__ out) {
    __shared__ short f1h[8192], f1l[8192];   // [64 rows][128 ch] bf16
    __shared__ short f3h[8192], f3l[8192];   // [64 rows][128 chunk-ch] bf16
    __shared__ float nbs[192];
    int t = threadIdx.x;
    int g0 = blockIdx.x * 2;
    if (t < 192) nbs[t] = nbg[(size_t)g0 * 96 + t];
    __syncthreads();
    // ---- f1 = relu(bn1(nb*w1)), split to bf16 hi/lo, swizzled LDS store ----
    {
        int cp = t & 63;            // channel pair (2*cp, 2*cp+1)
        int r0 = (t >> 6) * 16;
        int c0 = cp * 2;
        float w00=w1[c0*3+0], w01=w1[c0*3+1], w02=w1[c0*3+2];
        float w10=w1[c0*3+3], w11=w1[c0*3+4], w12=w1[c0*3+5];
        float aA=bn1a[c0], dA=bn1d[c0], aB=bn1a[c0+1], dB=bn1d[c0+1];
        for (int rr = 0; rr < 16; ++rr) {
            int r = r0 + rr;
            float x = nbs[r*3], y = nbs[r*3+1], z = nbs[r*3+2];
            float mA = __fmul_rn(x, w00); mA = __fmaf_rn(y, w01, mA); mA = __fmaf_rn(z, w02, mA);
            mA = __fmaf_rn(mA, aA, dA); mA = fmaxf(mA, 0.f);
            float mB = __fmul_rn(x, w10); mB = __fmaf_rn(y, w11, mB); mB = __fmaf_rn(z, w12, mB);
            mB = __fmaf_rn(mB, aB, dB); mB = fmaxf(mB, 0.f);
            unsigned uA = __float_as_uint(mA), uB = __float_as_uint(mB);
            unsigned hA = (uA + 0x7fffu + ((uA>>16)&1u)) >> 16;
            unsigned hB = (uB + 0x7fffu + ((uB>>16)&1u)) >> 16;
            float rA = mA - __uint_as_float(hA<<16);
            float rB = mB - __uint_as_float(hB<<16);
            unsigned vA = __float_as_uint(rA), vB = __float_as_uint(rB);
            unsigned lA = (vA + 0x7fffu + ((vA>>16)&1u)) >> 16;
            unsigned lB = (vB + 0x7fffu + ((vB>>16)&1u)) >> 16;
            int off = r*256 + ((cp*4) ^ ((r&7)<<4));
            *(unsigned*)((char*)f1h + off) = hA | (hB << 16);
            *(unsigned*)((char*)f1l + off) = lA | (lB << 16);
        }
    }
    __syncthreads();

    int lane = t & 63, wid = t >> 6;
    int wm = wid >> 1, wn = wid & 1;    // wave row-half (=group), col-half
    int l15 = lane & 15, lh = lane >> 4;
    int g = g0 + wm;

    f32x4 acc4[2][12];
#pragma unroll
    for (int mt = 0; mt < 2; ++mt)
#pragma unroll
        for (int nt = 0; nt < 12; ++nt) acc4[mt][nt] = (f32x4){0.f, 0.f, 0.f, 0.f};

    for (int chunk = 0; chunk < 4; ++chunk) {
        // ---- mm3 chunk: acc3 = base3 + f1*W23[:,chunk] ----
        f32x4 acc3[2][4];
#pragma unroll
        for (int nt = 0; nt < 4; ++nt) {
            float bval = base3[(size_t)g*512 + chunk*128 + wn*64 + nt*16 + l15];
            f32x4 v = (f32x4){bval, bval, bval, bval};
            acc3[0][nt] = v; acc3[1][nt] = v;
        }
#pragma unroll
        for (int ks = 0; ks < 4; ++ks) {
            bf16x8 ah[2], al[2];
#pragma unroll
            for (int mt = 0; mt < 2; ++mt) {
                int row = wm*32 + mt*16 + l15;
                int off = row*256 + ((ks*64 + lh*16) ^ ((row&7)<<4));
                ah[mt] = *(bf16x8*)((char*)f1h + off);
                al[mt] = *(bf16x8*)((char*)f1l + off);
            }
#pragma unroll
            for (int nt = 0; nt < 4; ++nt) {
                int n = chunk*128 + wn*64 + nt*16 + l15;
                size_t wo = (size_t)n*128 + ks*32 + lh*8;
                bf16x8 bh = *(const bf16x8*)(w23h + wo);
                bf16x8 bl = *(const bf16x8*)(w23l + wo);
#pragma unroll
                for (int mt = 0; mt < 2; ++mt) {
                    acc3[mt][nt] = __builtin_amdgcn_mfma_f32_16x16x32_bf16(ah[mt], bh, acc3[mt][nt], 0, 0, 0);
                    acc3[mt][nt] = __builtin_amdgcn_mfma_f32_16x16x32_bf16(ah[mt], bl, acc3[mt][nt], 0, 0, 0);
                    acc3[mt][nt] = __builtin_amdgcn_mfma_f32_16x16x32_bf16(al[mt], bh, acc3[mt][nt], 0, 0, 0);
                }
            }
        }
        __syncthreads();   // previous chunk's mm4 reads of f3 are done
        // ---- bn3 + relu + split -> f3 LDS ----
#pragma unroll
        for (int nt = 0; nt < 4; ++nt) {
            int c = chunk*128 + wn*64 + nt*16 + l15;
            float a = bn3a[c], d = bn3d[c];
#pragma unroll
            for (int mt = 0; mt < 2; ++mt) {
#pragma unroll
                for (int q = 0; q < 4; ++q) {
                    float v = __fmaf_rn(acc3[mt][nt][q], a, d);
                    v = fmaxf(v, 0.f);
                    unsigned u = __float_as_uint(v);
                    unsigned h = (u + 0x7fffu + ((u>>16)&1u)) >> 16;
                    float r2 = v - __uint_as_float(h << 16);
                    unsigned u2 = __float_as_uint(r2);
                    unsigned lo = (u2 + 0x7fffu + ((u2>>16)&1u)) >> 16;
                    int row = wm*32 + mt*16 + lh*4 + q;
                    int colb = (wn*64 + nt*16 + l15) * 2;
                    int off = row*256 + (colb ^ ((row&7)<<4));
                    *(short*)((char*)f3h + off) = (short)h;
                    *(short*)((char*)f3l + off) = (short)lo;
                }
            }
        }
        __syncthreads();
        // ---- mm4 accumulate: acc4 += f3 * w4[:, chunk-k] ----
#pragma unroll
        for (int ks = 0; ks < 4; ++ks) {
            bf16x8 ah[2], al[2];
#pragma unroll
            for (int mt = 0; mt < 2; ++mt) {
                int row = wm*32 + mt*16 + l15;
                int off = row*256 + ((ks*64 + lh*16) ^ ((row&7)<<4));
                ah[mt] = *(bf16x8*)((char*)f3h + off);
                al[mt] = *(bf16x8*)((char*)f3l + off);
            }
#pragma unroll
            for (int nt = 0; nt < 12; ++nt) {
                int n = wn*192 + nt*16 + l15;
                size_t wo = (size_t)n*512 + chunk*128 + ks*32 + lh*8;
                bf16x8 bh = *(const bf16x8*)(w4h + wo);
                bf16x8 bl = *(const bf16x8*)(w4l + wo);
#pragma unroll
                for (int mt = 0; mt < 2; ++mt) {
                    acc4[mt][nt] = __builtin_amdgcn_mfma_f32_16x16x32_bf16(ah[mt], bh, acc4[mt][nt], 0, 0, 0);
                    acc4[mt][nt] = __builtin_amdgcn_mfma_f32_16x16x32_bf16(ah[mt], bl, acc4[mt][nt], 0, 0, 0);
                    acc4[mt][nt] = __builtin_amdgcn_mfma_f32_16x16x32_bf16(al[mt], bh, acc4[mt][nt], 0, 0, 0);
                }
            }
        }
    }
    // ---- epilogue: max over 32 rows of this wave's group, + b4 ----
#pragma unroll
    for (int nt = 0; nt < 12; ++nt) {
        int n = wn*192 + nt*16 + l15;
        float m = acc4[0][nt][0];
#pragma unroll
        for (int q = 1; q < 4; ++q) m = fmaxf(m, acc4[0][nt][q]);
#pragma unroll
        for (int q = 0; q < 4; ++q) m = fmaxf(m, acc4[1][nt][q]);
        m = fmaxf(m, __shfl_xor(m, 16));
        m = fmaxf(m, __shfl_xor(m, 32));
        if (lh == 0) out[(size_t)g*384 + n] = m + b4[n];
    }
}

// =================== launch ===================
extern "C" void kernel_launch(void* const* d_in, const int* in_sizes, int n_in,
                              void* d_out, int out_size, void* d_ws, size_t ws_size,
                              hipStream_t stream) {
    const float* xyz = (const float*)d_in[0];
    const float* w1  = (const float*)d_in[1];
    const float* b1  = (const float*)d_in[2];
    const float* g1  = (const float*)d_in[3];
    const float* bt1 = (const float*)d_in[4];
    const float* w2  = (const float*)d_in[5];
    const float* b2  = (const float*)d_in[6];
    const float* w3  = (const float*)d_in[7];
    const float* b3  = (const float*)d_in[8];
    const float* g3  = (const float*)d_in[9];
    const float* bt3 = (const float*)d_in[10];
    const float* w4  = (const float*)d_in[11];
    const float* b4  = (const float*)d_in[12];
    float* out = (float*)d_out;
    float* ws  = (float*)d_ws;

    if (ws_size < WS_FLOATS * sizeof(float)) return;  // leaves poison -> clean mismatch signal

    float* centers = ws + OFF_CENTERS;
    float* nb      = ws + OFF_NB;
    float* fgB     = ws + OFF_FG;
    float* c1B     = ws + OFF_C1;
    float* mom     = ws + OFF_MOM;
    float* A       = ws + OFF_A;
    float* s1      = ws + OFF_S1;
    float* sf      = ws + OFF_SF;
    float* mu      = ws + OFF_MU;
    float* w2s1    = ws + OFF_W2S1;
    float* bn1a    = ws + OFF_BN1A;
    float* bn1d    = ws + OFF_BN1D;
    float* bn3a    = ws + OFF_BN3A;
    float* bn3d    = ws + OFF_BN3D;
    float* sff     = ws + OFF_SFF;
    float* pfct    = ws + OFF_PFCT;
    float* t1m     = ws + OFF_T1;
    float* sccw    = ws + OFF_SCCW;
    float* sfcm    = ws + OFF_SFC;
    float* w2t     = ws + OFF_W2T;
    float* w3t     = ws + OFF_W3T;
    ushort_t* w4h  = (ushort_t*)(ws + OFF_W4H);
    ushort_t* w4l  = (ushort_t*)(ws + OFF_W4L);
    float* apart   = ws + OFF_APART;
    float* w23     = ws + OFF_W23;
    ushort_t* w23h = (ushort_t*)(ws + OFF_W23H);
    ushort_t* w23l = (ushort_t*)(ws + OFF_W23L);
    float* base3   = ws + OFF_BASE3;   // aliases apart (valid after reduce_a)

    zero_mom_kernel<<<1, 64, 0, stream>>>(mom);
    fps_kernel<<<B_, 1024, 0, stream>>>(xyz, centers);
    knn_kernel<<<GT, 256, 0, stream>>>(xyz, centers, nb);
    moments_kernel<<<NROW/256, 256, 0, stream>>>(nb, mom);
    bn1_params_kernel<<<1, 128, 0, stream>>>(mom, w1, b1, g1, bt1, bn1a, bn1d);
    transpose_kernel<<<(256*128 + 255)/256, 256, 0, stream>>>(w2t, w2, 256, 128);
    transpose_kernel<<<(512*512 + 255)/256, 256, 0, stream>>>(w3t, w3, 512, 512);
    // W23[n][k] = sum_j w3[n][256+j] * w2[j][k]  (f2-linearity fold)
    gemm_tn_kernel<<<dim3(8, 32), 256, 0, stream>>>(w23, w3t + 256*512, w2, 512, 128, 256, 512, 128);
    split_kernel<<<(65536 + 255)/256, 256, 0, stream>>>(w23, w23h, w23l, 65536);
    split_kernel<<<(196608 + 255)/256, 256, 0, stream>>>(w4, w4h, w4l, 196608);
    p1_kernel<<<512, 256, 0, stream>>>(nb, w1, bn1a, bn1d, w2t, b2, fgB, c1B, apart);
    reduce_a_kernel<<<64, 256, 0, stream>>>(apart, A);
    // base3[g][n] = sum_{k<256} fg[g][k] * w3[n][k]   (overwrites apart region)
    gemm_nn_kernel<<<dim3(8, 128), 256, 0, stream>>>(base3, fgB, w3t, GT, 512, 256, 256, 512);
    reduce_cf_kernel<<<384, 256, 0, stream>>>(c1B, fgB, s1, sf);
    assemble_mu_kernel<<<2, 256, 0, stream>>>(s1, sf, w2t, b2, mu, w2s1);
    gemm_tn_kernel<<<dim3(16,16), 256, 0, stream>>>(sff,  fgB,  fgB, 256, 256, GT,  256, 256);
    gemm_tn_kernel<<<dim3(16, 8), 256, 0, stream>>>(pfct, c1B,  fgB, 128, 256, GT,  128, 256);
    gemm_tn_kernel<<<dim3(16, 8), 256, 0, stream>>>(t1m,  A,    w2t, 128, 256, 128, 128, 256);
    gemm_tn_kernel<<<dim3(16,16), 256, 0, stream>>>(sccw, w2t,  t1m, 256, 256, 128, 256, 256);
    gemm_tn_kernel<<<dim3(16,16), 256, 0, stream>>>(sfcm, pfct, w2t, 256, 256, 128, 256, 256);
    bn3_params_kernel<<<512, 256, 0, stream>>>(w3, b3, g3, bt3, sff, sfcm, sccw, sf, w2s1, b2, mu, bn3a, bn3d);
    p3_mfma_kernel<<<GT/2, 256, 0, stream>>>(nb, w1, bn1a, bn1d, w23h, w23l, w4h, w4l,
                                             base3, bn3a, bn3d, b4, out);
}

// Round 5
// 3624.829 us; speedup vs baseline: 2.0518x; 1.1862x over previous
//
#include <hip/hip_runtime.h>
#include <cstddef>

#define B_   16
#define N_   8192
#define G_   512
#define K_   32
#define GT   8192          // B_*G_
#define NROW 262144        // GT*K_
#define EPS  1e-5f

typedef unsigned short ushort_t;
typedef short bf16x8 __attribute__((ext_vector_type(8)));
typedef float f32x4  __attribute__((ext_vector_type(4)));

// ---------------- workspace layout (float offsets) ----------------
constexpr size_t OFF_CENTERS = 0;                          // B*G*3
constexpr size_t OFF_NB      = OFF_CENTERS + 24576;        // GT*K*3
constexpr size_t OFF_FG      = OFF_NB      + 786432;       // GT*256
constexpr size_t OFF_C1      = OFF_FG      + 2097152;      // GT*128
constexpr size_t OFF_MOM     = OFF_C1      + 1048576;      // 16
constexpr size_t OFF_A       = OFF_MOM     + 16;           // 128*128
constexpr size_t OFF_S1      = OFF_A       + 16384;        // 128
constexpr size_t OFF_SF      = OFF_S1      + 128;          // 256
constexpr size_t OFF_MU      = OFF_SF      + 256;          // 512
constexpr size_t OFF_W2S1    = OFF_MU      + 512;          // 256
constexpr size_t OFF_BN1A    = OFF_W2S1    + 256;          // 128
constexpr size_t OFF_BN1D    = OFF_BN1A    + 128;          // 128
constexpr size_t OFF_BN3A    = OFF_BN1D    + 128;          // 512
constexpr size_t OFF_BN3D    = OFF_BN3A    + 512;          // 512
constexpr size_t OFF_SFF     = OFF_BN3D    + 512;          // 256*256
constexpr size_t OFF_PFCT    = OFF_SFF     + 65536;        // 128*256
constexpr size_t OFF_T1      = OFF_PFCT    + 32768;        // 128*256
constexpr size_t OFF_SCCW    = OFF_T1      + 32768;        // 256*256
constexpr size_t OFF_SFC     = OFF_SCCW    + 65536;        // 256*256
constexpr size_t OFF_W2T     = OFF_SFC     + 65536;        // 128*256
constexpr size_t OFF_W3T     = OFF_W2T     + 32768;        // 512*512
constexpr size_t OFF_W4H     = OFF_W3T     + 262144;       // 196608 ushorts (bf16 hi of w4)
constexpr size_t OFF_W4L     = OFF_W4H     + 98304;        // 196608 ushorts
constexpr size_t OFF_APART   = OFF_W4L     + 98304;        // 512 blocks * 16384
constexpr size_t OFF_W23     = OFF_APART   + 8388608;      // 512*128 f32
constexpr size_t OFF_W23H    = OFF_W23     + 65536;        // 65536 ushorts
constexpr size_t OFF_W23L    = OFF_W23H    + 32768;        // 65536 ushorts
constexpr size_t WS_FLOATS   = OFF_W23L    + 32768;        // ~53.0 MB
constexpr size_t OFF_BASE3   = OFF_APART;                  // alias: base3 [8192][512] after reduce_a

__device__ __forceinline__ unsigned bf16_rne(float v) {
    unsigned u = __float_as_uint(v);
    return (u + 0x7fffu + ((u >> 16) & 1u)) >> 16;
}

// =================== FPS ===================
// One block per batch. Points + dists in registers. 2 barriers/iter:
// leaders write per-wave winners -> BAR -> all waves redundantly reduce 16
// partials (winner known everywhere), owner posts next center -> BAR.
__global__ __launch_bounds__(1024) void fps_kernel(const float* __restrict__ xyz,
                                                   float* __restrict__ centers) {
    int b = blockIdx.x, t = threadIdx.x;
    const float* xb = xyz + (size_t)b * N_ * 3;
    float px[8], py[8], pz[8], dist[8];
#pragma unroll
    for (int i = 0; i < 8; ++i) {
        int p = t + (i << 10);
        px[i] = xb[p*3]; py[i] = xb[p*3+1]; pz[i] = xb[p*3+2];
        dist[i] = 1e10f;
    }
    __shared__ float redV[2][16];
    __shared__ int   redI[2][16];
    __shared__ float cxyz[2][3];
    if (t == 0) { cxyz[0][0] = px[0]; cxyz[0][1] = py[0]; cxyz[0][2] = pz[0]; }
    __syncthreads();
    for (int it = 0; it < G_; ++it) {
        int cur = it & 1;
        float lcx = cxyz[cur][0], lcy = cxyz[cur][1], lcz = cxyz[cur][2];
        if (t == 0) {
            float* cd = centers + ((size_t)b * G_ + it) * 3;
            cd[0] = lcx; cd[1] = lcy; cd[2] = lcz;
        }
        float bv = -1.0f; int bp = 0;
#pragma unroll
        for (int i = 0; i < 8; ++i) {
            float dx = __fsub_rn(px[i], lcx);
            float dy = __fsub_rn(py[i], lcy);
            float dz = __fsub_rn(pz[i], lcz);
            float d  = __fadd_rn(__fadd_rn(__fmul_rn(dx,dx), __fmul_rn(dy,dy)), __fmul_rn(dz,dz));
            float nd = fminf(dist[i], d);
            dist[i] = nd;
            if (nd > bv) { bv = nd; bp = t + (i << 10); }
        }
#pragma unroll
        for (int off = 1; off < 64; off <<= 1) {
            float ov = __shfl_xor(bv, off);
            int   op = __shfl_xor(bp, off);
            if (ov > bv || (ov == bv && op < bp)) { bv = ov; bp = op; }
        }
        if ((t & 63) == 0) { redV[cur][t >> 6] = bv; redI[cur][t >> 6] = bp; }
        __syncthreads();
        // every wave reduces the 16 partials redundantly
        float v = redV[cur][t & 15]; int p = redI[cur][t & 15];
#pragma unroll
        for (int off = 1; off < 16; off <<= 1) {
            float ov = __shfl_xor(v, off);
            int   op = __shfl_xor(p, off);
            if (ov > v || (ov == v && op < p)) { v = ov; p = op; }
        }
        // owner posts next center coords
        if ((p & 1023) == t) {
            int i = p >> 10;
            cxyz[cur ^ 1][0] = px[i]; cxyz[cur ^ 1][1] = py[i]; cxyz[cur ^ 1][2] = pz[i];
        }
        __syncthreads();
    }
}

// =================== kNN + gather(centered) ===================
// Register-resident distances (32/thread). 1 barrier per selection pass.
// Tie-break = lowest index everywhere, matching lax.top_k.
__global__ __launch_bounds__(256) void knn_kernel(const float* __restrict__ xyz,
                                                  const float* __restrict__ centers,
                                                  float* __restrict__ nb) {
    int g = blockIdx.x, t = threadIdx.x;
    int b = g >> 9;
    const float* xb = xyz + (size_t)b * N_ * 3;
    const float* c  = centers + (size_t)g * 3;
    float lcx = c[0], lcy = c[1], lcz = c[2];
    float cn2 = __fadd_rn(__fadd_rn(__fmul_rn(lcx,lcx), __fmul_rn(lcy,lcy)), __fmul_rn(lcz,lcz));
    float dreg[32];
#pragma unroll 8
    for (int i = 0; i < 32; ++i) {
        int p = t + (i << 8);
        float x = xb[p*3], y = xb[p*3+1], z = xb[p*3+2];
        float pn2 = __fadd_rn(__fadd_rn(__fmul_rn(x,x), __fmul_rn(y,y)), __fmul_rn(z,z));
        float dot = __fadd_rn(__fadd_rn(__fmul_rn(lcx,x), __fmul_rn(lcy,y)), __fmul_rn(lcz,z));
        dreg[i]   = __fadd_rn(__fadd_rn(__fmul_rn(-2.0f,dot), cn2), pn2);
    }
    __shared__ float redV[2][4];
    __shared__ int   redI[2][4];
    int myp = 0;
    for (int s = 0; s < K_; ++s) {
        float bv = 1e30f; int bp = 0;
#pragma unroll
        for (int i = 0; i < 32; ++i) {
            float v = dreg[i];
            if (v < bv) { bv = v; bp = t + (i << 8); }
        }
#pragma unroll
        for (int off = 1; off < 64; off <<= 1) {
            float ov = __shfl_xor(bv, off);
            int   op = __shfl_xor(bp, off);
            if (ov < bv || (ov == bv && op < bp)) { bv = ov; bp = op; }
        }
        int buf = s & 1;
        if ((t & 63) == 0) { redV[buf][t >> 6] = bv; redI[buf][t >> 6] = bp; }
        __syncthreads();
        float v = redV[buf][0]; int p = redI[buf][0];
#pragma unroll
        for (int w = 1; w < 4; ++w) {
            float ov = redV[buf][w]; int op = redI[buf][w];
            if (ov < v || (ov == v && op < p)) { v = ov; p = op; }
        }
        if (s == t) myp = p;
#pragma unroll
        for (int i = 0; i < 32; ++i)
            if (p == t + (i << 8)) dreg[i] = 1e30f;
    }
    if (t < K_) {
        int p = myp;
        float* dst = nb + ((size_t)g * K_ + t) * 3;
        dst[0] = xb[p*3]   - lcx;
        dst[1] = xb[p*3+1] - lcy;
        dst[2] = xb[p*3+2] - lcz;
    }
}

// =================== small utility kernels ===================
__global__ void zero_mom_kernel(float* __restrict__ mom) {
    if (threadIdx.x < 16) mom[threadIdx.x] = 0.0f;
}

// first/second xyz moments of nb; block-level reduce -> 9 atomics per block
__global__ void moments_kernel(const float* __restrict__ nb, float* __restrict__ mom) {
    int idx = blockIdx.x * 256 + threadIdx.x;
    float x = nb[idx*3], y = nb[idx*3+1], z = nb[idx*3+2];
    float v[9] = {x, y, z, x*x, y*y, z*z, x*y, x*z, y*z};
    __shared__ float red[4][9];
    int t = threadIdx.x;
#pragma unroll
    for (int q = 0; q < 9; ++q) {
        float s = v[q];
#pragma unroll
        for (int off = 32; off; off >>= 1) s += __shfl_xor(s, off);
        if ((t & 63) == 0) red[t >> 6][q] = s;
    }
    __syncthreads();
    if (t < 9) atomicAdd(&mom[t], red[0][t] + red[1][t] + red[2][t] + red[3][t]);
}

__global__ void bn1_params_kernel(const float* __restrict__ mom,
                                  const float* __restrict__ w1, const float* __restrict__ b1,
                                  const float* __restrict__ g1, const float* __restrict__ bt1,
                                  float* __restrict__ bn1a, float* __restrict__ bn1d) {
    int c = threadIdx.x;  // 128
    const float inv_n = 1.0f / (float)NROW;
    float mx = mom[0]*inv_n, my = mom[1]*inv_n, mz = mom[2]*inv_n;
    float cxx = mom[3]*inv_n - mx*mx, cyy = mom[4]*inv_n - my*my, czz = mom[5]*inv_n - mz*mz;
    float cxy = mom[6]*inv_n - mx*my, cxz = mom[7]*inv_n - mx*mz, cyz = mom[8]*inv_n - my*mz;
    float wx = w1[c*3], wy = w1[c*3+1], wz = w1[c*3+2];
    float mean = wx*mx + wy*my + wz*mz + b1[c];
    float var  = wx*wx*cxx + wy*wy*cyy + wz*wz*czz
               + 2.0f*(wx*wy*cxy + wx*wz*cxz + wy*wz*cyz);
    float a = rsqrtf(var + EPS) * g1[c];
    bn1a[c] = a;
    bn1d[c] = (b1[c] - mean) * a + bt1[c];
}

__global__ void transpose_kernel(float* __restrict__ out, const float* __restrict__ in, int R, int C) {
    int t = blockIdx.x * blockDim.x + threadIdx.x;
    if (t < R * C) {
        int i = t / C, j = t % C;
        out[(size_t)j * R + i] = in[t];
    }
}

// split f32 -> bf16 hi (RNE) + bf16 lo (RNE of residual)
__global__ void split_kernel(const float* __restrict__ src, ushort_t* __restrict__ hi,
                             ushort_t* __restrict__ lo, int n) {
    int i = blockIdx.x * 256 + threadIdx.x;
    if (i < n) {
        float v = src[i];
        unsigned h = bf16_rne(v);
        hi[i] = (ushort_t)h;
        float r = v - __uint_as_float(h << 16);
        lo[i] = (ushort_t)bf16_rne(r);
    }
}

// =================== shared f1/f2 computation (p1 only; fmaf-pinned) ===================
__device__ __forceinline__ void compute_f1(const float* __restrict__ nbs, const float* __restrict__ w1,
                                           const float* __restrict__ bn1a, const float* __restrict__ bn1d,
                                           float* __restrict__ f1s, int t) {
    if (t < 128) {
        float a = bn1a[t], d = bn1d[t];
        float w0 = w1[t*3], wa = w1[t*3+1], wb = w1[t*3+2];
#pragma unroll 4
        for (int r = 0; r < 32; ++r) {
            float m = __fmul_rn(nbs[r*3], w0);
            m = __fmaf_rn(nbs[r*3+1], wa, m);
            m = __fmaf_rn(nbs[r*3+2], wb, m);
            m = __fmaf_rn(m, a, d);
            f1s[r*129 + t] = fmaxf(m, 0.0f);
        }
    }
}

__device__ __forceinline__ void compute_f2(const float* __restrict__ f1s, const float* __restrict__ w2t,
                                           const float* __restrict__ b2, float* __restrict__ f2s, int t) {
    int rb = t >> 6, cb = t & 63;     // 8-row x 4-col micro tile
    float4 bv = *reinterpret_cast<const float4*>(&b2[cb*4]);
    float acc[8][4];
#pragma unroll
    for (int m = 0; m < 8; ++m) { acc[m][0]=bv.x; acc[m][1]=bv.y; acc[m][2]=bv.z; acc[m][3]=bv.w; }
    for (int k = 0; k < 128; ++k) {
        float4 wv = *reinterpret_cast<const float4*>(&w2t[k*256 + cb*4]);
#pragma unroll
        for (int m = 0; m < 8; ++m) {
            float fv = f1s[(rb*8 + m)*129 + k];
            acc[m][0] = __fmaf_rn(fv, wv.x, acc[m][0]);
            acc[m][1] = __fmaf_rn(fv, wv.y, acc[m][1]);
            acc[m][2] = __fmaf_rn(fv, wv.z, acc[m][2]);
            acc[m][3] = __fmaf_rn(fv, wv.w, acc[m][3]);
        }
    }
#pragma unroll
    for (int m = 0; m < 8; ++m) {
        float4 o; o.x=acc[m][0]; o.y=acc[m][1]; o.z=acc[m][2]; o.w=acc[m][3];
        *reinterpret_cast<float4*>(&f2s[(rb*8 + m)*256 + cb*4]) = o;
    }
}

// =================== P1: per-group f1/f2 -> fg, c1, A-partials ===================
__global__ __launch_bounds__(256) void p1_kernel(const float* __restrict__ nbg, const float* __restrict__ w1,
                                                 const float* __restrict__ bn1a, const float* __restrict__ bn1d,
                                                 const float* __restrict__ w2t, const float* __restrict__ b2,
                                                 float* __restrict__ fg, float* __restrict__ c1,
                                                 float* __restrict__ apart) {
    __shared__ float f1s[32*129];
    __shared__ float f2s[32*256];
    __shared__ float nbs[96];
    int t = threadIdx.x;
    int i0 = (t >> 4) * 8, j0 = (t & 15) * 8;
    float accA[8][8];
#pragma unroll
    for (int m = 0; m < 8; ++m)
#pragma unroll
        for (int n = 0; n < 8; ++n) accA[m][n] = 0.f;

    for (int gi = 0; gi < 16; ++gi) {
        int g = blockIdx.x * 16 + gi;
        if (t < 96) nbs[t] = nbg[(size_t)g * 96 + t];
        __syncthreads();
        compute_f1(nbs, w1, bn1a, bn1d, f1s, t);
        __syncthreads();
        compute_f2(f1s, w2t, b2, f2s, t);
        __syncthreads();
        {
            float mx = f2s[t];
#pragma unroll 4
            for (int r = 1; r < 32; ++r) mx = fmaxf(mx, f2s[r*256 + t]);
            fg[(size_t)g * 256 + t] = mx;
            if (t < 128) {
                float s = 0.f;
#pragma unroll 4
                for (int r = 0; r < 32; ++r) s = __fadd_rn(s, f1s[r*129 + t]);
                c1[(size_t)g * 128 + t] = s;
            }
        }
#pragma unroll 2
        for (int r = 0; r < 32; ++r) {
            float am[8], bn_[8];
#pragma unroll
            for (int m = 0; m < 8; ++m) am[m]  = f1s[r*129 + i0 + m];
#pragma unroll
            for (int n = 0; n < 8; ++n) bn_[n] = f1s[r*129 + j0 + n];
#pragma unroll
            for (int m = 0; m < 8; ++m)
#pragma unroll
                for (int n = 0; n < 8; ++n)
                    accA[m][n] = __fmaf_rn(am[m], bn_[n], accA[m][n]);
        }
        __syncthreads();
    }
    float* ap = apart + (size_t)blockIdx.x * 16384;
#pragma unroll
    for (int m = 0; m < 8; ++m)
#pragma unroll
        for (int n = 0; n < 8; ++n)
            ap[(i0 + m)*128 + j0 + n] = accA[m][n];
}

__global__ void reduce_a_kernel(const float* __restrict__ apart, float* __restrict__ A) {
    int e = blockIdx.x * 256 + threadIdx.x;  // < 16384
    float s = 0.f;
    for (int b = 0; b < 512; ++b) s = __fadd_rn(s, apart[(size_t)b * 16384 + e]);
    A[e] = s;
}

__global__ void reduce_cf_kernel(const float* __restrict__ c1, const float* __restrict__ fgb,
                                 float* __restrict__ s1, float* __restrict__ sf) {
    int c = blockIdx.x, t = threadIdx.x;  // 384 blocks
    __shared__ float red[256];
    float s = 0.f;
    if (c < 128) { for (int g = t; g < GT; g += 256) s += c1[(size_t)g*128 + c]; }
    else { int cc = c - 128; for (int g = t; g < GT; g += 256) s += fgb[(size_t)g*256 + cc]; }
    red[t] = s; __syncthreads();
    for (int w = 128; w; w >>= 1) { if (t < w) red[t] += red[t + w]; __syncthreads(); }
    if (t == 0) { if (c < 128) s1[c] = red[0]; else sf[c - 128] = red[0]; }
}

__global__ void assemble_mu_kernel(const float* __restrict__ s1, const float* __restrict__ sf,
                                   const float* __restrict__ w2t, const float* __restrict__ b2,
                                   float* __restrict__ mu, float* __restrict__ w2s1) {
    int t = blockIdx.x * 256 + threadIdx.x;  // < 512
    const float inv_n = 1.0f / (float)NROW;
    if (t < 256) {
        mu[t] = sf[t] * (1.0f / (float)GT);
    } else {
        int c = t - 256;
        float s = 0.f;
        for (int k = 0; k < 128; ++k) s = __fmaf_rn(w2t[k*256 + c], s1[k], s);
        w2s1[c] = s;
        mu[t] = (s + (float)NROW * b2[c]) * inv_n;
    }
}

// C[i,j] = sum_k A[k*lda+i] * B[k*ldb+j]   (TN gemm, all dims % 16 == 0)
__global__ __launch_bounds__(256) void gemm_tn_kernel(float* __restrict__ Cm,
                                                      const float* __restrict__ Am, const float* __restrict__ Bm,
                                                      int M, int N, int Kd, int lda, int ldb) {
    __shared__ float As[16][17], Bs[16][17];
    int tx = threadIdx.x & 15, ty = threadIdx.x >> 4;
    int j = blockIdx.x * 16 + tx;
    int i = blockIdx.y * 16 + ty;
    float acc = 0.f;
    for (int k0 = 0; k0 < Kd; k0 += 16) {
        As[ty][tx] = Am[(size_t)(k0 + ty) * lda + blockIdx.y*16 + tx];
        Bs[ty][tx] = Bm[(size_t)(k0 + ty) * ldb + blockIdx.x*16 + tx];
        __syncthreads();
#pragma unroll
        for (int kk = 0; kk < 16; ++kk) acc = __fmaf_rn(As[kk][ty], Bs[kk][tx], acc);
        __syncthreads();
    }
    Cm[(size_t)i * N + j] = acc;
}

// C[i,j] = sum_k A[i*lda+k] * B[k*ldb+j]   (NN gemm, M%64==0, N%64==0, K%16==0)
__global__ __launch_bounds__(256) void gemm_nn_kernel(float* __restrict__ Cm,
                                                      const float* __restrict__ Am, const float* __restrict__ Bm,
                                                      int M, int N, int Kd, int lda, int ldb) {
    __shared__ float As[16][65], Bs[16][65];
    int t = threadIdx.x;
    int i0 = blockIdx.y * 64, j0 = blockIdx.x * 64;
    int tx = t & 15, ty = t >> 4;
    int lr = t & 63, lk = t >> 6;
    float acc[4][4];
#pragma unroll
    for (int a = 0; a < 4; ++a)
#pragma unroll
        for (int b = 0; b < 4; ++b) acc[a][b] = 0.f;
    for (int k0 = 0; k0 < Kd; k0 += 16) {
#pragma unroll
        for (int u = 0; u < 4; ++u) {
            int k = lk*4 + u;
            As[k][lr] = Am[(size_t)(i0 + lr) * lda + k0 + k];
            Bs[k][lr] = Bm[(size_t)(k0 + k) * ldb + j0 + lr];
        }
        __syncthreads();
#pragma unroll
        for (int kk = 0; kk < 16; ++kk) {
            float av[4], bv[4];
#pragma unroll
            for (int u = 0; u < 4; ++u) av[u] = As[kk][ty*4+u];
#pragma unroll
            for (int u = 0; u < 4; ++u) bv[u] = Bs[kk][tx*4+u];
#pragma unroll
            for (int a = 0; a < 4; ++a)
#pragma unroll
                for (int b = 0; b < 4; ++b) acc[a][b] = __fmaf_rn(av[a], bv[b], acc[a][b]);
        }
        __syncthreads();
    }
#pragma unroll
    for (int a = 0; a < 4; ++a)
#pragma unroll
        for (int b = 0; b < 4; ++b)
            Cm[(size_t)(i0 + ty*4 + a) * N + j0 + tx*4 + b] = acc[a][b];
}

// bn3 stats from quadratic forms: var_c = w3_c S w3_c^T / n - mean^2
__global__ __launch_bounds__(256) void bn3_params_kernel(const float* __restrict__ w3, const float* __restrict__ b3,
        const float* __restrict__ g3, const float* __restrict__ bt3,
        const float* __restrict__ sff, const float* __restrict__ sfc, const float* __restrict__ sccw,
        const float* __restrict__ sf, const float* __restrict__ w2s1, const float* __restrict__ b2,
        const float* __restrict__ mu, float* __restrict__ bn3a, float* __restrict__ bn3d) {
    int c = blockIdx.x, t = threadIdx.x;
    __shared__ float wL[512];
    __shared__ float red[256];
    wL[t]       = w3[(size_t)c*512 + t];
    wL[256 + t] = w3[(size_t)c*512 + 256 + t];
    __syncthreads();
    float v1 = 0.f, v2 = 0.f, v3 = 0.f;
    for (int i = 0; i < 256; ++i) {
        float wfi = wL[i], wci = wL[256 + i];
        v1 = __fmaf_rn(wfi, sff[(size_t)i*256 + t], v1);
        v2 = __fmaf_rn(wfi, sfc[(size_t)i*256 + t], v2);
        v3 = __fmaf_rn(wci, sccw[(size_t)i*256 + t], v3);
    }
    float wf_t = wL[t], wc_t = wL[256 + t];
    float vals[7];
    vals[0] = v1 * wf_t;
    vals[1] = v2 * wc_t;
    vals[2] = v3 * wc_t;
    vals[3] = wf_t * sf[t];
    vals[4] = wc_t * b2[t];
    vals[5] = wc_t * w2s1[t];
    vals[6] = wf_t * mu[t] + wc_t * mu[256 + t];
    float sums[7];
    for (int q = 0; q < 7; ++q) {
        red[t] = vals[q]; __syncthreads();
        for (int w = 128; w; w >>= 1) { if (t < w) red[t] += red[t + w]; __syncthreads(); }
        sums[q] = red[0]; __syncthreads();
    }
    if (t == 0) {
        float n = (float)NROW;
        float Q = 32.f*sums[0] + 2.f*(sums[1] + 32.f*sums[3]*sums[4])
                + sums[2] + 2.f*sums[5]*sums[4] + n*sums[4]*sums[4];
        float m3 = sums[6] + b3[c];
        float E2 = Q / n + 2.f*b3[c]*sums[6] + b3[c]*b3[c];
        float var = E2 - m3*m3;
        float a = rsqrtf(var + EPS) * g3[c];
        bn3a[c] = a;
        // d folds in b23 (= sums[4]) since mm3 acc = base3 + f1*W23 (no biases)
        bn3d[c] = (b3[c] + sums[4] - m3) * a + bt3[c];
    }
}

// =================== P3 (MFMA, v2) ===================
// 2 groups (64 rows), 512 threads (8 waves), chunk=64 output channels.
// mm3 computed SWAPPED (A=W23 rows=channels, B=f1^T) so the C-fragment holds 4
// consecutive channels per lane -> bn3+relu+split packs to one ds_write_b64.
// f1/f3 LDS XOR-swizzled (byte ^= (row&7)<<4); all accesses at bank minimum.
__global__ __launch_bounds__(512, 4) void p3_mfma_kernel(
        const float* __restrict__ nbg, const float* __restrict__ w1,
        const float* __restrict__ bn1a, const float* __restrict__ bn1d,
        const ushort_t* __restrict__ w23h, const ushort_t* __restrict__ w23l,
        const ushort_t* __restrict__ w4h, const ushort_t* __restrict__ w4l,
        const float* __restrict__ base3, const float* __restrict__ bn3a, const float* __restrict__ bn3d,
        const float* __restrict__ b4, float* __restrict__ out) {
    __shared__ short f1h[64*128], f1l[64*128];   // 16 KB each
    __shared__ short f3h[64*64],  f3l[64*64];    // 8 KB each
    __shared__ float nbs[192];
    int t = threadIdx.x;
    int g0 = blockIdx.x * 2;
    if (t < 192) nbs[t] = nbg[(size_t)g0 * 96 + t];
    __syncthreads();
    // ---- f1 = relu(bn1(nb*w1)), split hi/lo, swizzled LDS ----
    {
        int cp = t & 63;            // channel pair (2cp, 2cp+1)
        int r0 = (t >> 6) * 8;      // 8 waves x 8 rows
        int c0 = cp * 2;
        float w00=w1[c0*3+0], w01=w1[c0*3+1], w02=w1[c0*3+2];
        float w10=w1[c0*3+3], w11=w1[c0*3+4], w12=w1[c0*3+5];
        float aA=bn1a[c0], dA=bn1d[c0], aB=bn1a[c0+1], dB=bn1d[c0+1];
#pragma unroll
        for (int rr = 0; rr < 8; ++rr) {
            int r = r0 + rr;
            float x = nbs[r*3], y = nbs[r*3+1], z = nbs[r*3+2];
            float mA = __fmul_rn(x, w00); mA = __fmaf_rn(y, w01, mA); mA = __fmaf_rn(z, w02, mA);
            mA = __fmaf_rn(mA, aA, dA); mA = fmaxf(mA, 0.f);
            float mB = __fmul_rn(x, w10); mB = __fmaf_rn(y, w11, mB); mB = __fmaf_rn(z, w12, mB);
            mB = __fmaf_rn(mB, aB, dB); mB = fmaxf(mB, 0.f);
            unsigned hA = bf16_rne(mA), hB = bf16_rne(mB);
            unsigned lA = bf16_rne(mA - __uint_as_float(hA << 16));
            unsigned lB = bf16_rne(mB - __uint_as_float(hB << 16));
            int off = r*256 + ((cp*4) ^ ((r&7)<<4));
            *(unsigned*)((char*)f1h + off) = hA | (hB << 16);
            *(unsigned*)((char*)f1l + off) = lA | (lB << 16);
        }
    }
    int lane = t & 63, w = t >> 6;
    int l15 = lane & 15, lh = lane >> 4;
    // mm3 role: channel-block (w&3)*16 of chunk, row-group (w>>2)
    int m3c  = (w & 3) * 16;
    int m3rg = w >> 2;
    // mm4 role: group (w>>2), out-channel quarter (w&3)*96
    int m4g = w >> 2, m4n = (w & 3) * 96;

    f32x4 acc4[2][6];
#pragma unroll
    for (int mt = 0; mt < 2; ++mt)
#pragma unroll
        for (int nt = 0; nt < 6; ++nt) acc4[mt][nt] = (f32x4){0.f, 0.f, 0.f, 0.f};

    const float* b3p = base3 + (size_t)(g0 + m3rg) * 512 + m3c + lh * 4;
    f32x4 b3cur = *(const f32x4*)b3p;   // chunk 0
    __syncthreads();                    // f1 ready

    for (int chunk = 0; chunk < 8; ++chunk) {
        f32x4 b3nxt = b3cur;
        if (chunk < 7) b3nxt = *(const f32x4*)(b3p + (chunk + 1) * 64);
        // ---- mm3 (swapped): acc3[nt] = base3 + W23 * f1^T ----
        f32x4 acc3[2];
        acc3[0] = b3cur; acc3[1] = b3cur;
#pragma unroll
        for (int ks = 0; ks < 4; ++ks) {
            size_t wo = (size_t)(chunk*64 + m3c + l15) * 128 + ks*32 + lh*8;
            bf16x8 wah = *(const bf16x8*)(w23h + wo);
            bf16x8 wal = *(const bf16x8*)(w23l + wo);
#pragma unroll
            for (int nt = 0; nt < 2; ++nt) {
                int row = m3rg*32 + nt*16 + l15;
                int off = row*256 + ((ks*64 + lh*16) ^ ((row&7)<<4));
                bf16x8 fbh = *(bf16x8*)((char*)f1h + off);
                bf16x8 fbl = *(bf16x8*)((char*)f1l + off);
                acc3[nt] = __builtin_amdgcn_mfma_f32_16x16x32_bf16(wah, fbh, acc3[nt], 0, 0, 0);
                acc3[nt] = __builtin_amdgcn_mfma_f32_16x16x32_bf16(wah, fbl, acc3[nt], 0, 0, 0);
                acc3[nt] = __builtin_amdgcn_mfma_f32_16x16x32_bf16(wal, fbh, acc3[nt], 0, 0, 0);
            }
        }
        __syncthreads();   // prev chunk's mm4 reads of f3 done
        // ---- bn3+relu+split -> f3 (4 consecutive channels per lane, b64 store) ----
        {
            int cb = chunk*64 + m3c + lh*4;
            f32x4 a4 = *(const f32x4*)(bn3a + cb);
            f32x4 d4 = *(const f32x4*)(bn3d + cb);
#pragma unroll
            for (int nt = 0; nt < 2; ++nt) {
                int row = m3rg*32 + nt*16 + l15;
                unsigned hw0, hw1, lw0, lw1;
                {
                    float v0 = fmaxf(__fmaf_rn(acc3[nt][0], a4[0], d4[0]), 0.f);
                    float v1 = fmaxf(__fmaf_rn(acc3[nt][1], a4[1], d4[1]), 0.f);
                    float v2 = fmaxf(__fmaf_rn(acc3[nt][2], a4[2], d4[2]), 0.f);
                    float v3 = fmaxf(__fmaf_rn(acc3[nt][3], a4[3], d4[3]), 0.f);
                    unsigned h0 = bf16_rne(v0), h1 = bf16_rne(v1), h2 = bf16_rne(v2), h3 = bf16_rne(v3);
                    unsigned l0 = bf16_rne(v0 - __uint_as_float(h0 << 16));
                    unsigned l1 = bf16_rne(v1 - __uint_as_float(h1 << 16));
                    unsigned l2 = bf16_rne(v2 - __uint_as_float(h2 << 16));
                    unsigned l3 = bf16_rne(v3 - __uint_as_float(h3 << 16));
                    hw0 = h0 | (h1 << 16); hw1 = h2 | (h3 << 16);
                    lw0 = l0 | (l1 << 16); lw1 = l2 | (l3 << 16);
                }
                int off = row*128 + (((m3c + lh*4) * 2) ^ ((row&7)<<4));
                *(unsigned long long*)((char*)f3h + off) = (unsigned long long)hw0 | ((unsigned long long)hw1 << 32);
                *(unsigned long long*)((char*)f3l + off) = (unsigned long long)lw0 | ((unsigned long long)lw1 << 32);
            }
        }
        __syncthreads();
        // ---- mm4: acc4 += f3 * w4[:, chunk] ----
#pragma unroll
        for (int ks = 0; ks < 2; ++ks) {
            bf16x8 fah[2], fal[2];
#pragma unroll
            for (int mt = 0; mt < 2; ++mt) {
                int row = m4g*32 + mt*16 + l15;
                int off = row*128 + ((ks*64 + lh*16) ^ ((row&7)<<4));
                fah[mt] = *(bf16x8*)((char*)f3h + off);
                fal[mt] = *(bf16x8*)((char*)f3l + off);
            }
#pragma unroll
            for (int nt = 0; nt < 6; ++nt) {
                int n = m4n + nt*16 + l15;
                size_t wo = (size_t)n*512 + chunk*64 + ks*32 + lh*8;
                bf16x8 wbh = *(const bf16x8*)(w4h + wo);
                bf16x8 wbl = *(const bf16x8*)(w4l + wo);
#pragma unroll
                for (int mt = 0; mt < 2; ++mt) {
                    acc4[mt][nt] = __builtin_amdgcn_mfma_f32_16x16x32_bf16(fah[mt], wbh, acc4[mt][nt], 0, 0, 0);
                    acc4[mt][nt] = __builtin_amdgcn_mfma_f32_16x16x32_bf16(fah[mt], wbl, acc4[mt][nt], 0, 0, 0);
                    acc4[mt][nt] = __builtin_amdgcn_mfma_f32_16x16x32_bf16(fal[mt], wbh, acc4[mt][nt], 0, 0, 0);
                }
            }
        }
        b3cur = b3nxt;
    }
    // ---- epilogue: max over the wave's 32 rows, + b4 ----
    int gg = g0 + m4g;
#pragma unroll
    for (int nt = 0; nt < 6; ++nt) {
        int n = m4n + nt*16 + l15;
        float m = acc4[0][nt][0];
#pragma unroll
        for (int q = 1; q < 4; ++q) m = fmaxf(m, acc4[0][nt][q]);
#pragma unroll
        for (int q = 0; q < 4; ++q) m = fmaxf(m, acc4[1][nt][q]);
        m = fmaxf(m, __shfl_xor(m, 16));
        m = fmaxf(m, __shfl_xor(m, 32));
        if (lh == 0) out[(size_t)gg * 384 + n] = m + b4[n];
    }
}

// =================== launch ===================
extern "C" void kernel_launch(void* const* d_in, const int* in_sizes, int n_in,
                              void* d_out, int out_size, void* d_ws, size_t ws_size,
                              hipStream_t stream) {
    const float* xyz = (const float*)d_in[0];
    const float* w1  = (const float*)d_in[1];
    const float* b1  = (const float*)d_in[2];
    const float* g1  = (const float*)d_in[3];
    const float* bt1 = (const float*)d_in[4];
    const float* w2  = (const float*)d_in[5];
    const float* b2  = (const float*)d_in[6];
    const float* w3  = (const float*)d_in[7];
    const float* b3  = (const float*)d_in[8];
    const float* g3  = (const float*)d_in[9];
    const float* bt3 = (const float*)d_in[10];
    const float* w4  = (const float*)d_in[11];
    const float* b4  = (const float*)d_in[12];
    float* out = (float*)d_out;
    float* ws  = (float*)d_ws;

    if (ws_size < WS_FLOATS * sizeof(float)) return;  // leaves poison -> clean mismatch signal

    float* centers = ws + OFF_CENTERS;
    float* nb      = ws + OFF_NB;
    float* fgB     = ws + OFF_FG;
    float* c1B     = ws + OFF_C1;
    float* mom     = ws + OFF_MOM;
    float* A       = ws + OFF_A;
    float* s1      = ws + OFF_S1;
    float* sf      = ws + OFF_SF;
    float* mu      = ws + OFF_MU;
    float* w2s1    = ws + OFF_W2S1;
    float* bn1a    = ws + OFF_BN1A;
    float* bn1d    = ws + OFF_BN1D;
    float* bn3a    = ws + OFF_BN3A;
    float* bn3d    = ws + OFF_BN3D;
    float* sff     = ws + OFF_SFF;
    float* pfct    = ws + OFF_PFCT;
    float* t1m     = ws + OFF_T1;
    float* sccw    = ws + OFF_SCCW;
    float* sfcm    = ws + OFF_SFC;
    float* w2t     = ws + OFF_W2T;
    float* w3t     = ws + OFF_W3T;
    ushort_t* w4h  = (ushort_t*)(ws + OFF_W4H);
    ushort_t* w4l  = (ushort_t*)(ws + OFF_W4L);
    float* apart   = ws + OFF_APART;
    float* w23     = ws + OFF_W23;
    ushort_t* w23h = (ushort_t*)(ws + OFF_W23H);
    ushort_t* w23l = (ushort_t*)(ws + OFF_W23L);
    float* base3   = ws + OFF_BASE3;   // aliases apart (valid after reduce_a)

    zero_mom_kernel<<<1, 64, 0, stream>>>(mom);
    fps_kernel<<<B_, 1024, 0, stream>>>(xyz, centers);
    knn_kernel<<<GT, 256, 0, stream>>>(xyz, centers, nb);
    moments_kernel<<<NROW/256, 256, 0, stream>>>(nb, mom);
    bn1_params_kernel<<<1, 128, 0, stream>>>(mom, w1, b1, g1, bt1, bn1a, bn1d);
    transpose_kernel<<<(256*128 + 255)/256, 256, 0, stream>>>(w2t, w2, 256, 128);
    transpose_kernel<<<(512*512 + 255)/256, 256, 0, stream>>>(w3t, w3, 512, 512);
    // W23[n][k] = sum_j w3[n][256+j] * w2[j][k]  (f2-linearity fold)
    gemm_tn_kernel<<<dim3(8, 32), 256, 0, stream>>>(w23, w3t + 256*512, w2, 512, 128, 256, 512, 128);
    split_kernel<<<(65536 + 255)/256, 256, 0, stream>>>(w23, w23h, w23l, 65536);
    split_kernel<<<(196608 + 255)/256, 256, 0, stream>>>(w4, w4h, w4l, 196608);
    p1_kernel<<<512, 256, 0, stream>>>(nb, w1, bn1a, bn1d, w2t, b2, fgB, c1B, apart);
    reduce_a_kernel<<<64, 256, 0, stream>>>(apart, A);
    // base3[g][n] = sum_{k<256} fg[g][k] * w3[n][k]   (overwrites apart region)
    gemm_nn_kernel<<<dim3(8, 128), 256, 0, stream>>>(base3, fgB, w3t, GT, 512, 256, 256, 512);
    reduce_cf_kernel<<<384, 256, 0, stream>>>(c1B, fgB, s1, sf);
    assemble_mu_kernel<<<2, 256, 0, stream>>>(s1, sf, w2t, b2, mu, w2s1);
    gemm_tn_kernel<<<dim3(16,16), 256, 0, stream>>>(sff,  fgB,  fgB, 256, 256, GT,  256, 256);
    gemm_tn_kernel<<<dim3(16, 8), 256, 0, stream>>>(pfct, c1B,  fgB, 128, 256, GT,  128, 256);
    gemm_tn_kernel<<<dim3(16, 8), 256, 0, stream>>>(t1m,  A,    w2t, 128, 256, 128, 128, 256);
    gemm_tn_kernel<<<dim3(16,16), 256, 0, stream>>>(sccw, w2t,  t1m, 256, 256, 128, 256, 256);
    gemm_tn_kernel<<<dim3(16,16), 256, 0, stream>>>(sfcm, pfct, w2t, 256, 256, 128, 256, 256);
    bn3_params_kernel<<<512, 256, 0, stream>>>(w3, b3, g3, bt3, sff, sfcm, sccw, sf, w2s1, b2, mu, bn3a, bn3d);
    p3_mfma_kernel<<<GT/2, 512, 0, stream>>>(nb, w1, bn1a, bn1d, w23h, w23l, w4h, w4l,
                                             base3, bn3a, bn3d, b4, out);
}

// Round 6
// 3194.955 us; speedup vs baseline: 2.3279x; 1.1345x over previous
//
#include <hip/hip_runtime.h>
#include <cstddef>

#define B_   16
#define N_   8192
#define G_   512
#define K_   32
#define GT   8192          // B_*G_
#define NROW 262144        // GT*K_
#define EPS  1e-5f

typedef unsigned short ushort_t;
typedef short bf16x8 __attribute__((ext_vector_type(8)));
typedef float f32x4  __attribute__((ext_vector_type(4)));

// ---------------- workspace layout (float offsets) ----------------
constexpr size_t OFF_CENTERS = 0;                          // B*G*3
constexpr size_t OFF_NB      = OFF_CENTERS + 24576;        // GT*K*3
constexpr size_t OFF_FG      = OFF_NB      + 786432;       // GT*256
constexpr size_t OFF_C1      = OFF_FG      + 2097152;      // GT*128
constexpr size_t OFF_MOM     = OFF_C1      + 1048576;      // 16
constexpr size_t OFF_A       = OFF_MOM     + 16;           // 128*128
constexpr size_t OFF_S1      = OFF_A       + 16384;        // 128
constexpr size_t OFF_SF      = OFF_S1      + 128;          // 256
constexpr size_t OFF_MU      = OFF_SF      + 256;          // 512
constexpr size_t OFF_W2S1    = OFF_MU      + 512;          // 256
constexpr size_t OFF_BN1A    = OFF_W2S1    + 256;          // 128
constexpr size_t OFF_BN1D    = OFF_BN1A    + 128;          // 128
constexpr size_t OFF_BN3A    = OFF_BN1D    + 128;          // 512
constexpr size_t OFF_BN3D    = OFF_BN3A    + 512;          // 512
constexpr size_t OFF_SFF     = OFF_BN3D    + 512;          // 256*256
constexpr size_t OFF_PFCT    = OFF_SFF     + 65536;        // 128*256
constexpr size_t OFF_T1      = OFF_PFCT    + 32768;        // 128*256
constexpr size_t OFF_SCCW    = OFF_T1      + 32768;        // 256*256
constexpr size_t OFF_SFC     = OFF_SCCW    + 65536;        // 256*256
constexpr size_t OFF_W2T     = OFF_SFC     + 65536;        // 128*256
constexpr size_t OFF_W3T     = OFF_W2T     + 32768;        // 512*512
constexpr size_t OFF_W4H     = OFF_W3T     + 262144;       // 196608 ushorts (bf16 hi of w4)
constexpr size_t OFF_W4L     = OFF_W4H     + 98304;        // 196608 ushorts
constexpr size_t OFF_APART   = OFF_W4L     + 98304;        // 512 blocks * 16384
constexpr size_t OFF_W23     = OFF_APART   + 8388608;      // 512*128 f32
constexpr size_t OFF_W23H    = OFF_W23     + 65536;        // 65536 ushorts
constexpr size_t OFF_W23L    = OFF_W23H    + 32768;        // 65536 ushorts
constexpr size_t OFF_W2H     = OFF_W23L    + 32768;        // 32768 ushorts (bf16 hi of w2)
constexpr size_t OFF_W2L     = OFF_W2H     + 16384;        // 32768 ushorts
constexpr size_t WS_FLOATS   = OFF_W2L     + 16384;        // ~53.1 MB
constexpr size_t OFF_BASE3   = OFF_APART;                  // alias: base3 [8192][512] after reduce_a

__device__ __forceinline__ unsigned bf16_rne(float v) {
    unsigned u = __float_as_uint(v);
    return (u + 0x7fffu + ((u >> 16) & 1u)) >> 16;
}

// =================== FPS ===================
// One block per batch. Points + dists in registers. 2 barriers/iter.
__global__ __launch_bounds__(1024) void fps_kernel(const float* __restrict__ xyz,
                                                   float* __restrict__ centers) {
    int b = blockIdx.x, t = threadIdx.x;
    const float* xb = xyz + (size_t)b * N_ * 3;
    float px[8], py[8], pz[8], dist[8];
#pragma unroll
    for (int i = 0; i < 8; ++i) {
        int p = t + (i << 10);
        px[i] = xb[p*3]; py[i] = xb[p*3+1]; pz[i] = xb[p*3+2];
        dist[i] = 1e10f;
    }
    __shared__ float redV[2][16];
    __shared__ int   redI[2][16];
    __shared__ float cxyz[2][3];
    if (t == 0) { cxyz[0][0] = px[0]; cxyz[0][1] = py[0]; cxyz[0][2] = pz[0]; }
    __syncthreads();
    for (int it = 0; it < G_; ++it) {
        int cur = it & 1;
        float lcx = cxyz[cur][0], lcy = cxyz[cur][1], lcz = cxyz[cur][2];
        if (t == 0) {
            float* cd = centers + ((size_t)b * G_ + it) * 3;
            cd[0] = lcx; cd[1] = lcy; cd[2] = lcz;
        }
        float bv = -1.0f; int bp = 0;
#pragma unroll
        for (int i = 0; i < 8; ++i) {
            float dx = __fsub_rn(px[i], lcx);
            float dy = __fsub_rn(py[i], lcy);
            float dz = __fsub_rn(pz[i], lcz);
            float d  = __fadd_rn(__fadd_rn(__fmul_rn(dx,dx), __fmul_rn(dy,dy)), __fmul_rn(dz,dz));
            float nd = fminf(dist[i], d);
            dist[i] = nd;
            if (nd > bv) { bv = nd; bp = t + (i << 10); }
        }
#pragma unroll
        for (int off = 1; off < 64; off <<= 1) {
            float ov = __shfl_xor(bv, off);
            int   op = __shfl_xor(bp, off);
            if (ov > bv || (ov == bv && op < bp)) { bv = ov; bp = op; }
        }
        if ((t & 63) == 0) { redV[cur][t >> 6] = bv; redI[cur][t >> 6] = bp; }
        __syncthreads();
        float v = redV[cur][t & 15]; int p = redI[cur][t & 15];
#pragma unroll
        for (int off = 1; off < 16; off <<= 1) {
            float ov = __shfl_xor(v, off);
            int   op = __shfl_xor(p, off);
            if (ov > v || (ov == v && op < p)) { v = ov; p = op; }
        }
        if ((p & 1023) == t) {
            int i = p >> 10;
            cxyz[cur ^ 1][0] = px[i]; cxyz[cur ^ 1][1] = py[i]; cxyz[cur ^ 1][2] = pz[i];
        }
        __syncthreads();
    }
}

// =================== kNN + gather(centered) ===================
__global__ __launch_bounds__(256) void knn_kernel(const float* __restrict__ xyz,
                                                  const float* __restrict__ centers,
                                                  float* __restrict__ nb) {
    int g = blockIdx.x, t = threadIdx.x;
    int b = g >> 9;
    const float* xb = xyz + (size_t)b * N_ * 3;
    const float* c  = centers + (size_t)g * 3;
    float lcx = c[0], lcy = c[1], lcz = c[2];
    float cn2 = __fadd_rn(__fadd_rn(__fmul_rn(lcx,lcx), __fmul_rn(lcy,lcy)), __fmul_rn(lcz,lcz));
    float dreg[32];
#pragma unroll 8
    for (int i = 0; i < 32; ++i) {
        int p = t + (i << 8);
        float x = xb[p*3], y = xb[p*3+1], z = xb[p*3+2];
        float pn2 = __fadd_rn(__fadd_rn(__fmul_rn(x,x), __fmul_rn(y,y)), __fmul_rn(z,z));
        float dot = __fadd_rn(__fadd_rn(__fmul_rn(lcx,x), __fmul_rn(lcy,y)), __fmul_rn(lcz,z));
        dreg[i]   = __fadd_rn(__fadd_rn(__fmul_rn(-2.0f,dot), cn2), pn2);
    }
    __shared__ float redV[2][4];
    __shared__ int   redI[2][4];
    int myp = 0;
    for (int s = 0; s < K_; ++s) {
        float bv = 1e30f; int bp = 0;
#pragma unroll
        for (int i = 0; i < 32; ++i) {
            float v = dreg[i];
            if (v < bv) { bv = v; bp = t + (i << 8); }
        }
#pragma unroll
        for (int off = 1; off < 64; off <<= 1) {
            float ov = __shfl_xor(bv, off);
            int   op = __shfl_xor(bp, off);
            if (ov < bv || (ov == bv && op < bp)) { bv = ov; bp = op; }
        }
        int buf = s & 1;
        if ((t & 63) == 0) { redV[buf][t >> 6] = bv; redI[buf][t >> 6] = bp; }
        __syncthreads();
        float v = redV[buf][0]; int p = redI[buf][0];
#pragma unroll
        for (int w = 1; w < 4; ++w) {
            float ov = redV[buf][w]; int op = redI[buf][w];
            if (ov < v || (ov == v && op < p)) { v = ov; p = op; }
        }
        if (s == t) myp = p;
#pragma unroll
        for (int i = 0; i < 32; ++i)
            if (p == t + (i << 8)) dreg[i] = 1e30f;
    }
    if (t < K_) {
        int p = myp;
        float* dst = nb + ((size_t)g * K_ + t) * 3;
        dst[0] = xb[p*3]   - lcx;
        dst[1] = xb[p*3+1] - lcy;
        dst[2] = xb[p*3+2] - lcz;
    }
}

// =================== small utility kernels ===================
__global__ void zero_mom_kernel(float* __restrict__ mom) {
    if (threadIdx.x < 16) mom[threadIdx.x] = 0.0f;
}

__global__ void moments_kernel(const float* __restrict__ nb, float* __restrict__ mom) {
    int idx = blockIdx.x * 256 + threadIdx.x;
    float x = nb[idx*3], y = nb[idx*3+1], z = nb[idx*3+2];
    float v[9] = {x, y, z, x*x, y*y, z*z, x*y, x*z, y*z};
    __shared__ float red[4][9];
    int t = threadIdx.x;
#pragma unroll
    for (int q = 0; q < 9; ++q) {
        float s = v[q];
#pragma unroll
        for (int off = 32; off; off >>= 1) s += __shfl_xor(s, off);
        if ((t & 63) == 0) red[t >> 6][q] = s;
    }
    __syncthreads();
    if (t < 9) atomicAdd(&mom[t], red[0][t] + red[1][t] + red[2][t] + red[3][t]);
}

__global__ void bn1_params_kernel(const float* __restrict__ mom,
                                  const float* __restrict__ w1, const float* __restrict__ b1,
                                  const float* __restrict__ g1, const float* __restrict__ bt1,
                                  float* __restrict__ bn1a, float* __restrict__ bn1d) {
    int c = threadIdx.x;  // 128
    const float inv_n = 1.0f / (float)NROW;
    float mx = mom[0]*inv_n, my = mom[1]*inv_n, mz = mom[2]*inv_n;
    float cxx = mom[3]*inv_n - mx*mx, cyy = mom[4]*inv_n - my*my, czz = mom[5]*inv_n - mz*mz;
    float cxy = mom[6]*inv_n - mx*my, cxz = mom[7]*inv_n - mx*mz, cyz = mom[8]*inv_n - my*mz;
    float wx = w1[c*3], wy = w1[c*3+1], wz = w1[c*3+2];
    float mean = wx*mx + wy*my + wz*mz + b1[c];
    float var  = wx*wx*cxx + wy*wy*cyy + wz*wz*czz
               + 2.0f*(wx*wy*cxy + wx*wz*cxz + wy*wz*cyz);
    float a = rsqrtf(var + EPS) * g1[c];
    bn1a[c] = a;
    bn1d[c] = (b1[c] - mean) * a + bt1[c];
}

__global__ void transpose_kernel(float* __restrict__ out, const float* __restrict__ in, int R, int C) {
    int t = blockIdx.x * blockDim.x + threadIdx.x;
    if (t < R * C) {
        int i = t / C, j = t % C;
        out[(size_t)j * R + i] = in[t];
    }
}

// split f32 -> bf16 hi (RNE) + bf16 lo (RNE of residual)
__global__ void split_kernel(const float* __restrict__ src, ushort_t* __restrict__ hi,
                             ushort_t* __restrict__ lo, int n) {
    int i = blockIdx.x * 256 + threadIdx.x;
    if (i < n) {
        float v = src[i];
        unsigned h = bf16_rne(v);
        hi[i] = (ushort_t)h;
        float r = v - __uint_as_float(h << 16);
        lo[i] = (ushort_t)bf16_rne(r);
    }
}

// =================== P1 (MFMA): per-group f1 -> fg, c1, A-partials ===================
// 256 threads (4 waves), 16 groups/block, 512 blocks.
// f2 via swapped MFMA (A=W2-split global, B=f1 row-frag from XOR-swizzled LDS)
// -- byte-identical addressing to p3's validated mm3. fg = rowmax(D)+b2.
// A = f1^T f1 via transposed f1 copy at 80B pitch (bank rotation 20 words/row
// -> b128 frag reads at the 8-pass minimum). c1 exact f32 in the builder.
__global__ __launch_bounds__(256) void p1_mfma_kernel(
        const float* __restrict__ nbg, const float* __restrict__ w1,
        const float* __restrict__ bn1a, const float* __restrict__ bn1d,
        const ushort_t* __restrict__ w2h, const ushort_t* __restrict__ w2l,
        const float* __restrict__ b2,
        float* __restrict__ fg, float* __restrict__ c1,
        float* __restrict__ apart) {
    __shared__ short f1h[32*128], f1l[32*128];     // [32 rows][256B] swizzled, 8KB each
    __shared__ short f1Th[128*40], f1Tl[128*40];   // [128 ch][80B pitch], 10KB each
    __shared__ float c1part[2][128];
    __shared__ float nbs[96];
    int t = threadIdx.x;
    int lane = t & 63, w = t >> 6;
    int l15 = lane & 15, lh = lane >> 4;

    // A accumulators: wave w owns tiles i in {2w,2w+1}, j in 0..7 (16-ch tiles)
    f32x4 accA[2][8];
#pragma unroll
    for (int i2 = 0; i2 < 2; ++i2)
#pragma unroll
        for (int j = 0; j < 8; ++j) accA[i2][j] = (f32x4){0.f, 0.f, 0.f, 0.f};

    for (int gi = 0; gi < 16; ++gi) {
        int g = blockIdx.x * 16 + gi;
        if (gi == 0 && t < 96) nbs[t] = nbg[(size_t)g * 96 + t];
        __syncthreads();   // BAR1: nbs ready; prev group's MFMA reads of f1/f1T done
        // ---- build f1 = relu(bn1(nb*w1)); split hi/lo; row-major + transposed LDS; c1 exact ----
        {
            int ch = t & 127, rh = t >> 7;   // thread: 1 channel x 16 rows
            float a = bn1a[ch], d = bn1d[ch];
            float w0 = w1[ch*3], wa = w1[ch*3+1], wb = w1[ch*3+2];
            float csum = 0.f;
#pragma unroll
            for (int rr = 0; rr < 16; rr += 2) {
                int r0 = rh*16 + rr;
                unsigned hp[2], lp[2];
#pragma unroll
                for (int u = 0; u < 2; ++u) {
                    int r = r0 + u;
                    float x = nbs[r*3], y = nbs[r*3+1], z = nbs[r*3+2];
                    float m = __fmul_rn(x, w0);
                    m = __fmaf_rn(y, wa, m);
                    m = __fmaf_rn(z, wb, m);
                    m = __fmaf_rn(m, a, d);
                    m = fmaxf(m, 0.f);
                    csum = __fadd_rn(csum, m);
                    unsigned h = bf16_rne(m);
                    unsigned l = bf16_rne(m - __uint_as_float(h << 16));
                    hp[u] = h; lp[u] = l;
                    int off = r*256 + ((ch*2) ^ ((r&7)<<4));
                    *(short*)((char*)f1h + off) = (short)h;
                    *(short*)((char*)f1l + off) = (short)l;
                }
                int offT = ch*80 + r0*2;     // packed 2 points, word-aligned
                *(unsigned*)((char*)f1Th + offT) = hp[0] | (hp[1] << 16);
                *(unsigned*)((char*)f1Tl + offT) = lp[0] | (lp[1] << 16);
            }
            c1part[rh][ch] = csum;
        }
        __syncthreads();   // BAR2: f1/f1T/c1part ready
        if (t < 128) c1[(size_t)g*128 + t] = __fadd_rn(c1part[0][t], c1part[1][t]);
        if (gi < 15 && t < 96) nbs[t] = nbg[(size_t)(g+1) * 96 + t];  // prefetch (safe: nbs reads done)

        // ---- f2 + fg: wave w handles ct = 4w..4w+3 (16 out-ch each) ----
#pragma unroll
        for (int ci = 0; ci < 4; ++ci) {
            int ct = w*4 + ci;
            f32x4 acc2[2];
            acc2[0] = (f32x4){0.f,0.f,0.f,0.f};
            acc2[1] = (f32x4){0.f,0.f,0.f,0.f};
#pragma unroll
            for (int kq = 0; kq < 4; ++kq) {
                size_t wo = (size_t)(ct*16 + l15)*128 + kq*32 + lh*8;
                bf16x8 wah = *(const bf16x8*)(w2h + wo);
                bf16x8 wal = *(const bf16x8*)(w2l + wo);
#pragma unroll
                for (int pt = 0; pt < 2; ++pt) {
                    int row = pt*16 + l15;
                    int off = row*256 + ((kq*64 + lh*16) ^ ((row&7)<<4));
                    bf16x8 fbh = *(bf16x8*)((char*)f1h + off);
                    bf16x8 fbl = *(bf16x8*)((char*)f1l + off);
                    acc2[pt] = __builtin_amdgcn_mfma_f32_16x16x32_bf16(wah, fbh, acc2[pt], 0, 0, 0);
                    acc2[pt] = __builtin_amdgcn_mfma_f32_16x16x32_bf16(wah, fbl, acc2[pt], 0, 0, 0);
                    acc2[pt] = __builtin_amdgcn_mfma_f32_16x16x32_bf16(wal, fbh, acc2[pt], 0, 0, 0);
                }
            }
            // fg = max over 32 points (cols l15 x 2 tiles), +b2 (commutes with max)
            f32x4 mx;
#pragma unroll
            for (int q = 0; q < 4; ++q) mx[q] = fmaxf(acc2[0][q], acc2[1][q]);
#pragma unroll
            for (int off = 1; off < 16; off <<= 1) {
#pragma unroll
                for (int q = 0; q < 4; ++q) mx[q] = fmaxf(mx[q], __shfl_xor(mx[q], off));
            }
            if (l15 == 0) {
                int cb = ct*16 + lh*4;
#pragma unroll
                for (int q = 0; q < 4; ++q)
                    fg[(size_t)g*256 + cb + q] = mx[q] + b2[cb + q];
            }
        }

        // ---- A += f1^T f1 (tiles from f1T; both operands same frag pattern) ----
        {
            bf16x8 ahA[2], alA[2];
#pragma unroll
            for (int i2 = 0; i2 < 2; ++i2) {
                int chi = (2*w + i2)*16 + l15;
                int offA = chi*80 + lh*16;
                ahA[i2] = *(bf16x8*)((char*)f1Th + offA);
                alA[i2] = *(bf16x8*)((char*)f1Tl + offA);
            }
#pragma unroll
            for (int j = 0; j < 8; ++j) {
                int chj = j*16 + l15;
                int offB = chj*80 + lh*16;
                bf16x8 bh = *(bf16x8*)((char*)f1Th + offB);
                bf16x8 bl = *(bf16x8*)((char*)f1Tl + offB);
#pragma unroll
                for (int i2 = 0; i2 < 2; ++i2) {
                    accA[i2][j] = __builtin_amdgcn_mfma_f32_16x16x32_bf16(ahA[i2], bh, accA[i2][j], 0, 0, 0);
                    accA[i2][j] = __builtin_amdgcn_mfma_f32_16x16x32_bf16(ahA[i2], bl, accA[i2][j], 0, 0, 0);
                    accA[i2][j] = __builtin_amdgcn_mfma_f32_16x16x32_bf16(alA[i2], bh, accA[i2][j], 0, 0, 0);
                }
            }
        }
    }
    // ---- write A partials: D row=(lh*4+q)=i-ch, col=l15=j-ch ----
    float* ap = apart + (size_t)blockIdx.x * 16384;
#pragma unroll
    for (int i2 = 0; i2 < 2; ++i2)
#pragma unroll
        for (int j = 0; j < 8; ++j)
#pragma unroll
            for (int q = 0; q < 4; ++q)
                ap[((2*w + i2)*16 + lh*4 + q)*128 + j*16 + l15] = accA[i2][j][q];
}

__global__ void reduce_a_kernel(const float* __restrict__ apart, float* __restrict__ A) {
    int e = blockIdx.x * 256 + threadIdx.x;  // < 16384
    float s = 0.f;
    for (int b = 0; b < 512; ++b) s = __fadd_rn(s, apart[(size_t)b * 16384 + e]);
    A[e] = s;
}

__global__ void reduce_cf_kernel(const float* __restrict__ c1, const float* __restrict__ fgb,
                                 float* __restrict__ s1, float* __restrict__ sf) {
    int c = blockIdx.x, t = threadIdx.x;  // 384 blocks
    __shared__ float red[256];
    float s = 0.f;
    if (c < 128) { for (int g = t; g < GT; g += 256) s += c1[(size_t)g*128 + c]; }
    else { int cc = c - 128; for (int g = t; g < GT; g += 256) s += fgb[(size_t)g*256 + cc]; }
    red[t] = s; __syncthreads();
    for (int w = 128; w; w >>= 1) { if (t < w) red[t] += red[t + w]; __syncthreads(); }
    if (t == 0) { if (c < 128) s1[c] = red[0]; else sf[c - 128] = red[0]; }
}

__global__ void assemble_mu_kernel(const float* __restrict__ s1, const float* __restrict__ sf,
                                   const float* __restrict__ w2t, const float* __restrict__ b2,
                                   float* __restrict__ mu, float* __restrict__ w2s1) {
    int t = blockIdx.x * 256 + threadIdx.x;  // < 512
    const float inv_n = 1.0f / (float)NROW;
    if (t < 256) {
        mu[t] = sf[t] * (1.0f / (float)GT);
    } else {
        int c = t - 256;
        float s = 0.f;
        for (int k = 0; k < 128; ++k) s = __fmaf_rn(w2t[k*256 + c], s1[k], s);
        w2s1[c] = s;
        mu[t] = (s + (float)NROW * b2[c]) * inv_n;
    }
}

// C[i,j] = sum_k A[k*lda+i] * B[k*ldb+j]   (TN gemm, all dims % 16 == 0)
__global__ __launch_bounds__(256) void gemm_tn_kernel(float* __restrict__ Cm,
                                                      const float* __restrict__ Am, const float* __restrict__ Bm,
                                                      int M, int N, int Kd, int lda, int ldb) {
    __shared__ float As[16][17], Bs[16][17];
    int tx = threadIdx.x & 15, ty = threadIdx.x >> 4;
    int j = blockIdx.x * 16 + tx;
    int i = blockIdx.y * 16 + ty;
    float acc = 0.f;
    for (int k0 = 0; k0 < Kd; k0 += 16) {
        As[ty][tx] = Am[(size_t)(k0 + ty) * lda + blockIdx.y*16 + tx];
        Bs[ty][tx] = Bm[(size_t)(k0 + ty) * ldb + blockIdx.x*16 + tx];
        __syncthreads();
#pragma unroll
        for (int kk = 0; kk < 16; ++kk) acc = __fmaf_rn(As[kk][ty], Bs[kk][tx], acc);
        __syncthreads();
    }
    Cm[(size_t)i * N + j] = acc;
}

// C[i,j] = sum_k A[i*lda+k] * B[k*ldb+j]   (NN gemm, M%64==0, N%64==0, K%16==0)
__global__ __launch_bounds__(256) void gemm_nn_kernel(float* __restrict__ Cm,
                                                      const float* __restrict__ Am, const float* __restrict__ Bm,
                                                      int M, int N, int Kd, int lda, int ldb) {
    __shared__ float As[16][65], Bs[16][65];
    int t = threadIdx.x;
    int i0 = blockIdx.y * 64, j0 = blockIdx.x * 64;
    int tx = t & 15, ty = t >> 4;
    int lr = t & 63, lk = t >> 6;
    float acc[4][4];
#pragma unroll
    for (int a = 0; a < 4; ++a)
#pragma unroll
        for (int b = 0; b < 4; ++b) acc[a][b] = 0.f;
    for (int k0 = 0; k0 < Kd; k0 += 16) {
#pragma unroll
        for (int u = 0; u < 4; ++u) {
            int k = lk*4 + u;
            As[k][lr] = Am[(size_t)(i0 + lr) * lda + k0 + k];
            Bs[k][lr] = Bm[(size_t)(k0 + k) * ldb + j0 + lr];
        }
        __syncthreads();
#pragma unroll
        for (int kk = 0; kk < 16; ++kk) {
            float av[4], bv[4];
#pragma unroll
            for (int u = 0; u < 4; ++u) av[u] = As[kk][ty*4+u];
#pragma unroll
            for (int u = 0; u < 4; ++u) bv[u] = Bs[kk][tx*4+u];
#pragma unroll
            for (int a = 0; a < 4; ++a)
#pragma unroll
                for (int b = 0; b < 4; ++b) acc[a][b] = __fmaf_rn(av[a], bv[b], acc[a][b]);
        }
        __syncthreads();
    }
#pragma unroll
    for (int a = 0; a < 4; ++a)
#pragma unroll
        for (int b = 0; b < 4; ++b)
            Cm[(size_t)(i0 + ty*4 + a) * N + j0 + tx*4 + b] = acc[a][b];
}

// bn3 stats from quadratic forms: var_c = w3_c S w3_c^T / n - mean^2
__global__ __launch_bounds__(256) void bn3_params_kernel(const float* __restrict__ w3, const float* __restrict__ b3,
        const float* __restrict__ g3, const float* __restrict__ bt3,
        const float* __restrict__ sff, const float* __restrict__ sfc, const float* __restrict__ sccw,
        const float* __restrict__ sf, const float* __restrict__ w2s1, const float* __restrict__ b2,
        const float* __restrict__ mu, float* __restrict__ bn3a, float* __restrict__ bn3d) {
    int c = blockIdx.x, t = threadIdx.x;
    __shared__ float wL[512];
    __shared__ float red[256];
    wL[t]       = w3[(size_t)c*512 + t];
    wL[256 + t] = w3[(size_t)c*512 + 256 + t];
    __syncthreads();
    float v1 = 0.f, v2 = 0.f, v3 = 0.f;
    for (int i = 0; i < 256; ++i) {
        float wfi = wL[i], wci = wL[256 + i];
        v1 = __fmaf_rn(wfi, sff[(size_t)i*256 + t], v1);
        v2 = __fmaf_rn(wfi, sfc[(size_t)i*256 + t], v2);
        v3 = __fmaf_rn(wci, sccw[(size_t)i*256 + t], v3);
    }
    float wf_t = wL[t], wc_t = wL[256 + t];
    float vals[7];
    vals[0] = v1 * wf_t;
    vals[1] = v2 * wc_t;
    vals[2] = v3 * wc_t;
    vals[3] = wf_t * sf[t];
    vals[4] = wc_t * b2[t];
    vals[5] = wc_t * w2s1[t];
    vals[6] = wf_t * mu[t] + wc_t * mu[256 + t];
    float sums[7];
    for (int q = 0; q < 7; ++q) {
        red[t] = vals[q]; __syncthreads();
        for (int w = 128; w; w >>= 1) { if (t < w) red[t] += red[t + w]; __syncthreads(); }
        sums[q] = red[0]; __syncthreads();
    }
    if (t == 0) {
        float n = (float)NROW;
        float Q = 32.f*sums[0] + 2.f*(sums[1] + 32.f*sums[3]*sums[4])
                + sums[2] + 2.f*sums[5]*sums[4] + n*sums[4]*sums[4];
        float m3 = sums[6] + b3[c];
        float E2 = Q / n + 2.f*b3[c]*sums[6] + b3[c]*b3[c];
        float var = E2 - m3*m3;
        float a = rsqrtf(var + EPS) * g3[c];
        bn3a[c] = a;
        // d folds in b23 (= sums[4]) since mm3 acc = base3 + f1*W23 (no biases)
        bn3d[c] = (b3[c] + sums[4] - m3) * a + bt3[c];
    }
}

// =================== P3 (MFMA, v3) ===================
// Identical structure to v2 but WITHOUT the occupancy bound: v2's
// __launch_bounds__(512,4) forced VGPR=64 -> ~120MB/launch scratch spill
// (WRITE_SIZE 134MB vs 12.6MB of real output). Let the allocator pick (~130).
__global__ __launch_bounds__(512) void p3_mfma_kernel(
        const float* __restrict__ nbg, const float* __restrict__ w1,
        const float* __restrict__ bn1a, const float* __restrict__ bn1d,
        const ushort_t* __restrict__ w23h, const ushort_t* __restrict__ w23l,
        const ushort_t* __restrict__ w4h, const ushort_t* __restrict__ w4l,
        const float* __restrict__ base3, const float* __restrict__ bn3a, const float* __restrict__ bn3d,
        const float* __restrict__ b4, float* __restrict__ out) {
    __shared__ short f1h[64*128], f1l[64*128];   // 16 KB each
    __shared__ short f3h[64*64],  f3l[64*64];    // 8 KB each
    __shared__ float nbs[192];
    int t = threadIdx.x;
    int g0 = blockIdx.x * 2;
    if (t < 192) nbs[t] = nbg[(size_t)g0 * 96 + t];
    __syncthreads();
    // ---- f1 = relu(bn1(nb*w1)), split hi/lo, swizzled LDS ----
    {
        int cp = t & 63;            // channel pair (2cp, 2cp+1)
        int r0 = (t >> 6) * 8;      // 8 waves x 8 rows
        int c0 = cp * 2;
        float w00=w1[c0*3+0], w01=w1[c0*3+1], w02=w1[c0*3+2];
        float w10=w1[c0*3+3], w11=w1[c0*3+4], w12=w1[c0*3+5];
        float aA=bn1a[c0], dA=bn1d[c0], aB=bn1a[c0+1], dB=bn1d[c0+1];
#pragma unroll
        for (int rr = 0; rr < 8; ++rr) {
            int r = r0 + rr;
            float x = nbs[r*3], y = nbs[r*3+1], z = nbs[r*3+2];
            float mA = __fmul_rn(x, w00); mA = __fmaf_rn(y, w01, mA); mA = __fmaf_rn(z, w02, mA);
            mA = __fmaf_rn(mA, aA, dA); mA = fmaxf(mA, 0.f);
            float mB = __fmul_rn(x, w10); mB = __fmaf_rn(y, w11, mB); mB = __fmaf_rn(z, w12, mB);
            mB = __fmaf_rn(mB, aB, dB); mB = fmaxf(mB, 0.f);
            unsigned hA = bf16_rne(mA), hB = bf16_rne(mB);
            unsigned lA = bf16_rne(mA - __uint_as_float(hA << 16));
            unsigned lB = bf16_rne(mB - __uint_as_float(hB << 16));
            int off = r*256 + ((cp*4) ^ ((r&7)<<4));
            *(unsigned*)((char*)f1h + off) = hA | (hB << 16);
            *(unsigned*)((char*)f1l + off) = lA | (lB << 16);
        }
    }
    int lane = t & 63, w = t >> 6;
    int l15 = lane & 15, lh = lane >> 4;
    int m3c  = (w & 3) * 16;
    int m3rg = w >> 2;
    int m4g = w >> 2, m4n = (w & 3) * 96;

    f32x4 acc4[2][6];
#pragma unroll
    for (int mt = 0; mt < 2; ++mt)
#pragma unroll
        for (int nt = 0; nt < 6; ++nt) acc4[mt][nt] = (f32x4){0.f, 0.f, 0.f, 0.f};

    const float* b3p = base3 + (size_t)(g0 + m3rg) * 512 + m3c + lh * 4;
    f32x4 b3cur = *(const f32x4*)b3p;   // chunk 0
    __syncthreads();                    // f1 ready

    for (int chunk = 0; chunk < 8; ++chunk) {
        f32x4 b3nxt = b3cur;
        if (chunk < 7) b3nxt = *(const f32x4*)(b3p + (chunk + 1) * 64);
        // ---- mm3 (swapped): acc3[nt] = base3 + W23 * f1^T ----
        f32x4 acc3[2];
        acc3[0] = b3cur; acc3[1] = b3cur;
#pragma unroll
        for (int ks = 0; ks < 4; ++ks) {
            size_t wo = (size_t)(chunk*64 + m3c + l15) * 128 + ks*32 + lh*8;
            bf16x8 wah = *(const bf16x8*)(w23h + wo);
            bf16x8 wal = *(const bf16x8*)(w23l + wo);
#pragma unroll
            for (int nt = 0; nt < 2; ++nt) {
                int row = m3rg*32 + nt*16 + l15;
                int off = row*256 + ((ks*64 + lh*16) ^ ((row&7)<<4));
                bf16x8 fbh = *(bf16x8*)((char*)f1h + off);
                bf16x8 fbl = *(bf16x8*)((char*)f1l + off);
                acc3[nt] = __builtin_amdgcn_mfma_f32_16x16x32_bf16(wah, fbh, acc3[nt], 0, 0, 0);
                acc3[nt] = __builtin_amdgcn_mfma_f32_16x16x32_bf16(wah, fbl, acc3[nt], 0, 0, 0);
                acc3[nt] = __builtin_amdgcn_mfma_f32_16x16x32_bf16(wal, fbh, acc3[nt], 0, 0, 0);
            }
        }
        __syncthreads();   // prev chunk's mm4 reads of f3 done
        // ---- bn3+relu+split -> f3 (4 consecutive channels per lane, b64 store) ----
        {
            int cb = chunk*64 + m3c + lh*4;
            f32x4 a4 = *(const f32x4*)(bn3a + cb);
            f32x4 d4 = *(const f32x4*)(bn3d + cb);
#pragma unroll
            for (int nt = 0; nt < 2; ++nt) {
                int row = m3rg*32 + nt*16 + l15;
                unsigned hw0, hw1, lw0, lw1;
                {
                    float v0 = fmaxf(__fmaf_rn(acc3[nt][0], a4[0], d4[0]), 0.f);
                    float v1 = fmaxf(__fmaf_rn(acc3[nt][1], a4[1], d4[1]), 0.f);
                    float v2 = fmaxf(__fmaf_rn(acc3[nt][2], a4[2], d4[2]), 0.f);
                    float v3 = fmaxf(__fmaf_rn(acc3[nt][3], a4[3], d4[3]), 0.f);
                    unsigned h0 = bf16_rne(v0), h1 = bf16_rne(v1), h2 = bf16_rne(v2), h3 = bf16_rne(v3);
                    unsigned l0 = bf16_rne(v0 - __uint_as_float(h0 << 16));
                    unsigned l1 = bf16_rne(v1 - __uint_as_float(h1 << 16));
                    unsigned l2 = bf16_rne(v2 - __uint_as_float(h2 << 16));
                    unsigned l3 = bf16_rne(v3 - __uint_as_float(h3 << 16));
                    hw0 = h0 | (h1 << 16); hw1 = h2 | (h3 << 16);
                    lw0 = l0 | (l1 << 16); lw1 = l2 | (l3 << 16);
                }
                int off = row*128 + (((m3c + lh*4) * 2) ^ ((row&7)<<4));
                *(unsigned long long*)((char*)f3h + off) = (unsigned long long)hw0 | ((unsigned long long)hw1 << 32);
                *(unsigned long long*)((char*)f3l + off) = (unsigned long long)lw0 | ((unsigned long long)lw1 << 32);
            }
        }
        __syncthreads();
        // ---- mm4: acc4 += f3 * w4[:, chunk] ----
#pragma unroll
        for (int ks = 0; ks < 2; ++ks) {
            bf16x8 fah[2], fal[2];
#pragma unroll
            for (int mt = 0; mt < 2; ++mt) {
                int row = m4g*32 + mt*16 + l15;
                int off = row*128 + ((ks*64 + lh*16) ^ ((row&7)<<4));
                fah[mt] = *(bf16x8*)((char*)f3h + off);
                fal[mt] = *(bf16x8*)((char*)f3l + off);
            }
#pragma unroll
            for (int nt = 0; nt < 6; ++nt) {
                int n = m4n + nt*16 + l15;
                size_t wo = (size_t)n*512 + chunk*64 + ks*32 + lh*8;
                bf16x8 wbh = *(const bf16x8*)(w4h + wo);
                bf16x8 wbl = *(const bf16x8*)(w4l + wo);
#pragma unroll
                for (int mt = 0; mt < 2; ++mt) {
                    acc4[mt][nt] = __builtin_amdgcn_mfma_f32_16x16x32_bf16(fah[mt], wbh, acc4[mt][nt], 0, 0, 0);
                    acc4[mt][nt] = __builtin_amdgcn_mfma_f32_16x16x32_bf16(fah[mt], wbl, acc4[mt][nt], 0, 0, 0);
                    acc4[mt][nt] = __builtin_amdgcn_mfma_f32_16x16x32_bf16(fal[mt], wbh, acc4[mt][nt], 0, 0, 0);
                }
            }
        }
        b3cur = b3nxt;
    }
    // ---- epilogue: max over the wave's 32 rows, + b4 ----
    int gg = g0 + m4g;
#pragma unroll
    for (int nt = 0; nt < 6; ++nt) {
        int n = m4n + nt*16 + l15;
        float m = acc4[0][nt][0];
#pragma unroll
        for (int q = 1; q < 4; ++q) m = fmaxf(m, acc4[0][nt][q]);
#pragma unroll
        for (int q = 0; q < 4; ++q) m = fmaxf(m, acc4[1][nt][q]);
        m = fmaxf(m, __shfl_xor(m, 16));
        m = fmaxf(m, __shfl_xor(m, 32));
        if (lh == 0) out[(size_t)gg * 384 + n] = m + b4[n];
    }
}

// =================== launch ===================
extern "C" void kernel_launch(void* const* d_in, const int* in_sizes, int n_in,
                              void* d_out, int out_size, void* d_ws, size_t ws_size,
                              hipStream_t stream) {
    const float* xyz = (const float*)d_in[0];
    const float* w1  = (const float*)d_in[1];
    const float* b1  = (const float*)d_in[2];
    const float* g1  = (const float*)d_in[3];
    const float* bt1 = (const float*)d_in[4];
    const float* w2  = (const float*)d_in[5];
    const float* b2  = (const float*)d_in[6];
    const float* w3  = (const float*)d_in[7];
    const float* b3  = (const float*)d_in[8];
    const float* g3  = (const float*)d_in[9];
    const float* bt3 = (const float*)d_in[10];
    const float* w4  = (const float*)d_in[11];
    const float* b4  = (const float*)d_in[12];
    float* out = (float*)d_out;
    float* ws  = (float*)d_ws;

    if (ws_size < WS_FLOATS * sizeof(float)) return;  // leaves poison -> clean mismatch signal

    float* centers = ws + OFF_CENTERS;
    float* nb      = ws + OFF_NB;
    float* fgB     = ws + OFF_FG;
    float* c1B     = ws + OFF_C1;
    float* mom     = ws + OFF_MOM;
    float* A       = ws + OFF_A;
    float* s1      = ws + OFF_S1;
    float* sf      = ws + OFF_SF;
    float* mu      = ws + OFF_MU;
    float* w2s1    = ws + OFF_W2S1;
    float* bn1a    = ws + OFF_BN1A;
    float* bn1d    = ws + OFF_BN1D;
    float* bn3a    = ws + OFF_BN3A;
    float* bn3d    = ws + OFF_BN3D;
    float* sff     = ws + OFF_SFF;
    float* pfct    = ws + OFF_PFCT;
    float* t1m     = ws + OFF_T1;
    float* sccw    = ws + OFF_SCCW;
    float* sfcm    = ws + OFF_SFC;
    float* w2t     = ws + OFF_W2T;
    float* w3t     = ws + OFF_W3T;
    ushort_t* w4h  = (ushort_t*)(ws + OFF_W4H);
    ushort_t* w4l  = (ushort_t*)(ws + OFF_W4L);
    float* apart   = ws + OFF_APART;
    float* w23     = ws + OFF_W23;
    ushort_t* w23h = (ushort_t*)(ws + OFF_W23H);
    ushort_t* w23l = (ushort_t*)(ws + OFF_W23L);
    ushort_t* w2h  = (ushort_t*)(ws + OFF_W2H);
    ushort_t* w2l  = (ushort_t*)(ws + OFF_W2L);
    float* base3   = ws + OFF_BASE3;   // aliases apart (valid after reduce_a)

    zero_mom_kernel<<<1, 64, 0, stream>>>(mom);
    fps_kernel<<<B_, 1024, 0, stream>>>(xyz, centers);
    knn_kernel<<<GT, 256, 0, stream>>>(xyz, centers, nb);
    moments_kernel<<<NROW/256, 256, 0, stream>>>(nb, mom);
    bn1_params_kernel<<<1, 128, 0, stream>>>(mom, w1, b1, g1, bt1, bn1a, bn1d);
    transpose_kernel<<<(256*128 + 255)/256, 256, 0, stream>>>(w2t, w2, 256, 128);
    transpose_kernel<<<(512*512 + 255)/256, 256, 0, stream>>>(w3t, w3, 512, 512);
    // W23[n][k] = sum_j w3[n][256+j] * w2[j][k]  (f2-linearity fold)
    gemm_tn_kernel<<<dim3(8, 32), 256, 0, stream>>>(w23, w3t + 256*512, w2, 512, 128, 256, 512, 128);
    split_kernel<<<(65536 + 255)/256, 256, 0, stream>>>(w23, w23h, w23l, 65536);
    split_kernel<<<(196608 + 255)/256, 256, 0, stream>>>(w4, w4h, w4l, 196608);
    split_kernel<<<(32768 + 255)/256, 256, 0, stream>>>(w2, w2h, w2l, 32768);
    p1_mfma_kernel<<<512, 256, 0, stream>>>(nb, w1, bn1a, bn1d, w2h, w2l, b2, fgB, c1B, apart);
    reduce_a_kernel<<<64, 256, 0, stream>>>(apart, A);
    // base3[g][n] = sum_{k<256} fg[g][k] * w3[n][k]   (overwrites apart region)
    gemm_nn_kernel<<<dim3(8, 128), 256, 0, stream>>>(base3, fgB, w3t, GT, 512, 256, 256, 512);
    reduce_cf_kernel<<<384, 256, 0, stream>>>(c1B, fgB, s1, sf);
    assemble_mu_kernel<<<2, 256, 0, stream>>>(s1, sf, w2t, b2, mu, w2s1);
    gemm_tn_kernel<<<dim3(16,16), 256, 0, stream>>>(sff,  fgB,  fgB, 256, 256, GT,  256, 256);
    gemm_tn_kernel<<<dim3(16, 8), 256, 0, stream>>>(pfct, c1B,  fgB, 128, 256, GT,  128, 256);
    gemm_tn_kernel<<<dim3(16, 8), 256, 0, stream>>>(t1m,  A,    w2t, 128, 256, 128, 128, 256);
    gemm_tn_kernel<<<dim3(16,16), 256, 0, stream>>>(sccw, w2t,  t1m, 256, 256, 128, 256, 256);
    gemm_tn_kernel<<<dim3(16,16), 256, 0, stream>>>(sfcm, pfct, w2t, 256, 256, 128, 256, 256);
    bn3_params_kernel<<<512, 256, 0, stream>>>(w3, b3, g3, bt3, sff, sfcm, sccw, sf, w2s1, b2, mu, bn3a, bn3d);
    p3_mfma_kernel<<<GT/2, 512, 0, stream>>>(nb, w1, bn1a, bn1d, w23h, w23l, w4h, w4l,
                                             base3, bn3a, bn3d, b4, out);
}

// Round 7
// 3140.033 us; speedup vs baseline: 2.3686x; 1.0175x over previous
//
#include <hip/hip_runtime.h>
#include <cstddef>

#define B_   16
#define N_   8192
#define G_   512
#define K_   32
#define GT   8192          // B_*G_
#define NROW 262144        // GT*K_
#define EPS  1e-5f

typedef unsigned short ushort_t;
typedef short bf16x8 __attribute__((ext_vector_type(8)));
typedef float f32x4  __attribute__((ext_vector_type(4)));

// ---------------- workspace layout (float offsets) ----------------
constexpr size_t OFF_CENTERS = 0;                          // B*G*3
constexpr size_t OFF_NB      = OFF_CENTERS + 24576;        // GT*K*3
constexpr size_t OFF_FG      = OFF_NB      + 786432;       // GT*256
constexpr size_t OFF_C1      = OFF_FG      + 2097152;      // GT*128
constexpr size_t OFF_MOM     = OFF_C1      + 1048576;      // 16
constexpr size_t OFF_A       = OFF_MOM     + 16;           // 128*128
constexpr size_t OFF_S1      = OFF_A       + 16384;        // 128
constexpr size_t OFF_SF      = OFF_S1      + 128;          // 256
constexpr size_t OFF_MU      = OFF_SF      + 256;          // 512
constexpr size_t OFF_W2S1    = OFF_MU      + 512;          // 256
constexpr size_t OFF_BN1A    = OFF_W2S1    + 256;          // 128
constexpr size_t OFF_BN1D    = OFF_BN1A    + 128;          // 128
constexpr size_t OFF_BN3A    = OFF_BN1D    + 128;          // 512
constexpr size_t OFF_BN3D    = OFF_BN3A    + 512;          // 512
constexpr size_t OFF_SFF     = OFF_BN3D    + 512;          // 256*256
constexpr size_t OFF_PFCT    = OFF_SFF     + 65536;        // 128*256
constexpr size_t OFF_T1      = OFF_PFCT    + 32768;        // 128*256
constexpr size_t OFF_SCCW    = OFF_T1      + 32768;        // 256*256
constexpr size_t OFF_SFC     = OFF_SCCW    + 65536;        // 256*256
constexpr size_t OFF_W2T     = OFF_SFC     + 65536;        // 128*256
constexpr size_t OFF_W3T     = OFF_W2T     + 32768;        // 512*512
constexpr size_t OFF_W4H     = OFF_W3T     + 262144;       // 196608 ushorts (bf16 hi of w4)
constexpr size_t OFF_W4L     = OFF_W4H     + 98304;        // 196608 ushorts
constexpr size_t OFF_APART   = OFF_W4L     + 98304;        // 512 blocks * 16384
constexpr size_t OFF_W23     = OFF_APART   + 8388608;      // 512*128 f32
constexpr size_t OFF_W23H    = OFF_W23     + 65536;        // 65536 ushorts
constexpr size_t OFF_W23L    = OFF_W23H    + 32768;        // 65536 ushorts
constexpr size_t OFF_W2H     = OFF_W23L    + 32768;        // 32768 ushorts (bf16 hi of w2)
constexpr size_t OFF_W2L     = OFF_W2H     + 16384;        // 32768 ushorts
constexpr size_t WS_FLOATS   = OFF_W2L     + 16384;        // ~53.1 MB
constexpr size_t OFF_BASE3   = OFF_APART;                  // alias: base3 [8192][512] after reduce_a

__device__ __forceinline__ unsigned bf16_rne(float v) {
    unsigned u = __float_as_uint(v);
    return (u + 0x7fffu + ((u >> 16) & 1u)) >> 16;
}

// =================== FPS ===================
// One block per batch. Points + dists in registers. 2 barriers/iter.
__global__ __launch_bounds__(1024) void fps_kernel(const float* __restrict__ xyz,
                                                   float* __restrict__ centers) {
    int b = blockIdx.x, t = threadIdx.x;
    const float* xb = xyz + (size_t)b * N_ * 3;
    float px[8], py[8], pz[8], dist[8];
#pragma unroll
    for (int i = 0; i < 8; ++i) {
        int p = t + (i << 10);
        px[i] = xb[p*3]; py[i] = xb[p*3+1]; pz[i] = xb[p*3+2];
        dist[i] = 1e10f;
    }
    __shared__ float redV[2][16];
    __shared__ int   redI[2][16];
    __shared__ float cxyz[2][3];
    if (t == 0) { cxyz[0][0] = px[0]; cxyz[0][1] = py[0]; cxyz[0][2] = pz[0]; }
    __syncthreads();
    for (int it = 0; it < G_; ++it) {
        int cur = it & 1;
        float lcx = cxyz[cur][0], lcy = cxyz[cur][1], lcz = cxyz[cur][2];
        if (t == 0) {
            float* cd = centers + ((size_t)b * G_ + it) * 3;
            cd[0] = lcx; cd[1] = lcy; cd[2] = lcz;
        }
        float bv = -1.0f; int bp = 0;
#pragma unroll
        for (int i = 0; i < 8; ++i) {
            float dx = __fsub_rn(px[i], lcx);
            float dy = __fsub_rn(py[i], lcy);
            float dz = __fsub_rn(pz[i], lcz);
            float d  = __fadd_rn(__fadd_rn(__fmul_rn(dx,dx), __fmul_rn(dy,dy)), __fmul_rn(dz,dz));
            float nd = fminf(dist[i], d);
            dist[i] = nd;
            if (nd > bv) { bv = nd; bp = t + (i << 10); }
        }
#pragma unroll
        for (int off = 1; off < 64; off <<= 1) {
            float ov = __shfl_xor(bv, off);
            int   op = __shfl_xor(bp, off);
            if (ov > bv || (ov == bv && op < bp)) { bv = ov; bp = op; }
        }
        if ((t & 63) == 0) { redV[cur][t >> 6] = bv; redI[cur][t >> 6] = bp; }
        __syncthreads();
        float v = redV[cur][t & 15]; int p = redI[cur][t & 15];
#pragma unroll
        for (int off = 1; off < 16; off <<= 1) {
            float ov = __shfl_xor(v, off);
            int   op = __shfl_xor(p, off);
            if (ov > v || (ov == v && op < p)) { v = ov; p = op; }
        }
        if ((p & 1023) == t) {
            int i = p >> 10;
            cxyz[cur ^ 1][0] = px[i]; cxyz[cur ^ 1][1] = py[i]; cxyz[cur ^ 1][2] = pz[i];
        }
        __syncthreads();
    }
}

// =================== kNN + gather(centered) ===================
// Register-resident distances (32/thread) with CACHED per-thread min:
// per selection pass only the winner-owning thread rescans its 32 elements;
// everyone else reuses (bvt,bpt). Identical tie-break semantics (lowest index).
__global__ __launch_bounds__(256) void knn_kernel(const float* __restrict__ xyz,
                                                  const float* __restrict__ centers,
                                                  float* __restrict__ nb) {
    int g = blockIdx.x, t = threadIdx.x;
    int b = g >> 9;
    const float* xb = xyz + (size_t)b * N_ * 3;
    const float* c  = centers + (size_t)g * 3;
    float lcx = c[0], lcy = c[1], lcz = c[2];
    float cn2 = __fadd_rn(__fadd_rn(__fmul_rn(lcx,lcx), __fmul_rn(lcy,lcy)), __fmul_rn(lcz,lcz));
    float dreg[32];
    float bvt = 1e30f; int bpt = 0;
#pragma unroll 8
    for (int i = 0; i < 32; ++i) {
        int p = t + (i << 8);
        float x = xb[p*3], y = xb[p*3+1], z = xb[p*3+2];
        float pn2 = __fadd_rn(__fadd_rn(__fmul_rn(x,x), __fmul_rn(y,y)), __fmul_rn(z,z));
        float dot = __fadd_rn(__fadd_rn(__fmul_rn(lcx,x), __fmul_rn(lcy,y)), __fmul_rn(lcz,z));
        float d   = __fadd_rn(__fadd_rn(__fmul_rn(-2.0f,dot), cn2), pn2);
        dreg[i] = d;
        if (d < bvt) { bvt = d; bpt = p; }
    }
    __shared__ float redV[2][4];
    __shared__ int   redI[2][4];
    int myp = 0;
    for (int s = 0; s < K_; ++s) {
        float bv = bvt; int bp = bpt;
#pragma unroll
        for (int off = 1; off < 64; off <<= 1) {
            float ov = __shfl_xor(bv, off);
            int   op = __shfl_xor(bp, off);
            if (ov < bv || (ov == bv && op < bp)) { bv = ov; bp = op; }
        }
        int buf = s & 1;
        if ((t & 63) == 0) { redV[buf][t >> 6] = bv; redI[buf][t >> 6] = bp; }
        __syncthreads();
        float v = redV[buf][0]; int p = redI[buf][0];
#pragma unroll
        for (int w = 1; w < 4; ++w) {
            float ov = redV[buf][w]; int op = redI[buf][w];
            if (ov < v || (ov == v && op < p)) { v = ov; p = op; }
        }
        if (s == t) myp = p;
        if ((p & 255) == t) {
            // this thread owned the winner: invalidate + refresh cached min
#pragma unroll
            for (int i = 0; i < 32; ++i)
                if (p == t + (i << 8)) dreg[i] = 1e30f;
            bvt = 1e30f; bpt = t;
#pragma unroll
            for (int i = 0; i < 32; ++i) {
                float vv = dreg[i];
                if (vv < bvt) { bvt = vv; bpt = t + (i << 8); }
            }
        }
    }
    if (t < K_) {
        int p = myp;
        float* dst = nb + ((size_t)g * K_ + t) * 3;
        dst[0] = xb[p*3]   - lcx;
        dst[1] = xb[p*3+1] - lcy;
        dst[2] = xb[p*3+2] - lcz;
    }
}

// =================== small utility kernels ===================
__global__ void zero_mom_kernel(float* __restrict__ mom) {
    if (threadIdx.x < 16) mom[threadIdx.x] = 0.0f;
}

__global__ void moments_kernel(const float* __restrict__ nb, float* __restrict__ mom) {
    int idx = blockIdx.x * 256 + threadIdx.x;
    float x = nb[idx*3], y = nb[idx*3+1], z = nb[idx*3+2];
    float v[9] = {x, y, z, x*x, y*y, z*z, x*y, x*z, y*z};
    __shared__ float red[4][9];
    int t = threadIdx.x;
#pragma unroll
    for (int q = 0; q < 9; ++q) {
        float s = v[q];
#pragma unroll
        for (int off = 32; off; off >>= 1) s += __shfl_xor(s, off);
        if ((t & 63) == 0) red[t >> 6][q] = s;
    }
    __syncthreads();
    if (t < 9) atomicAdd(&mom[t], red[0][t] + red[1][t] + red[2][t] + red[3][t]);
}

__global__ void bn1_params_kernel(const float* __restrict__ mom,
                                  const float* __restrict__ w1, const float* __restrict__ b1,
                                  const float* __restrict__ g1, const float* __restrict__ bt1,
                                  float* __restrict__ bn1a, float* __restrict__ bn1d) {
    int c = threadIdx.x;  // 128
    const float inv_n = 1.0f / (float)NROW;
    float mx = mom[0]*inv_n, my = mom[1]*inv_n, mz = mom[2]*inv_n;
    float cxx = mom[3]*inv_n - mx*mx, cyy = mom[4]*inv_n - my*my, czz = mom[5]*inv_n - mz*mz;
    float cxy = mom[6]*inv_n - mx*my, cxz = mom[7]*inv_n - mx*mz, cyz = mom[8]*inv_n - my*mz;
    float wx = w1[c*3], wy = w1[c*3+1], wz = w1[c*3+2];
    float mean = wx*mx + wy*my + wz*mz + b1[c];
    float var  = wx*wx*cxx + wy*wy*cyy + wz*wz*czz
               + 2.0f*(wx*wy*cxy + wx*wz*cxz + wy*wz*cyz);
    float a = rsqrtf(var + EPS) * g1[c];
    bn1a[c] = a;
    bn1d[c] = (b1[c] - mean) * a + bt1[c];
}

__global__ void transpose_kernel(float* __restrict__ out, const float* __restrict__ in, int R, int C) {
    int t = blockIdx.x * blockDim.x + threadIdx.x;
    if (t < R * C) {
        int i = t / C, j = t % C;
        out[(size_t)j * R + i] = in[t];
    }
}

// split f32 -> bf16 hi (RNE) + bf16 lo (RNE of residual)
__global__ void split_kernel(const float* __restrict__ src, ushort_t* __restrict__ hi,
                             ushort_t* __restrict__ lo, int n) {
    int i = blockIdx.x * 256 + threadIdx.x;
    if (i < n) {
        float v = src[i];
        unsigned h = bf16_rne(v);
        hi[i] = (ushort_t)h;
        float r = v - __uint_as_float(h << 16);
        lo[i] = (ushort_t)bf16_rne(r);
    }
}

// =================== P1 (MFMA): per-group f1 -> fg, c1, A-partials ===================
__global__ __launch_bounds__(256) void p1_mfma_kernel(
        const float* __restrict__ nbg, const float* __restrict__ w1,
        const float* __restrict__ bn1a, const float* __restrict__ bn1d,
        const ushort_t* __restrict__ w2h, const ushort_t* __restrict__ w2l,
        const float* __restrict__ b2,
        float* __restrict__ fg, float* __restrict__ c1,
        float* __restrict__ apart) {
    __shared__ short f1h[32*128], f1l[32*128];     // [32 rows][256B] swizzled, 8KB each
    __shared__ short f1Th[128*40], f1Tl[128*40];   // [128 ch][80B pitch], 10KB each
    __shared__ float c1part[2][128];
    __shared__ float nbs[96];
    int t = threadIdx.x;
    int lane = t & 63, w = t >> 6;
    int l15 = lane & 15, lh = lane >> 4;

    f32x4 accA[2][8];
#pragma unroll
    for (int i2 = 0; i2 < 2; ++i2)
#pragma unroll
        for (int j = 0; j < 8; ++j) accA[i2][j] = (f32x4){0.f, 0.f, 0.f, 0.f};

    for (int gi = 0; gi < 16; ++gi) {
        int g = blockIdx.x * 16 + gi;
        if (gi == 0 && t < 96) nbs[t] = nbg[(size_t)g * 96 + t];
        __syncthreads();   // BAR1: nbs ready; prev group's MFMA reads of f1/f1T done
        {
            int ch = t & 127, rh = t >> 7;   // thread: 1 channel x 16 rows
            float a = bn1a[ch], d = bn1d[ch];
            float w0 = w1[ch*3], wa = w1[ch*3+1], wb = w1[ch*3+2];
            float csum = 0.f;
#pragma unroll
            for (int rr = 0; rr < 16; rr += 2) {
                int r0 = rh*16 + rr;
                unsigned hp[2], lp[2];
#pragma unroll
                for (int u = 0; u < 2; ++u) {
                    int r = r0 + u;
                    float x = nbs[r*3], y = nbs[r*3+1], z = nbs[r*3+2];
                    float m = __fmul_rn(x, w0);
                    m = __fmaf_rn(y, wa, m);
                    m = __fmaf_rn(z, wb, m);
                    m = __fmaf_rn(m, a, d);
                    m = fmaxf(m, 0.f);
                    csum = __fadd_rn(csum, m);
                    unsigned h = bf16_rne(m);
                    unsigned l = bf16_rne(m - __uint_as_float(h << 16));
                    hp[u] = h; lp[u] = l;
                    int off = r*256 + ((ch*2) ^ ((r&7)<<4));
                    *(short*)((char*)f1h + off) = (short)h;
                    *(short*)((char*)f1l + off) = (short)l;
                }
                int offT = ch*80 + r0*2;
                *(unsigned*)((char*)f1Th + offT) = hp[0] | (hp[1] << 16);
                *(unsigned*)((char*)f1Tl + offT) = lp[0] | (lp[1] << 16);
            }
            c1part[rh][ch] = csum;
        }
        __syncthreads();   // BAR2: f1/f1T/c1part ready
        if (t < 128) c1[(size_t)g*128 + t] = __fadd_rn(c1part[0][t], c1part[1][t]);
        if (gi < 15 && t < 96) nbs[t] = nbg[(size_t)(g+1) * 96 + t];  // prefetch

        // ---- f2 + fg ----
#pragma unroll
        for (int ci = 0; ci < 4; ++ci) {
            int ct = w*4 + ci;
            f32x4 acc2[2];
            acc2[0] = (f32x4){0.f,0.f,0.f,0.f};
            acc2[1] = (f32x4){0.f,0.f,0.f,0.f};
            __builtin_amdgcn_s_setprio(1);
#pragma unroll
            for (int kq = 0; kq < 4; ++kq) {
                size_t wo = (size_t)(ct*16 + l15)*128 + kq*32 + lh*8;
                bf16x8 wah = *(const bf16x8*)(w2h + wo);
                bf16x8 wal = *(const bf16x8*)(w2l + wo);
#pragma unroll
                for (int pt = 0; pt < 2; ++pt) {
                    int row = pt*16 + l15;
                    int off = row*256 + ((kq*64 + lh*16) ^ ((row&7)<<4));
                    bf16x8 fbh = *(bf16x8*)((char*)f1h + off);
                    bf16x8 fbl = *(bf16x8*)((char*)f1l + off);
                    acc2[pt] = __builtin_amdgcn_mfma_f32_16x16x32_bf16(wah, fbh, acc2[pt], 0, 0, 0);
                    acc2[pt] = __builtin_amdgcn_mfma_f32_16x16x32_bf16(wah, fbl, acc2[pt], 0, 0, 0);
                    acc2[pt] = __builtin_amdgcn_mfma_f32_16x16x32_bf16(wal, fbh, acc2[pt], 0, 0, 0);
                }
            }
            __builtin_amdgcn_s_setprio(0);
            f32x4 mx;
#pragma unroll
            for (int q = 0; q < 4; ++q) mx[q] = fmaxf(acc2[0][q], acc2[1][q]);
#pragma unroll
            for (int off = 1; off < 16; off <<= 1) {
#pragma unroll
                for (int q = 0; q < 4; ++q) mx[q] = fmaxf(mx[q], __shfl_xor(mx[q], off));
            }
            if (l15 == 0) {
                int cb = ct*16 + lh*4;
#pragma unroll
                for (int q = 0; q < 4; ++q)
                    fg[(size_t)g*256 + cb + q] = mx[q] + b2[cb + q];
            }
        }

        // ---- A += f1^T f1 ----
        {
            bf16x8 ahA[2], alA[2];
#pragma unroll
            for (int i2 = 0; i2 < 2; ++i2) {
                int chi = (2*w + i2)*16 + l15;
                int offA = chi*80 + lh*16;
                ahA[i2] = *(bf16x8*)((char*)f1Th + offA);
                alA[i2] = *(bf16x8*)((char*)f1Tl + offA);
            }
            __builtin_amdgcn_s_setprio(1);
#pragma unroll
            for (int j = 0; j < 8; ++j) {
                int chj = j*16 + l15;
                int offB = chj*80 + lh*16;
                bf16x8 bh = *(bf16x8*)((char*)f1Th + offB);
                bf16x8 bl = *(bf16x8*)((char*)f1Tl + offB);
#pragma unroll
                for (int i2 = 0; i2 < 2; ++i2) {
                    accA[i2][j] = __builtin_amdgcn_mfma_f32_16x16x32_bf16(ahA[i2], bh, accA[i2][j], 0, 0, 0);
                    accA[i2][j] = __builtin_amdgcn_mfma_f32_16x16x32_bf16(ahA[i2], bl, accA[i2][j], 0, 0, 0);
                    accA[i2][j] = __builtin_amdgcn_mfma_f32_16x16x32_bf16(alA[i2], bh, accA[i2][j], 0, 0, 0);
                }
            }
            __builtin_amdgcn_s_setprio(0);
        }
    }
    float* ap = apart + (size_t)blockIdx.x * 16384;
#pragma unroll
    for (int i2 = 0; i2 < 2; ++i2)
#pragma unroll
        for (int j = 0; j < 8; ++j)
#pragma unroll
            for (int q = 0; q < 4; ++q)
                ap[((2*w + i2)*16 + lh*4 + q)*128 + j*16 + l15] = accA[i2][j][q];
}

__global__ void reduce_a_kernel(const float* __restrict__ apart, float* __restrict__ A) {
    int e = blockIdx.x * 256 + threadIdx.x;  // < 16384
    float s = 0.f;
    for (int b = 0; b < 512; ++b) s = __fadd_rn(s, apart[(size_t)b * 16384 + e]);
    A[e] = s;
}

__global__ void reduce_cf_kernel(const float* __restrict__ c1, const float* __restrict__ fgb,
                                 float* __restrict__ s1, float* __restrict__ sf) {
    int c = blockIdx.x, t = threadIdx.x;  // 384 blocks
    __shared__ float red[256];
    float s = 0.f;
    if (c < 128) { for (int g = t; g < GT; g += 256) s += c1[(size_t)g*128 + c]; }
    else { int cc = c - 128; for (int g = t; g < GT; g += 256) s += fgb[(size_t)g*256 + cc]; }
    red[t] = s; __syncthreads();
    for (int w = 128; w; w >>= 1) { if (t < w) red[t] += red[t + w]; __syncthreads(); }
    if (t == 0) { if (c < 128) s1[c] = red[0]; else sf[c - 128] = red[0]; }
}

__global__ void assemble_mu_kernel(const float* __restrict__ s1, const float* __restrict__ sf,
                                   const float* __restrict__ w2t, const float* __restrict__ b2,
                                   float* __restrict__ mu, float* __restrict__ w2s1) {
    int t = blockIdx.x * 256 + threadIdx.x;  // < 512
    const float inv_n = 1.0f / (float)NROW;
    if (t < 256) {
        mu[t] = sf[t] * (1.0f / (float)GT);
    } else {
        int c = t - 256;
        float s = 0.f;
        for (int k = 0; k < 128; ++k) s = __fmaf_rn(w2t[k*256 + c], s1[k], s);
        w2s1[c] = s;
        mu[t] = (s + (float)NROW * b2[c]) * inv_n;
    }
}

// C[i,j] = sum_k A[k*lda+i] * B[k*ldb+j]   (TN gemm, all dims % 16 == 0)
__global__ __launch_bounds__(256) void gemm_tn_kernel(float* __restrict__ Cm,
                                                      const float* __restrict__ Am, const float* __restrict__ Bm,
                                                      int M, int N, int Kd, int lda, int ldb) {
    __shared__ float As[16][17], Bs[16][17];
    int tx = threadIdx.x & 15, ty = threadIdx.x >> 4;
    int j = blockIdx.x * 16 + tx;
    int i = blockIdx.y * 16 + ty;
    float acc = 0.f;
    for (int k0 = 0; k0 < Kd; k0 += 16) {
        As[ty][tx] = Am[(size_t)(k0 + ty) * lda + blockIdx.y*16 + tx];
        Bs[ty][tx] = Bm[(size_t)(k0 + ty) * ldb + blockIdx.x*16 + tx];
        __syncthreads();
#pragma unroll
        for (int kk = 0; kk < 16; ++kk) acc = __fmaf_rn(As[kk][ty], Bs[kk][tx], acc);
        __syncthreads();
    }
    Cm[(size_t)i * N + j] = acc;
}

// C[i,j] = sum_k A[i*lda+k] * B[k*ldb+j]   (NN gemm, M%64==0, N%64==0, K%16==0)
__global__ __launch_bounds__(256) void gemm_nn_kernel(float* __restrict__ Cm,
                                                      const float* __restrict__ Am, const float* __restrict__ Bm,
                                                      int M, int N, int Kd, int lda, int ldb) {
    __shared__ float As[16][65], Bs[16][65];
    int t = threadIdx.x;
    int i0 = blockIdx.y * 64, j0 = blockIdx.x * 64;
    int tx = t & 15, ty = t >> 4;
    int lr = t & 63, lk = t >> 6;
    float acc[4][4];
#pragma unroll
    for (int a = 0; a < 4; ++a)
#pragma unroll
        for (int b = 0; b < 4; ++b) acc[a][b] = 0.f;
    for (int k0 = 0; k0 < Kd; k0 += 16) {
#pragma unroll
        for (int u = 0; u < 4; ++u) {
            int k = lk*4 + u;
            As[k][lr] = Am[(size_t)(i0 + lr) * lda + k0 + k];
            Bs[k][lr] = Bm[(size_t)(k0 + k) * ldb + j0 + lr];
        }
        __syncthreads();
#pragma unroll
        for (int kk = 0; kk < 16; ++kk) {
            float av[4], bv[4];
#pragma unroll
            for (int u = 0; u < 4; ++u) av[u] = As[kk][ty*4+u];
#pragma unroll
            for (int u = 0; u < 4; ++u) bv[u] = Bs[kk][tx*4+u];
#pragma unroll
            for (int a = 0; a < 4; ++a)
#pragma unroll
                for (int b = 0; b < 4; ++b) acc[a][b] = __fmaf_rn(av[a], bv[b], acc[a][b]);
        }
        __syncthreads();
    }
#pragma unroll
    for (int a = 0; a < 4; ++a)
#pragma unroll
        for (int b = 0; b < 4; ++b)
            Cm[(size_t)(i0 + ty*4 + a) * N + j0 + tx*4 + b] = acc[a][b];
}

// bn3 stats from quadratic forms: var_c = w3_c S w3_c^T / n - mean^2
__global__ __launch_bounds__(256) void bn3_params_kernel(const float* __restrict__ w3, const float* __restrict__ b3,
        const float* __restrict__ g3, const float* __restrict__ bt3,
        const float* __restrict__ sff, const float* __restrict__ sfc, const float* __restrict__ sccw,
        const float* __restrict__ sf, const float* __restrict__ w2s1, const float* __restrict__ b2,
        const float* __restrict__ mu, float* __restrict__ bn3a, float* __restrict__ bn3d) {
    int c = blockIdx.x, t = threadIdx.x;
    __shared__ float wL[512];
    __shared__ float red[256];
    wL[t]       = w3[(size_t)c*512 + t];
    wL[256 + t] = w3[(size_t)c*512 + 256 + t];
    __syncthreads();
    float v1 = 0.f, v2 = 0.f, v3 = 0.f;
    for (int i = 0; i < 256; ++i) {
        float wfi = wL[i], wci = wL[256 + i];
        v1 = __fmaf_rn(wfi, sff[(size_t)i*256 + t], v1);
        v2 = __fmaf_rn(wfi, sfc[(size_t)i*256 + t], v2);
        v3 = __fmaf_rn(wci, sccw[(size_t)i*256 + t], v3);
    }
    float wf_t = wL[t], wc_t = wL[256 + t];
    float vals[7];
    vals[0] = v1 * wf_t;
    vals[1] = v2 * wc_t;
    vals[2] = v3 * wc_t;
    vals[3] = wf_t * sf[t];
    vals[4] = wc_t * b2[t];
    vals[5] = wc_t * w2s1[t];
    vals[6] = wf_t * mu[t] + wc_t * mu[256 + t];
    float sums[7];
    for (int q = 0; q < 7; ++q) {
        red[t] = vals[q]; __syncthreads();
        for (int w = 128; w; w >>= 1) { if (t < w) red[t] += red[t + w]; __syncthreads(); }
        sums[q] = red[0]; __syncthreads();
    }
    if (t == 0) {
        float n = (float)NROW;
        float Q = 32.f*sums[0] + 2.f*(sums[1] + 32.f*sums[3]*sums[4])
                + sums[2] + 2.f*sums[5]*sums[4] + n*sums[4]*sums[4];
        float m3 = sums[6] + b3[c];
        float E2 = Q / n + 2.f*b3[c]*sums[6] + b3[c]*b3[c];
        float var = E2 - m3*m3;
        float a = rsqrtf(var + EPS) * g3[c];
        bn3a[c] = a;
        bn3d[c] = (b3[c] + sums[4] - m3) * a + bt3[c];
    }
}

// =================== P3 (MFMA, v4) ===================
// v3 counters: MfmaUtil 17%, 17 barriers/block lock-stepping 8 waves = issue-bound.
// v4: f3 DOUBLE-BUFFER -> 1 barrier/chunk (write(c)->buf[c&1] vs readers of
// buf[(c-2)&1] protected by BAR(c-1) arrival; hazard-traced). nbs LDS dropped
// (nb read direct from global, L2-hot) so LDS = 65536 B exactly. T5 setprio
// around MFMA clusters (phase-split regime).
__global__ __launch_bounds__(512) void p3_mfma_kernel(
        const float* __restrict__ nbg, const float* __restrict__ w1,
        const float* __restrict__ bn1a, const float* __restrict__ bn1d,
        const ushort_t* __restrict__ w23h, const ushort_t* __restrict__ w23l,
        const ushort_t* __restrict__ w4h, const ushort_t* __restrict__ w4l,
        const float* __restrict__ base3, const float* __restrict__ bn3a, const float* __restrict__ bn3d,
        const float* __restrict__ b4, float* __restrict__ out) {
    __shared__ short f1h[64*128], f1l[64*128];       // 16 KB each
    __shared__ short f3h[2][64*64], f3l[2][64*64];   // 8 KB per buffer; total LDS = 64 KB
    int t = threadIdx.x;
    int g0 = blockIdx.x * 2;
    // ---- f1 = relu(bn1(nb*w1)) from GLOBAL nb, split hi/lo, swizzled LDS ----
    {
        int cp = t & 63;            // channel pair (2cp, 2cp+1)
        int r0 = (t >> 6) * 8;      // 8 waves x 8 rows
        int c0 = cp * 2;
        const float* nbp = nbg + (size_t)g0 * 96;
        float w00=w1[c0*3+0], w01=w1[c0*3+1], w02=w1[c0*3+2];
        float w10=w1[c0*3+3], w11=w1[c0*3+4], w12=w1[c0*3+5];
        float aA=bn1a[c0], dA=bn1d[c0], aB=bn1a[c0+1], dB=bn1d[c0+1];
#pragma unroll
        for (int rr = 0; rr < 8; ++rr) {
            int r = r0 + rr;
            float x = nbp[r*3], y = nbp[r*3+1], z = nbp[r*3+2];
            float mA = __fmul_rn(x, w00); mA = __fmaf_rn(y, w01, mA); mA = __fmaf_rn(z, w02, mA);
            mA = __fmaf_rn(mA, aA, dA); mA = fmaxf(mA, 0.f);
            float mB = __fmul_rn(x, w10); mB = __fmaf_rn(y, w11, mB); mB = __fmaf_rn(z, w12, mB);
            mB = __fmaf_rn(mB, aB, dB); mB = fmaxf(mB, 0.f);
            unsigned hA = bf16_rne(mA), hB = bf16_rne(mB);
            unsigned lA = bf16_rne(mA - __uint_as_float(hA << 16));
            unsigned lB = bf16_rne(mB - __uint_as_float(hB << 16));
            int off = r*256 + ((cp*4) ^ ((r&7)<<4));
            *(unsigned*)((char*)f1h + off) = hA | (hB << 16);
            *(unsigned*)((char*)f1l + off) = lA | (lB << 16);
        }
    }
    int lane = t & 63, w = t >> 6;
    int l15 = lane & 15, lh = lane >> 4;
    int m3c  = (w & 3) * 16;
    int m3rg = w >> 2;
    int m4g = w >> 2, m4n = (w & 3) * 96;

    f32x4 acc4[2][6];
#pragma unroll
    for (int mt = 0; mt < 2; ++mt)
#pragma unroll
        for (int nt = 0; nt < 6; ++nt) acc4[mt][nt] = (f32x4){0.f, 0.f, 0.f, 0.f};

    const float* b3p = base3 + (size_t)(g0 + m3rg) * 512 + m3c + lh * 4;
    f32x4 b3cur = *(const f32x4*)b3p;   // chunk 0
    __syncthreads();                    // f1 ready

    for (int chunk = 0; chunk < 8; ++chunk) {
        f32x4 b3nxt = b3cur;
        if (chunk < 7) b3nxt = *(const f32x4*)(b3p + (chunk + 1) * 64);
        short* f3hb = &f3h[chunk & 1][0];
        short* f3lb = &f3l[chunk & 1][0];
        // ---- mm3 (swapped): acc3[nt] = base3 + W23 * f1^T ----
        f32x4 acc3[2];
        acc3[0] = b3cur; acc3[1] = b3cur;
        __builtin_amdgcn_s_setprio(1);
#pragma unroll
        for (int ks = 0; ks < 4; ++ks) {
            size_t wo = (size_t)(chunk*64 + m3c + l15) * 128 + ks*32 + lh*8;
            bf16x8 wah = *(const bf16x8*)(w23h + wo);
            bf16x8 wal = *(const bf16x8*)(w23l + wo);
#pragma unroll
            for (int nt = 0; nt < 2; ++nt) {
                int row = m3rg*32 + nt*16 + l15;
                int off = row*256 + ((ks*64 + lh*16) ^ ((row&7)<<4));
                bf16x8 fbh = *(bf16x8*)((char*)f1h + off);
                bf16x8 fbl = *(bf16x8*)((char*)f1l + off);
                acc3[nt] = __builtin_amdgcn_mfma_f32_16x16x32_bf16(wah, fbh, acc3[nt], 0, 0, 0);
                acc3[nt] = __builtin_amdgcn_mfma_f32_16x16x32_bf16(wah, fbl, acc3[nt], 0, 0, 0);
                acc3[nt] = __builtin_amdgcn_mfma_f32_16x16x32_bf16(wal, fbh, acc3[nt], 0, 0, 0);
            }
        }
        __builtin_amdgcn_s_setprio(0);
        // ---- bn3+relu+split -> f3[chunk&1] (no barrier needed pre-write: dbuf) ----
        {
            int cb = chunk*64 + m3c + lh*4;
            f32x4 a4 = *(const f32x4*)(bn3a + cb);
            f32x4 d4 = *(const f32x4*)(bn3d + cb);
#pragma unroll
            for (int nt = 0; nt < 2; ++nt) {
                int row = m3rg*32 + nt*16 + l15;
                unsigned hw0, hw1, lw0, lw1;
                {
                    float v0 = fmaxf(__fmaf_rn(acc3[nt][0], a4[0], d4[0]), 0.f);
                    float v1 = fmaxf(__fmaf_rn(acc3[nt][1], a4[1], d4[1]), 0.f);
                    float v2 = fmaxf(__fmaf_rn(acc3[nt][2], a4[2], d4[2]), 0.f);
                    float v3 = fmaxf(__fmaf_rn(acc3[nt][3], a4[3], d4[3]), 0.f);
                    unsigned h0 = bf16_rne(v0), h1 = bf16_rne(v1), h2 = bf16_rne(v2), h3 = bf16_rne(v3);
                    unsigned l0 = bf16_rne(v0 - __uint_as_float(h0 << 16));
                    unsigned l1 = bf16_rne(v1 - __uint_as_float(h1 << 16));
                    unsigned l2 = bf16_rne(v2 - __uint_as_float(h2 << 16));
                    unsigned l3 = bf16_rne(v3 - __uint_as_float(h3 << 16));
                    hw0 = h0 | (h1 << 16); hw1 = h2 | (h3 << 16);
                    lw0 = l0 | (l1 << 16); lw1 = l2 | (l3 << 16);
                }
                int off = row*128 + (((m3c + lh*4) * 2) ^ ((row&7)<<4));
                *(unsigned long long*)((char*)f3hb + off) = (unsigned long long)hw0 | ((unsigned long long)hw1 << 32);
                *(unsigned long long*)((char*)f3lb + off) = (unsigned long long)lw0 | ((unsigned long long)lw1 << 32);
            }
        }
        __syncthreads();   // f3[chunk&1] visible; ONLY barrier per chunk
        // ---- mm4: acc4 += f3[chunk&1] * w4[:, chunk] ----
        __builtin_amdgcn_s_setprio(1);
#pragma unroll
        for (int ks = 0; ks < 2; ++ks) {
            bf16x8 fah[2], fal[2];
#pragma unroll
            for (int mt = 0; mt < 2; ++mt) {
                int row = m4g*32 + mt*16 + l15;
                int off = row*128 + ((ks*64 + lh*16) ^ ((row&7)<<4));
                fah[mt] = *(bf16x8*)((char*)f3hb + off);
                fal[mt] = *(bf16x8*)((char*)f3lb + off);
            }
#pragma unroll
            for (int nt = 0; nt < 6; ++nt) {
                int n = m4n + nt*16 + l15;
                size_t wo = (size_t)n*512 + chunk*64 + ks*32 + lh*8;
                bf16x8 wbh = *(const bf16x8*)(w4h + wo);
                bf16x8 wbl = *(const bf16x8*)(w4l + wo);
#pragma unroll
                for (int mt = 0; mt < 2; ++mt) {
                    acc4[mt][nt] = __builtin_amdgcn_mfma_f32_16x16x32_bf16(fah[mt], wbh, acc4[mt][nt], 0, 0, 0);
                    acc4[mt][nt] = __builtin_amdgcn_mfma_f32_16x16x32_bf16(fah[mt], wbl, acc4[mt][nt], 0, 0, 0);
                    acc4[mt][nt] = __builtin_amdgcn_mfma_f32_16x16x32_bf16(fal[mt], wbh, acc4[mt][nt], 0, 0, 0);
                }
            }
        }
        __builtin_amdgcn_s_setprio(0);
        b3cur = b3nxt;
    }
    // ---- epilogue: max over the wave's 32 rows, + b4 ----
    int gg = g0 + m4g;
#pragma unroll
    for (int nt = 0; nt < 6; ++nt) {
        int n = m4n + nt*16 + l15;
        float m = acc4[0][nt][0];
#pragma unroll
        for (int q = 1; q < 4; ++q) m = fmaxf(m, acc4[0][nt][q]);
#pragma unroll
        for (int q = 0; q < 4; ++q) m = fmaxf(m, acc4[1][nt][q]);
        m = fmaxf(m, __shfl_xor(m, 16));
        m = fmaxf(m, __shfl_xor(m, 32));
        if (lh == 0) out[(size_t)gg * 384 + n] = m + b4[n];
    }
}

// =================== launch ===================
extern "C" void kernel_launch(void* const* d_in, const int* in_sizes, int n_in,
                              void* d_out, int out_size, void* d_ws, size_t ws_size,
                              hipStream_t stream) {
    const float* xyz = (const float*)d_in[0];
    const float* w1  = (const float*)d_in[1];
    const float* b1  = (const float*)d_in[2];
    const float* g1  = (const float*)d_in[3];
    const float* bt1 = (const float*)d_in[4];
    const float* w2  = (const float*)d_in[5];
    const float* b2  = (const float*)d_in[6];
    const float* w3  = (const float*)d_in[7];
    const float* b3  = (const float*)d_in[8];
    const float* g3  = (const float*)d_in[9];
    const float* bt3 = (const float*)d_in[10];
    const float* w4  = (const float*)d_in[11];
    const float* b4  = (const float*)d_in[12];
    float* out = (float*)d_out;
    float* ws  = (float*)d_ws;

    if (ws_size < WS_FLOATS * sizeof(float)) return;  // leaves poison -> clean mismatch signal

    float* centers = ws + OFF_CENTERS;
    float* nb      = ws + OFF_NB;
    float* fgB     = ws + OFF_FG;
    float* c1B     = ws + OFF_C1;
    float* mom     = ws + OFF_MOM;
    float* A       = ws + OFF_A;
    float* s1      = ws + OFF_S1;
    float* sf      = ws + OFF_SF;
    float* mu      = ws + OFF_MU;
    float* w2s1    = ws + OFF_W2S1;
    float* bn1a    = ws + OFF_BN1A;
    float* bn1d    = ws + OFF_BN1D;
    float* bn3a    = ws + OFF_BN3A;
    float* bn3d    = ws + OFF_BN3D;
    float* sff     = ws + OFF_SFF;
    float* pfct    = ws + OFF_PFCT;
    float* t1m     = ws + OFF_T1;
    float* sccw    = ws + OFF_SCCW;
    float* sfcm    = ws + OFF_SFC;
    float* w2t     = ws + OFF_W2T;
    float* w3t     = ws + OFF_W3T;
    ushort_t* w4h  = (ushort_t*)(ws + OFF_W4H);
    ushort_t* w4l  = (ushort_t*)(ws + OFF_W4L);
    float* apart   = ws + OFF_APART;
    float* w23     = ws + OFF_W23;
    ushort_t* w23h = (ushort_t*)(ws + OFF_W23H);
    ushort_t* w23l = (ushort_t*)(ws + OFF_W23L);
    ushort_t* w2h  = (ushort_t*)(ws + OFF_W2H);
    ushort_t* w2l  = (ushort_t*)(ws + OFF_W2L);
    float* base3   = ws + OFF_BASE3;   // aliases apart (valid after reduce_a)

    zero_mom_kernel<<<1, 64, 0, stream>>>(mom);
    fps_kernel<<<B_, 1024, 0, stream>>>(xyz, centers);
    knn_kernel<<<GT, 256, 0, stream>>>(xyz, centers, nb);
    moments_kernel<<<NROW/256, 256, 0, stream>>>(nb, mom);
    bn1_params_kernel<<<1, 128, 0, stream>>>(mom, w1, b1, g1, bt1, bn1a, bn1d);
    transpose_kernel<<<(256*128 + 255)/256, 256, 0, stream>>>(w2t, w2, 256, 128);
    transpose_kernel<<<(512*512 + 255)/256, 256, 0, stream>>>(w3t, w3, 512, 512);
    // W23[n][k] = sum_j w3[n][256+j] * w2[j][k]  (f2-linearity fold)
    gemm_tn_kernel<<<dim3(8, 32), 256, 0, stream>>>(w23, w3t + 256*512, w2, 512, 128, 256, 512, 128);
    split_kernel<<<(65536 + 255)/256, 256, 0, stream>>>(w23, w23h, w23l, 65536);
    split_kernel<<<(196608 + 255)/256, 256, 0, stream>>>(w4, w4h, w4l, 196608);
    split_kernel<<<(32768 + 255)/256, 256, 0, stream>>>(w2, w2h, w2l, 32768);
    p1_mfma_kernel<<<512, 256, 0, stream>>>(nb, w1, bn1a, bn1d, w2h, w2l, b2, fgB, c1B, apart);
    reduce_a_kernel<<<64, 256, 0, stream>>>(apart, A);
    // base3[g][n] = sum_{k<256} fg[g][k] * w3[n][k]   (overwrites apart region)
    gemm_nn_kernel<<<dim3(8, 128), 256, 0, stream>>>(base3, fgB, w3t, GT, 512, 256, 256, 512);
    reduce_cf_kernel<<<384, 256, 0, stream>>>(c1B, fgB, s1, sf);
    assemble_mu_kernel<<<2, 256, 0, stream>>>(s1, sf, w2t, b2, mu, w2s1);
    gemm_tn_kernel<<<dim3(16,16), 256, 0, stream>>>(sff,  fgB,  fgB, 256, 256, GT,  256, 256);
    gemm_tn_kernel<<<dim3(16, 8), 256, 0, stream>>>(pfct, c1B,  fgB, 128, 256, GT,  128, 256);
    gemm_tn_kernel<<<dim3(16, 8), 256, 0, stream>>>(t1m,  A,    w2t, 128, 256, 128, 128, 256);
    gemm_tn_kernel<<<dim3(16,16), 256, 0, stream>>>(sccw, w2t,  t1m, 256, 256, 128, 256, 256);
    gemm_tn_kernel<<<dim3(16,16), 256, 0, stream>>>(sfcm, pfct, w2t, 256, 256, 128, 256, 256);
    bn3_params_kernel<<<512, 256, 0, stream>>>(w3, b3, g3, bt3, sff, sfcm, sccw, sf, w2s1, b2, mu, bn3a, bn3d);
    p3_mfma_kernel<<<GT/2, 512, 0, stream>>>(nb, w1, bn1a, bn1d, w23h, w23l, w4h, w4l,
                                             base3, bn3a, bn3d, b4, out);
}

// Round 8
// 2715.613 us; speedup vs baseline: 2.7388x; 1.1563x over previous
//
#include <hip/hip_runtime.h>
#include <cstddef>

#define B_   16
#define N_   8192
#define G_   512
#define K_   32
#define GT   8192          // B_*G_
#define NROW 262144        // GT*K_
#define EPS  1e-5f

typedef unsigned short ushort_t;
typedef short bf16x8 __attribute__((ext_vector_type(8)));
typedef float f32x4  __attribute__((ext_vector_type(4)));

// ---------------- workspace layout (float offsets) ----------------
constexpr size_t OFF_CENTERS = 0;                          // B*G*3
constexpr size_t OFF_NB      = OFF_CENTERS + 24576;        // GT*K*3
constexpr size_t OFF_FG      = OFF_NB      + 786432;       // GT*256
constexpr size_t OFF_C1      = OFF_FG      + 2097152;      // GT*128
constexpr size_t OFF_MOM     = OFF_C1      + 1048576;      // 16
constexpr size_t OFF_A       = OFF_MOM     + 16;           // 128*128
constexpr size_t OFF_S1      = OFF_A       + 16384;        // 128
constexpr size_t OFF_SF      = OFF_S1      + 128;          // 256
constexpr size_t OFF_MU      = OFF_SF      + 256;          // 512
constexpr size_t OFF_W2S1    = OFF_MU      + 512;          // 256
constexpr size_t OFF_BN1A    = OFF_W2S1    + 256;          // 128
constexpr size_t OFF_BN1D    = OFF_BN1A    + 128;          // 128
constexpr size_t OFF_BN3A    = OFF_BN1D    + 128;          // 512
constexpr size_t OFF_BN3D    = OFF_BN3A    + 512;          // 512
constexpr size_t OFF_SFF     = OFF_BN3D    + 512;          // 256*256
constexpr size_t OFF_PFCT    = OFF_SFF     + 65536;        // 128*256
constexpr size_t OFF_T1      = OFF_PFCT    + 32768;        // 128*256
constexpr size_t OFF_SCCW    = OFF_T1      + 32768;        // 256*256
constexpr size_t OFF_SFC     = OFF_SCCW    + 65536;        // 256*256
constexpr size_t OFF_W2T     = OFF_SFC     + 65536;        // 128*256
constexpr size_t OFF_W3T     = OFF_W2T     + 32768;        // 512*512
constexpr size_t OFF_W4H     = OFF_W3T     + 262144;       // 196608 ushorts (bf16 hi of w4)
constexpr size_t OFF_W4L     = OFF_W4H     + 98304;        // 196608 ushorts
constexpr size_t OFF_APART   = OFF_W4L     + 98304;        // 512 blocks * 16384
constexpr size_t OFF_W23     = OFF_APART   + 8388608;      // 512*128 f32
constexpr size_t OFF_W23H    = OFF_W23     + 65536;        // 65536 ushorts
constexpr size_t OFF_W23L    = OFF_W23H    + 32768;        // 65536 ushorts
constexpr size_t OFF_W2H     = OFF_W23L    + 32768;        // 32768 ushorts (bf16 hi of w2)
constexpr size_t OFF_W2L     = OFF_W2H     + 16384;        // 32768 ushorts
constexpr size_t WS_FLOATS   = OFF_W2L     + 16384;        // ~53.1 MB
constexpr size_t OFF_BASE3   = OFF_APART;                  // alias: base3 [8192][512] after reduce_a

__device__ __forceinline__ unsigned bf16_rne(float v) {
    unsigned u = __float_as_uint(v);
    return (u + 0x7fffu + ((u >> 16) & 1u)) >> 16;
}

// =================== FPS ===================
// One block per batch. Points + dists in registers. 2 barriers/iter.
__global__ __launch_bounds__(1024) void fps_kernel(const float* __restrict__ xyz,
                                                   float* __restrict__ centers) {
    int b = blockIdx.x, t = threadIdx.x;
    const float* xb = xyz + (size_t)b * N_ * 3;
    float px[8], py[8], pz[8], dist[8];
#pragma unroll
    for (int i = 0; i < 8; ++i) {
        int p = t + (i << 10);
        px[i] = xb[p*3]; py[i] = xb[p*3+1]; pz[i] = xb[p*3+2];
        dist[i] = 1e10f;
    }
    __shared__ float redV[2][16];
    __shared__ int   redI[2][16];
    __shared__ float cxyz[2][3];
    if (t == 0) { cxyz[0][0] = px[0]; cxyz[0][1] = py[0]; cxyz[0][2] = pz[0]; }
    __syncthreads();
    for (int it = 0; it < G_; ++it) {
        int cur = it & 1;
        float lcx = cxyz[cur][0], lcy = cxyz[cur][1], lcz = cxyz[cur][2];
        if (t == 0) {
            float* cd = centers + ((size_t)b * G_ + it) * 3;
            cd[0] = lcx; cd[1] = lcy; cd[2] = lcz;
        }
        float bv = -1.0f; int bp = 0;
#pragma unroll
        for (int i = 0; i < 8; ++i) {
            float dx = __fsub_rn(px[i], lcx);
            float dy = __fsub_rn(py[i], lcy);
            float dz = __fsub_rn(pz[i], lcz);
            float d  = __fadd_rn(__fadd_rn(__fmul_rn(dx,dx), __fmul_rn(dy,dy)), __fmul_rn(dz,dz));
            float nd = fminf(dist[i], d);
            dist[i] = nd;
            if (nd > bv) { bv = nd; bp = t + (i << 10); }
        }
#pragma unroll
        for (int off = 1; off < 64; off <<= 1) {
            float ov = __shfl_xor(bv, off);
            int   op = __shfl_xor(bp, off);
            if (ov > bv || (ov == bv && op < bp)) { bv = ov; bp = op; }
        }
        if ((t & 63) == 0) { redV[cur][t >> 6] = bv; redI[cur][t >> 6] = bp; }
        __syncthreads();
        float v = redV[cur][t & 15]; int p = redI[cur][t & 15];
#pragma unroll
        for (int off = 1; off < 16; off <<= 1) {
            float ov = __shfl_xor(v, off);
            int   op = __shfl_xor(p, off);
            if (ov > v || (ov == v && op < p)) { v = ov; p = op; }
        }
        if ((p & 1023) == t) {
            int i = p >> 10;
            cxyz[cur ^ 1][0] = px[i]; cxyz[cur ^ 1][1] = py[i]; cxyz[cur ^ 1][2] = pz[i];
        }
        __syncthreads();
    }
}

// =================== kNN + gather(centered) ===================
// Register-resident distances (32/thread) with CACHED per-thread min.
__global__ __launch_bounds__(256) void knn_kernel(const float* __restrict__ xyz,
                                                  const float* __restrict__ centers,
                                                  float* __restrict__ nb) {
    int g = blockIdx.x, t = threadIdx.x;
    int b = g >> 9;
    const float* xb = xyz + (size_t)b * N_ * 3;
    const float* c  = centers + (size_t)g * 3;
    float lcx = c[0], lcy = c[1], lcz = c[2];
    float cn2 = __fadd_rn(__fadd_rn(__fmul_rn(lcx,lcx), __fmul_rn(lcy,lcy)), __fmul_rn(lcz,lcz));
    float dreg[32];
    float bvt = 1e30f; int bpt = 0;
#pragma unroll 8
    for (int i = 0; i < 32; ++i) {
        int p = t + (i << 8);
        float x = xb[p*3], y = xb[p*3+1], z = xb[p*3+2];
        float pn2 = __fadd_rn(__fadd_rn(__fmul_rn(x,x), __fmul_rn(y,y)), __fmul_rn(z,z));
        float dot = __fadd_rn(__fadd_rn(__fmul_rn(lcx,x), __fmul_rn(lcy,y)), __fmul_rn(lcz,z));
        float d   = __fadd_rn(__fadd_rn(__fmul_rn(-2.0f,dot), cn2), pn2);
        dreg[i] = d;
        if (d < bvt) { bvt = d; bpt = p; }
    }
    __shared__ float redV[2][4];
    __shared__ int   redI[2][4];
    int myp = 0;
    for (int s = 0; s < K_; ++s) {
        float bv = bvt; int bp = bpt;
#pragma unroll
        for (int off = 1; off < 64; off <<= 1) {
            float ov = __shfl_xor(bv, off);
            int   op = __shfl_xor(bp, off);
            if (ov < bv || (ov == bv && op < bp)) { bv = ov; bp = op; }
        }
        int buf = s & 1;
        if ((t & 63) == 0) { redV[buf][t >> 6] = bv; redI[buf][t >> 6] = bp; }
        __syncthreads();
        float v = redV[buf][0]; int p = redI[buf][0];
#pragma unroll
        for (int w = 1; w < 4; ++w) {
            float ov = redV[buf][w]; int op = redI[buf][w];
            if (ov < v || (ov == v && op < p)) { v = ov; p = op; }
        }
        if (s == t) myp = p;
        if ((p & 255) == t) {
#pragma unroll
            for (int i = 0; i < 32; ++i)
                if (p == t + (i << 8)) dreg[i] = 1e30f;
            bvt = 1e30f; bpt = t;
#pragma unroll
            for (int i = 0; i < 32; ++i) {
                float vv = dreg[i];
                if (vv < bvt) { bvt = vv; bpt = t + (i << 8); }
            }
        }
    }
    if (t < K_) {
        int p = myp;
        float* dst = nb + ((size_t)g * K_ + t) * 3;
        dst[0] = xb[p*3]   - lcx;
        dst[1] = xb[p*3+1] - lcy;
        dst[2] = xb[p*3+2] - lcz;
    }
}

// =================== small utility kernels ===================
__global__ void zero_mom_kernel(float* __restrict__ mom) {
    if (threadIdx.x < 16) mom[threadIdx.x] = 0.0f;
}

__global__ void moments_kernel(const float* __restrict__ nb, float* __restrict__ mom) {
    int idx = blockIdx.x * 256 + threadIdx.x;
    float x = nb[idx*3], y = nb[idx*3+1], z = nb[idx*3+2];
    float v[9] = {x, y, z, x*x, y*y, z*z, x*y, x*z, y*z};
    __shared__ float red[4][9];
    int t = threadIdx.x;
#pragma unroll
    for (int q = 0; q < 9; ++q) {
        float s = v[q];
#pragma unroll
        for (int off = 32; off; off >>= 1) s += __shfl_xor(s, off);
        if ((t & 63) == 0) red[t >> 6][q] = s;
    }
    __syncthreads();
    if (t < 9) atomicAdd(&mom[t], red[0][t] + red[1][t] + red[2][t] + red[3][t]);
}

__global__ void bn1_params_kernel(const float* __restrict__ mom,
                                  const float* __restrict__ w1, const float* __restrict__ b1,
                                  const float* __restrict__ g1, const float* __restrict__ bt1,
                                  float* __restrict__ bn1a, float* __restrict__ bn1d) {
    int c = threadIdx.x;  // 128
    const float inv_n = 1.0f / (float)NROW;
    float mx = mom[0]*inv_n, my = mom[1]*inv_n, mz = mom[2]*inv_n;
    float cxx = mom[3]*inv_n - mx*mx, cyy = mom[4]*inv_n - my*my, czz = mom[5]*inv_n - mz*mz;
    float cxy = mom[6]*inv_n - mx*my, cxz = mom[7]*inv_n - mx*mz, cyz = mom[8]*inv_n - my*mz;
    float wx = w1[c*3], wy = w1[c*3+1], wz = w1[c*3+2];
    float mean = wx*mx + wy*my + wz*mz + b1[c];
    float var  = wx*wx*cxx + wy*wy*cyy + wz*wz*czz
               + 2.0f*(wx*wy*cxy + wx*wz*cxz + wy*wz*cyz);
    float a = rsqrtf(var + EPS) * g1[c];
    bn1a[c] = a;
    bn1d[c] = (b1[c] - mean) * a + bt1[c];
}

__global__ void transpose_kernel(float* __restrict__ out, const float* __restrict__ in, int R, int C) {
    int t = blockIdx.x * blockDim.x + threadIdx.x;
    if (t < R * C) {
        int i = t / C, j = t % C;
        out[(size_t)j * R + i] = in[t];
    }
}

// split f32 -> bf16 hi (RNE) + bf16 lo (RNE of residual)
__global__ void split_kernel(const float* __restrict__ src, ushort_t* __restrict__ hi,
                             ushort_t* __restrict__ lo, int n) {
    int i = blockIdx.x * 256 + threadIdx.x;
    if (i < n) {
        float v = src[i];
        unsigned h = bf16_rne(v);
        hi[i] = (ushort_t)h;
        float r = v - __uint_as_float(h << 16);
        lo[i] = (ushort_t)bf16_rne(r);
    }
}

// =================== P1 (MFMA): per-group f1 -> fg, c1, A-partials ===================
__global__ __launch_bounds__(256) void p1_mfma_kernel(
        const float* __restrict__ nbg, const float* __restrict__ w1,
        const float* __restrict__ bn1a, const float* __restrict__ bn1d,
        const ushort_t* __restrict__ w2h, const ushort_t* __restrict__ w2l,
        const float* __restrict__ b2,
        float* __restrict__ fg, float* __restrict__ c1,
        float* __restrict__ apart) {
    __shared__ short f1h[32*128], f1l[32*128];     // [32 rows][256B] swizzled, 8KB each
    __shared__ short f1Th[128*40], f1Tl[128*40];   // [128 ch][80B pitch], 10KB each
    __shared__ float c1part[2][128];
    __shared__ float nbs[96];
    int t = threadIdx.x;
    int lane = t & 63, w = t >> 6;
    int l15 = lane & 15, lh = lane >> 4;

    f32x4 accA[2][8];
#pragma unroll
    for (int i2 = 0; i2 < 2; ++i2)
#pragma unroll
        for (int j = 0; j < 8; ++j) accA[i2][j] = (f32x4){0.f, 0.f, 0.f, 0.f};

    for (int gi = 0; gi < 16; ++gi) {
        int g = blockIdx.x * 16 + gi;
        if (gi == 0 && t < 96) nbs[t] = nbg[(size_t)g * 96 + t];
        __syncthreads();   // BAR1: nbs ready; prev group's MFMA reads of f1/f1T done
        {
            int ch = t & 127, rh = t >> 7;   // thread: 1 channel x 16 rows
            float a = bn1a[ch], d = bn1d[ch];
            float w0 = w1[ch*3], wa = w1[ch*3+1], wb = w1[ch*3+2];
            float csum = 0.f;
#pragma unroll
            for (int rr = 0; rr < 16; rr += 2) {
                int r0 = rh*16 + rr;
                unsigned hp[2], lp[2];
#pragma unroll
                for (int u = 0; u < 2; ++u) {
                    int r = r0 + u;
                    float x = nbs[r*3], y = nbs[r*3+1], z = nbs[r*3+2];
                    float m = __fmul_rn(x, w0);
                    m = __fmaf_rn(y, wa, m);
                    m = __fmaf_rn(z, wb, m);
                    m = __fmaf_rn(m, a, d);
                    m = fmaxf(m, 0.f);
                    csum = __fadd_rn(csum, m);
                    unsigned h = bf16_rne(m);
                    unsigned l = bf16_rne(m - __uint_as_float(h << 16));
                    hp[u] = h; lp[u] = l;
                    int off = r*256 + ((ch*2) ^ ((r&7)<<4));
                    *(short*)((char*)f1h + off) = (short)h;
                    *(short*)((char*)f1l + off) = (short)l;
                }
                int offT = ch*80 + r0*2;
                *(unsigned*)((char*)f1Th + offT) = hp[0] | (hp[1] << 16);
                *(unsigned*)((char*)f1Tl + offT) = lp[0] | (lp[1] << 16);
            }
            c1part[rh][ch] = csum;
        }
        __syncthreads();   // BAR2: f1/f1T/c1part ready
        if (t < 128) c1[(size_t)g*128 + t] = __fadd_rn(c1part[0][t], c1part[1][t]);
        if (gi < 15 && t < 96) nbs[t] = nbg[(size_t)(g+1) * 96 + t];  // prefetch

        // ---- f2 + fg ----
#pragma unroll
        for (int ci = 0; ci < 4; ++ci) {
            int ct = w*4 + ci;
            f32x4 acc2[2];
            acc2[0] = (f32x4){0.f,0.f,0.f,0.f};
            acc2[1] = (f32x4){0.f,0.f,0.f,0.f};
            __builtin_amdgcn_s_setprio(1);
#pragma unroll
            for (int kq = 0; kq < 4; ++kq) {
                size_t wo = (size_t)(ct*16 + l15)*128 + kq*32 + lh*8;
                bf16x8 wah = *(const bf16x8*)(w2h + wo);
                bf16x8 wal = *(const bf16x8*)(w2l + wo);
#pragma unroll
                for (int pt = 0; pt < 2; ++pt) {
                    int row = pt*16 + l15;
                    int off = row*256 + ((kq*64 + lh*16) ^ ((row&7)<<4));
                    bf16x8 fbh = *(bf16x8*)((char*)f1h + off);
                    bf16x8 fbl = *(bf16x8*)((char*)f1l + off);
                    acc2[pt] = __builtin_amdgcn_mfma_f32_16x16x32_bf16(wah, fbh, acc2[pt], 0, 0, 0);
                    acc2[pt] = __builtin_amdgcn_mfma_f32_16x16x32_bf16(wah, fbl, acc2[pt], 0, 0, 0);
                    acc2[pt] = __builtin_amdgcn_mfma_f32_16x16x32_bf16(wal, fbh, acc2[pt], 0, 0, 0);
                }
            }
            __builtin_amdgcn_s_setprio(0);
            f32x4 mx;
#pragma unroll
            for (int q = 0; q < 4; ++q) mx[q] = fmaxf(acc2[0][q], acc2[1][q]);
#pragma unroll
            for (int off = 1; off < 16; off <<= 1) {
#pragma unroll
                for (int q = 0; q < 4; ++q) mx[q] = fmaxf(mx[q], __shfl_xor(mx[q], off));
            }
            if (l15 == 0) {
                int cb = ct*16 + lh*4;
#pragma unroll
                for (int q = 0; q < 4; ++q)
                    fg[(size_t)g*256 + cb + q] = mx[q] + b2[cb + q];
            }
        }

        // ---- A += f1^T f1 ----
        {
            bf16x8 ahA[2], alA[2];
#pragma unroll
            for (int i2 = 0; i2 < 2; ++i2) {
                int chi = (2*w + i2)*16 + l15;
                int offA = chi*80 + lh*16;
                ahA[i2] = *(bf16x8*)((char*)f1Th + offA);
                alA[i2] = *(bf16x8*)((char*)f1Tl + offA);
            }
            __builtin_amdgcn_s_setprio(1);
#pragma unroll
            for (int j = 0; j < 8; ++j) {
                int chj = j*16 + l15;
                int offB = chj*80 + lh*16;
                bf16x8 bh = *(bf16x8*)((char*)f1Th + offB);
                bf16x8 bl = *(bf16x8*)((char*)f1Tl + offB);
#pragma unroll
                for (int i2 = 0; i2 < 2; ++i2) {
                    accA[i2][j] = __builtin_amdgcn_mfma_f32_16x16x32_bf16(ahA[i2], bh, accA[i2][j], 0, 0, 0);
                    accA[i2][j] = __builtin_amdgcn_mfma_f32_16x16x32_bf16(ahA[i2], bl, accA[i2][j], 0, 0, 0);
                    accA[i2][j] = __builtin_amdgcn_mfma_f32_16x16x32_bf16(alA[i2], bh, accA[i2][j], 0, 0, 0);
                }
            }
            __builtin_amdgcn_s_setprio(0);
        }
    }
    float* ap = apart + (size_t)blockIdx.x * 16384;
#pragma unroll
    for (int i2 = 0; i2 < 2; ++i2)
#pragma unroll
        for (int j = 0; j < 8; ++j)
#pragma unroll
            for (int q = 0; q < 4; ++q)
                ap[((2*w + i2)*16 + lh*4 + q)*128 + j*16 + l15] = accA[i2][j][q];
}

__global__ void reduce_a_kernel(const float* __restrict__ apart, float* __restrict__ A) {
    int e = blockIdx.x * 256 + threadIdx.x;  // < 16384
    float s = 0.f;
    for (int b = 0; b < 512; ++b) s = __fadd_rn(s, apart[(size_t)b * 16384 + e]);
    A[e] = s;
}

__global__ void reduce_cf_kernel(const float* __restrict__ c1, const float* __restrict__ fgb,
                                 float* __restrict__ s1, float* __restrict__ sf) {
    int c = blockIdx.x, t = threadIdx.x;  // 384 blocks
    __shared__ float red[256];
    float s = 0.f;
    if (c < 128) { for (int g = t; g < GT; g += 256) s += c1[(size_t)g*128 + c]; }
    else { int cc = c - 128; for (int g = t; g < GT; g += 256) s += fgb[(size_t)g*256 + cc]; }
    red[t] = s; __syncthreads();
    for (int w = 128; w; w >>= 1) { if (t < w) red[t] += red[t + w]; __syncthreads(); }
    if (t == 0) { if (c < 128) s1[c] = red[0]; else sf[c - 128] = red[0]; }
}

__global__ void assemble_mu_kernel(const float* __restrict__ s1, const float* __restrict__ sf,
                                   const float* __restrict__ w2t, const float* __restrict__ b2,
                                   float* __restrict__ mu, float* __restrict__ w2s1) {
    int t = blockIdx.x * 256 + threadIdx.x;  // < 512
    const float inv_n = 1.0f / (float)NROW;
    if (t < 256) {
        mu[t] = sf[t] * (1.0f / (float)GT);
    } else {
        int c = t - 256;
        float s = 0.f;
        for (int k = 0; k < 128; ++k) s = __fmaf_rn(w2t[k*256 + c], s1[k], s);
        w2s1[c] = s;
        mu[t] = (s + (float)NROW * b2[c]) * inv_n;
    }
}

// C[i,j] = sum_k A[k*lda+i] * B[k*ldb+j]   (TN gemm, all dims % 16 == 0)
__global__ __launch_bounds__(256) void gemm_tn_kernel(float* __restrict__ Cm,
                                                      const float* __restrict__ Am, const float* __restrict__ Bm,
                                                      int M, int N, int Kd, int lda, int ldb) {
    __shared__ float As[16][17], Bs[16][17];
    int tx = threadIdx.x & 15, ty = threadIdx.x >> 4;
    int j = blockIdx.x * 16 + tx;
    int i = blockIdx.y * 16 + ty;
    float acc = 0.f;
    for (int k0 = 0; k0 < Kd; k0 += 16) {
        As[ty][tx] = Am[(size_t)(k0 + ty) * lda + blockIdx.y*16 + tx];
        Bs[ty][tx] = Bm[(size_t)(k0 + ty) * ldb + blockIdx.x*16 + tx];
        __syncthreads();
#pragma unroll
        for (int kk = 0; kk < 16; ++kk) acc = __fmaf_rn(As[kk][ty], Bs[kk][tx], acc);
        __syncthreads();
    }
    Cm[(size_t)i * N + j] = acc;
}

// C[i,j] = sum_k A[i*lda+k] * B[k*ldb+j]   (NN gemm, M%64==0, N%64==0, K%16==0)
__global__ __launch_bounds__(256) void gemm_nn_kernel(float* __restrict__ Cm,
                                                      const float* __restrict__ Am, const float* __restrict__ Bm,
                                                      int M, int N, int Kd, int lda, int ldb) {
    __shared__ float As[16][65], Bs[16][65];
    int t = threadIdx.x;
    int i0 = blockIdx.y * 64, j0 = blockIdx.x * 64;
    int tx = t & 15, ty = t >> 4;
    int lr = t & 63, lk = t >> 6;
    float acc[4][4];
#pragma unroll
    for (int a = 0; a < 4; ++a)
#pragma unroll
        for (int b = 0; b < 4; ++b) acc[a][b] = 0.f;
    for (int k0 = 0; k0 < Kd; k0 += 16) {
#pragma unroll
        for (int u = 0; u < 4; ++u) {
            int k = lk*4 + u;
            As[k][lr] = Am[(size_t)(i0 + lr) * lda + k0 + k];
            Bs[k][lr] = Bm[(size_t)(k0 + k) * ldb + j0 + lr];
        }
        __syncthreads();
#pragma unroll
        for (int kk = 0; kk < 16; ++kk) {
            float av[4], bv[4];
#pragma unroll
            for (int u = 0; u < 4; ++u) av[u] = As[kk][ty*4+u];
#pragma unroll
            for (int u = 0; u < 4; ++u) bv[u] = Bs[kk][tx*4+u];
#pragma unroll
            for (int a = 0; a < 4; ++a)
#pragma unroll
                for (int b = 0; b < 4; ++b) acc[a][b] = __fmaf_rn(av[a], bv[b], acc[a][b]);
        }
        __syncthreads();
    }
#pragma unroll
    for (int a = 0; a < 4; ++a)
#pragma unroll
        for (int b = 0; b < 4; ++b)
            Cm[(size_t)(i0 + ty*4 + a) * N + j0 + tx*4 + b] = acc[a][b];
}

// bn3 stats from quadratic forms: var_c = w3_c S w3_c^T / n - mean^2
__global__ __launch_bounds__(256) void bn3_params_kernel(const float* __restrict__ w3, const float* __restrict__ b3,
        const float* __restrict__ g3, const float* __restrict__ bt3,
        const float* __restrict__ sff, const float* __restrict__ sfc, const float* __restrict__ sccw,
        const float* __restrict__ sf, const float* __restrict__ w2s1, const float* __restrict__ b2,
        const float* __restrict__ mu, float* __restrict__ bn3a, float* __restrict__ bn3d) {
    int c = blockIdx.x, t = threadIdx.x;
    __shared__ float wL[512];
    __shared__ float red[256];
    wL[t]       = w3[(size_t)c*512 + t];
    wL[256 + t] = w3[(size_t)c*512 + 256 + t];
    __syncthreads();
    float v1 = 0.f, v2 = 0.f, v3 = 0.f;
    for (int i = 0; i < 256; ++i) {
        float wfi = wL[i], wci = wL[256 + i];
        v1 = __fmaf_rn(wfi, sff[(size_t)i*256 + t], v1);
        v2 = __fmaf_rn(wfi, sfc[(size_t)i*256 + t], v2);
        v3 = __fmaf_rn(wci, sccw[(size_t)i*256 + t], v3);
    }
    float wf_t = wL[t], wc_t = wL[256 + t];
    float vals[7];
    vals[0] = v1 * wf_t;
    vals[1] = v2 * wc_t;
    vals[2] = v3 * wc_t;
    vals[3] = wf_t * sf[t];
    vals[4] = wc_t * b2[t];
    vals[5] = wc_t * w2s1[t];
    vals[6] = wf_t * mu[t] + wc_t * mu[256 + t];
    float sums[7];
    for (int q = 0; q < 7; ++q) {
        red[t] = vals[q]; __syncthreads();
        for (int w = 128; w; w >>= 1) { if (t < w) red[t] += red[t + w]; __syncthreads(); }
        sums[q] = red[0]; __syncthreads();
    }
    if (t == 0) {
        float n = (float)NROW;
        float Q = 32.f*sums[0] + 2.f*(sums[1] + 32.f*sums[3]*sums[4])
                + sums[2] + 2.f*sums[5]*sums[4] + n*sums[4]*sums[4];
        float m3 = sums[6] + b3[c];
        float E2 = Q / n + 2.f*b3[c]*sums[6] + b3[c]*b3[c];
        float var = E2 - m3*m3;
        float a = rsqrtf(var + EPS) * g3[c];
        bn3a[c] = a;
        bn3d[c] = (b3[c] + sums[4] - m3) * a + bt3[c];
    }
}

// =================== P3 (MFMA, v5: weight dedup via 128-ch super-chunks) ===================
// v4 diagnosis: L2-load-latency bound (MfmaUtil 17%, weight bytes read 2x by the
// two row-group wave-sets, only 64 VGPRs for prefetch at 2 blocks/CU).
// v5: each wave covers ALL 64 rows (both groups) for its own channel/output slice:
//   mm3: 8 waves x 16 chans x 4 row-tiles (acc3[4]), super-chunk = 128 chans;
//   mm4: 8 waves x 48 out-cols x 4 row-tiles (acc4[4][3]).
// Every w23/w4 byte now read ONCE per block (1.02 MB vs 2.1 MB) and each load
// phase covers 2x the MFMA work. f3 single-buffered [64][128] (LDS 64 KB,
// 2 blocks/CU kept); 2 barriers per super-chunk (8+1 total, same as v4).
__global__ __launch_bounds__(512) void p3_mfma_kernel(
        const float* __restrict__ nbg, const float* __restrict__ w1,
        const float* __restrict__ bn1a, const float* __restrict__ bn1d,
        const ushort_t* __restrict__ w23h, const ushort_t* __restrict__ w23l,
        const ushort_t* __restrict__ w4h, const ushort_t* __restrict__ w4l,
        const float* __restrict__ base3, const float* __restrict__ bn3a, const float* __restrict__ bn3d,
        const float* __restrict__ b4, float* __restrict__ out) {
    __shared__ short f1h[64*128], f1l[64*128];   // 16 KB each
    __shared__ short f3h[64*128], f3l[64*128];   // 16 KB each; total LDS = 64 KB
    int t = threadIdx.x;
    int g0 = blockIdx.x * 2;
    // ---- f1 = relu(bn1(nb*w1)) from global nb, split hi/lo, swizzled LDS ----
    {
        int cp = t & 63;            // channel pair (2cp, 2cp+1)
        int r0 = (t >> 6) * 8;      // 8 waves x 8 rows
        int c0 = cp * 2;
        const float* nbp = nbg + (size_t)g0 * 96;
        float w00=w1[c0*3+0], w01=w1[c0*3+1], w02=w1[c0*3+2];
        float w10=w1[c0*3+3], w11=w1[c0*3+4], w12=w1[c0*3+5];
        float aA=bn1a[c0], dA=bn1d[c0], aB=bn1a[c0+1], dB=bn1d[c0+1];
#pragma unroll
        for (int rr = 0; rr < 8; ++rr) {
            int r = r0 + rr;
            float x = nbp[r*3], y = nbp[r*3+1], z = nbp[r*3+2];
            float mA = __fmul_rn(x, w00); mA = __fmaf_rn(y, w01, mA); mA = __fmaf_rn(z, w02, mA);
            mA = __fmaf_rn(mA, aA, dA); mA = fmaxf(mA, 0.f);
            float mB = __fmul_rn(x, w10); mB = __fmaf_rn(y, w11, mB); mB = __fmaf_rn(z, w12, mB);
            mB = __fmaf_rn(mB, aB, dB); mB = fmaxf(mB, 0.f);
            unsigned hA = bf16_rne(mA), hB = bf16_rne(mB);
            unsigned lA = bf16_rne(mA - __uint_as_float(hA << 16));
            unsigned lB = bf16_rne(mB - __uint_as_float(hB << 16));
            int off = r*256 + ((cp*4) ^ ((r&7)<<4));
            *(unsigned*)((char*)f1h + off) = hA | (hB << 16);
            *(unsigned*)((char*)f1l + off) = lA | (lB << 16);
        }
    }
    int lane = t & 63, w = t >> 6;
    int l15 = lane & 15, lh = lane >> 4;

    f32x4 acc4[4][3];   // [mt: 2 groups x 2 point-tiles][nt: 3 x 16 out-cols]
#pragma unroll
    for (int mt = 0; mt < 4; ++mt)
#pragma unroll
        for (int nt = 0; nt < 3; ++nt) acc4[mt][nt] = (f32x4){0.f, 0.f, 0.f, 0.f};

    // base3 slice for this wave's channel block (per group), super-chunk 0
    const float* b3p0 = base3 + (size_t)g0 * 512 + w*16 + lh*4;
    const float* b3p1 = base3 + (size_t)(g0 + 1) * 512 + w*16 + lh*4;
    f32x4 b3c0 = *(const f32x4*)b3p0;
    f32x4 b3c1 = *(const f32x4*)b3p1;
    __syncthreads();                    // f1 ready

    for (int sc = 0; sc < 4; ++sc) {
        f32x4 b3n0 = b3c0, b3n1 = b3c1;
        if (sc < 3) {
            b3n0 = *(const f32x4*)(b3p0 + (sc + 1) * 128);
            b3n1 = *(const f32x4*)(b3p1 + (sc + 1) * 128);
        }
        // ---- mm3 (swapped): acc3[mt] = base3 + W23 * f1^T, 16 chans/wave, 64 rows ----
        f32x4 acc3[4];
        acc3[0] = b3c0; acc3[1] = b3c0; acc3[2] = b3c1; acc3[3] = b3c1;
        __builtin_amdgcn_s_setprio(1);
#pragma unroll
        for (int ks = 0; ks < 4; ++ks) {
            size_t wo = (size_t)(sc*128 + w*16 + l15) * 128 + ks*32 + lh*8;
            bf16x8 wah = *(const bf16x8*)(w23h + wo);
            bf16x8 wal = *(const bf16x8*)(w23l + wo);
#pragma unroll
            for (int mt = 0; mt < 4; ++mt) {
                int row = mt*16 + l15;
                int off = row*256 + ((ks*64 + lh*16) ^ ((row&7)<<4));
                bf16x8 fbh = *(bf16x8*)((char*)f1h + off);
                bf16x8 fbl = *(bf16x8*)((char*)f1l + off);
                acc3[mt] = __builtin_amdgcn_mfma_f32_16x16x32_bf16(wah, fbh, acc3[mt], 0, 0, 0);
                acc3[mt] = __builtin_amdgcn_mfma_f32_16x16x32_bf16(wah, fbl, acc3[mt], 0, 0, 0);
                acc3[mt] = __builtin_amdgcn_mfma_f32_16x16x32_bf16(wal, fbh, acc3[mt], 0, 0, 0);
            }
        }
        __builtin_amdgcn_s_setprio(0);
        __syncthreads();   // BAR A: all waves' mm4 reads of prev f3 done
        // ---- bn3+relu+split -> f3 [64 rows][128 ch] (4 consecutive ch/lane, b64) ----
        {
            int cb = sc*128 + w*16 + lh*4;
            f32x4 a4 = *(const f32x4*)(bn3a + cb);
            f32x4 d4 = *(const f32x4*)(bn3d + cb);
#pragma unroll
            for (int mt = 0; mt < 4; ++mt) {
                int row = mt*16 + l15;
                unsigned hw0, hw1, lw0, lw1;
                {
                    float v0 = fmaxf(__fmaf_rn(acc3[mt][0], a4[0], d4[0]), 0.f);
                    float v1 = fmaxf(__fmaf_rn(acc3[mt][1], a4[1], d4[1]), 0.f);
                    float v2 = fmaxf(__fmaf_rn(acc3[mt][2], a4[2], d4[2]), 0.f);
                    float v3 = fmaxf(__fmaf_rn(acc3[mt][3], a4[3], d4[3]), 0.f);
                    unsigned h0 = bf16_rne(v0), h1 = bf16_rne(v1), h2 = bf16_rne(v2), h3 = bf16_rne(v3);
                    unsigned l0 = bf16_rne(v0 - __uint_as_float(h0 << 16));
                    unsigned l1 = bf16_rne(v1 - __uint_as_float(h1 << 16));
                    unsigned l2 = bf16_rne(v2 - __uint_as_float(h2 << 16));
                    unsigned l3 = bf16_rne(v3 - __uint_as_float(h3 << 16));
                    hw0 = h0 | (h1 << 16); hw1 = h2 | (h3 << 16);
                    lw0 = l0 | (l1 << 16); lw1 = l2 | (l3 << 16);
                }
                int off = row*256 + ((w*32 + lh*8) ^ ((row&7)<<4));
                *(unsigned long long*)((char*)f3h + off) = (unsigned long long)hw0 | ((unsigned long long)hw1 << 32);
                *(unsigned long long*)((char*)f3l + off) = (unsigned long long)lw0 | ((unsigned long long)lw1 << 32);
            }
        }
        __syncthreads();   // BAR B: f3 ready
        // ---- mm4: acc4 += f3 * w4[:, sc] — 48 out-cols/wave, 64 rows ----
        __builtin_amdgcn_s_setprio(1);
#pragma unroll
        for (int ks = 0; ks < 4; ++ks) {
            bf16x8 wbh[3], wbl[3];
#pragma unroll
            for (int nt = 0; nt < 3; ++nt) {
                int n = w*48 + nt*16 + l15;
                size_t wo = (size_t)n*512 + sc*128 + ks*32 + lh*8;
                wbh[nt] = *(const bf16x8*)(w4h + wo);
                wbl[nt] = *(const bf16x8*)(w4l + wo);
            }
#pragma unroll
            for (int mt = 0; mt < 4; ++mt) {
                int row = mt*16 + l15;
                int off = row*256 + ((ks*64 + lh*16) ^ ((row&7)<<4));
                bf16x8 fah = *(bf16x8*)((char*)f3h + off);
                bf16x8 fal = *(bf16x8*)((char*)f3l + off);
#pragma unroll
                for (int nt = 0; nt < 3; ++nt) {
                    acc4[mt][nt] = __builtin_amdgcn_mfma_f32_16x16x32_bf16(fah, wbh[nt], acc4[mt][nt], 0, 0, 0);
                    acc4[mt][nt] = __builtin_amdgcn_mfma_f32_16x16x32_bf16(fah, wbl[nt], acc4[mt][nt], 0, 0, 0);
                    acc4[mt][nt] = __builtin_amdgcn_mfma_f32_16x16x32_bf16(fal, wbh[nt], acc4[mt][nt], 0, 0, 0);
                }
            }
        }
        __builtin_amdgcn_s_setprio(0);
        b3c0 = b3n0; b3c1 = b3n1;
    }
    // ---- epilogue: per group, max over 32 rows, + b4 ----
#pragma unroll
    for (int nt = 0; nt < 3; ++nt) {
        int n = w*48 + nt*16 + l15;
        float m0 = acc4[0][nt][0], m1 = acc4[2][nt][0];
#pragma unroll
        for (int q = 1; q < 4; ++q) { m0 = fmaxf(m0, acc4[0][nt][q]); m1 = fmaxf(m1, acc4[2][nt][q]); }
#pragma unroll
        for (int q = 0; q < 4; ++q) { m0 = fmaxf(m0, acc4[1][nt][q]); m1 = fmaxf(m1, acc4[3][nt][q]); }
        m0 = fmaxf(m0, __shfl_xor(m0, 16));
        m0 = fmaxf(m0, __shfl_xor(m0, 32));
        m1 = fmaxf(m1, __shfl_xor(m1, 16));
        m1 = fmaxf(m1, __shfl_xor(m1, 32));
        if (lh == 0) {
            float bb = b4[n];
            out[(size_t)g0 * 384 + n]       = m0 + bb;
            out[(size_t)(g0 + 1) * 384 + n] = m1 + bb;
        }
    }
}

// =================== launch ===================
extern "C" void kernel_launch(void* const* d_in, const int* in_sizes, int n_in,
                              void* d_out, int out_size, void* d_ws, size_t ws_size,
                              hipStream_t stream) {
    const float* xyz = (const float*)d_in[0];
    const float* w1  = (const float*)d_in[1];
    const float* b1  = (const float*)d_in[2];
    const float* g1  = (const float*)d_in[3];
    const float* bt1 = (const float*)d_in[4];
    const float* w2  = (const float*)d_in[5];
    const float* b2  = (const float*)d_in[6];
    const float* w3  = (const float*)d_in[7];
    const float* b3  = (const float*)d_in[8];
    const float* g3  = (const float*)d_in[9];
    const float* bt3 = (const float*)d_in[10];
    const float* w4  = (const float*)d_in[11];
    const float* b4  = (const float*)d_in[12];
    float* out = (float*)d_out;
    float* ws  = (float*)d_ws;

    if (ws_size < WS_FLOATS * sizeof(float)) return;  // leaves poison -> clean mismatch signal

    float* centers = ws + OFF_CENTERS;
    float* nb      = ws + OFF_NB;
    float* fgB     = ws + OFF_FG;
    float* c1B     = ws + OFF_C1;
    float* mom     = ws + OFF_MOM;
    float* A       = ws + OFF_A;
    float* s1      = ws + OFF_S1;
    float* sf      = ws + OFF_SF;
    float* mu      = ws + OFF_MU;
    float* w2s1    = ws + OFF_W2S1;
    float* bn1a    = ws + OFF_BN1A;
    float* bn1d    = ws + OFF_BN1D;
    float* bn3a    = ws + OFF_BN3A;
    float* bn3d    = ws + OFF_BN3D;
    float* sff     = ws + OFF_SFF;
    float* pfct    = ws + OFF_PFCT;
    float* t1m     = ws + OFF_T1;
    float* sccw    = ws + OFF_SCCW;
    float* sfcm    = ws + OFF_SFC;
    float* w2t     = ws + OFF_W2T;
    float* w3t     = ws + OFF_W3T;
    ushort_t* w4h  = (ushort_t*)(ws + OFF_W4H);
    ushort_t* w4l  = (ushort_t*)(ws + OFF_W4L);
    float* apart   = ws + OFF_APART;
    float* w23     = ws + OFF_W23;
    ushort_t* w23h = (ushort_t*)(ws + OFF_W23H);
    ushort_t* w23l = (ushort_t*)(ws + OFF_W23L);
    ushort_t* w2h  = (ushort_t*)(ws + OFF_W2H);
    ushort_t* w2l  = (ushort_t*)(ws + OFF_W2L);
    float* base3   = ws + OFF_BASE3;   // aliases apart (valid after reduce_a)

    zero_mom_kernel<<<1, 64, 0, stream>>>(mom);
    fps_kernel<<<B_, 1024, 0, stream>>>(xyz, centers);
    knn_kernel<<<GT, 256, 0, stream>>>(xyz, centers, nb);
    moments_kernel<<<NROW/256, 256, 0, stream>>>(nb, mom);
    bn1_params_kernel<<<1, 128, 0, stream>>>(mom, w1, b1, g1, bt1, bn1a, bn1d);
    transpose_kernel<<<(256*128 + 255)/256, 256, 0, stream>>>(w2t, w2, 256, 128);
    transpose_kernel<<<(512*512 + 255)/256, 256, 0, stream>>>(w3t, w3, 512, 512);
    // W23[n][k] = sum_j w3[n][256+j] * w2[j][k]  (f2-linearity fold)
    gemm_tn_kernel<<<dim3(8, 32), 256, 0, stream>>>(w23, w3t + 256*512, w2, 512, 128, 256, 512, 128);
    split_kernel<<<(65536 + 255)/256, 256, 0, stream>>>(w23, w23h, w23l, 65536);
    split_kernel<<<(196608 + 255)/256, 256, 0, stream>>>(w4, w4h, w4l, 196608);
    split_kernel<<<(32768 + 255)/256, 256, 0, stream>>>(w2, w2h, w2l, 32768);
    p1_mfma_kernel<<<512, 256, 0, stream>>>(nb, w1, bn1a, bn1d, w2h, w2l, b2, fgB, c1B, apart);
    reduce_a_kernel<<<64, 256, 0, stream>>>(apart, A);
    // base3[g][n] = sum_{k<256} fg[g][k] * w3[n][k]   (overwrites apart region)
    gemm_nn_kernel<<<dim3(8, 128), 256, 0, stream>>>(base3, fgB, w3t, GT, 512, 256, 256, 512);
    reduce_cf_kernel<<<384, 256, 0, stream>>>(c1B, fgB, s1, sf);
    assemble_mu_kernel<<<2, 256, 0, stream>>>(s1, sf, w2t, b2, mu, w2s1);
    gemm_tn_kernel<<<dim3(16,16), 256, 0, stream>>>(sff,  fgB,  fgB, 256, 256, GT,  256, 256);
    gemm_tn_kernel<<<dim3(16, 8), 256, 0, stream>>>(pfct, c1B,  fgB, 128, 256, GT,  128, 256);
    gemm_tn_kernel<<<dim3(16, 8), 256, 0, stream>>>(t1m,  A,    w2t, 128, 256, 128, 128, 256);
    gemm_tn_kernel<<<dim3(16,16), 256, 0, stream>>>(sccw, w2t,  t1m, 256, 256, 128, 256, 256);
    gemm_tn_kernel<<<dim3(16,16), 256, 0, stream>>>(sfcm, pfct, w2t, 256, 256, 128, 256, 256);
    bn3_params_kernel<<<512, 256, 0, stream>>>(w3, b3, g3, bt3, sff, sfcm, sccw, sf, w2s1, b2, mu, bn3a, bn3d);
    p3_mfma_kernel<<<GT/2, 512, 0, stream>>>(nb, w1, bn1a, bn1d, w23h, w23l, w4h, w4l,
                                             base3, bn3a, bn3d, b4, out);
}